// Round 1
// baseline (2740.949 us; speedup 1.0000x reference)
//
#include <hip/hip_runtime.h>

#define EPSBN 2e-5f

// ---------------- Stage 1: lift_conv + pool + relu + stats ----------------
// x: (B,100,6)  w1: (12,6,7)  out r1: (B,12,9,50) = relu(maxpool2(lift_conv))
__global__ __launch_bounds__(256) void k_lift(const float* __restrict__ x,
    const float* __restrict__ w1, float* __restrict__ r1,
    float* __restrict__ sum, float* __restrict__ sq) {
  __shared__ float xs[6 * 100];
  __shared__ float ws[12 * 6 * 7];
  __shared__ float ssum[12], ssq[12];
  int b = blockIdx.x, tid = threadIdx.x;
  for (int i = tid; i < 600; i += 256) {
    int t = i / 6, c = i % 6;
    xs[c * 100 + t] = x[(size_t)b * 600 + i];
  }
  for (int i = tid; i < 504; i += 256) ws[i] = w1[i];
  if (tid < 12) { ssum[tid] = 0.f; ssq[tid] = 0.f; }
  __syncthreads();
  for (int idx = tid; idx < 5400; idx += 256) {
    int o = idx / 450, rem = idx % 450, si = rem / 50, u = rem % 50;
    int s = 1 << si;
    float inv = 1.0f / (float)s;
    float mx = -1e30f;
    for (int t = 2 * u; t <= 2 * u + 1; ++t) {
      float acc = 0.f;
      for (int c = 0; c < 6; ++c) {
        const float* wr = &ws[(o * 6 + c) * 7];
        const float* xr = &xs[c * 100];
#pragma unroll
        for (int j = 0; j < 7; ++j) {
          int tt = t + s * (j - 3);
          if (tt >= 0 && tt < 100) acc += xr[tt] * wr[j];
        }
      }
      mx = fmaxf(mx, acc * inv);
    }
    float v = fmaxf(mx, 0.f);
    r1[(size_t)b * 5400 + idx] = v;
    atomicAdd(&ssum[o], v);
    atomicAdd(&ssq[o], v * v);
  }
  __syncthreads();
  if (tid < 12) { atomicAdd(&sum[tid], ssum[tid]); atomicAdd(&sq[tid], ssq[tid]); }
}

// ---------------- BN stats -> scale/shift ----------------
__global__ void k_bnstat(const float* __restrict__ sum, const float* __restrict__ sq,
    const float* __restrict__ g, const float* __restrict__ bb,
    float* __restrict__ sc, float* __restrict__ sh, int C, float invN) {
  int c = threadIdx.x;
  if (c < C) {
    float m = sum[c] * invN;
    float v = sq[c] * invN - m * m;
    float scale = g[c] * rsqrtf(v + EPSBN);
    sc[c] = scale;
    sh[c] = bb[c] - m * scale;
  }
}

// ---------------- Stage 2: BN1-affine + pool + gg_conv(w2) + pool + relu + stats ----
// r1: (B,12,9,50) -> a(12,9,25); w2: (24,12,3,5); out r2: (B,24,7,12)
__global__ __launch_bounds__(256) void k_stage2(const float* __restrict__ r1,
    const float* __restrict__ w2, const float* __restrict__ sc, const float* __restrict__ sh,
    float* __restrict__ r2, float* __restrict__ sum, float* __restrict__ sq) {
  __shared__ float a[12 * 9 * 25];
  __shared__ float ws[24 * 12 * 3 * 5];
  __shared__ float ssum[24], ssq[24];
  int b = blockIdx.x, tid = threadIdx.x;
  const float2* src = (const float2*)(r1 + (size_t)b * 5400);
  for (int i = tid; i < 2700; i += 256) {
    float2 p = src[i];
    int c = i / 225;
    a[i] = fmaxf(p.x, p.y) * sc[c] + sh[c];
  }
  for (int i = tid; i < 4320; i += 256) ws[i] = w2[i];
  if (tid < 24) { ssum[tid] = 0.f; ssq[tid] = 0.f; }
  __syncthreads();
  for (int idx = tid; idx < 2016; idx += 256) {
    int o = idx / 84, rem = idx % 84, i2 = rem / 12, u = rem % 12;
    int s = 1 << i2;
    float inv = 1.0f / (float)s;
    float mx = -1e30f;
    for (int t = 2 * u; t <= 2 * u + 1; ++t) {
      float acc = 0.f;
      for (int c = 0; c < 12; ++c)
        for (int h = 0; h < 3; ++h) {
          const float* ar = &a[(c * 9 + i2 + h) * 25];
          const float* wr = &ws[((o * 12 + c) * 3 + h) * 5];
#pragma unroll
          for (int j = 0; j < 5; ++j) {
            int tt = t + s * (j - 2);
            if (tt >= 0 && tt < 25) acc += ar[tt] * wr[j];
          }
        }
      mx = fmaxf(mx, acc * inv);
    }
    float v = fmaxf(mx, 0.f);
    r2[(size_t)b * 2016 + idx] = v;
    atomicAdd(&ssum[o], v);
    atomicAdd(&ssq[o], v * v);
  }
  __syncthreads();
  if (tid < 24) { atomicAdd(&sum[tid], ssum[tid]); atomicAdd(&sq[tid], ssq[tid]); }
}

// ---------------- Stage 3: BN2-affine + pool + gg_conv(w3) + pool + relu + stats ----
// r2: (B,24,7,12) -> a(24,7,6); w3: (48,24,3,5); out r3: (B,48,5,3)
__global__ __launch_bounds__(256) void k_stage3(const float* __restrict__ r2,
    const float* __restrict__ w3, const float* __restrict__ sc, const float* __restrict__ sh,
    float* __restrict__ r3, float* __restrict__ sum, float* __restrict__ sq) {
  __shared__ float a[24 * 7 * 6];
  __shared__ float ws[48 * 24 * 3 * 5];  // 69 KB
  __shared__ float ssum[48], ssq[48];
  int b = blockIdx.x, tid = threadIdx.x;
  const float2* src = (const float2*)(r2 + (size_t)b * 2016);
  for (int i = tid; i < 1008; i += 256) {
    float2 p = src[i];
    int c = i / 42;
    a[i] = fmaxf(p.x, p.y) * sc[c] + sh[c];
  }
  for (int i = tid; i < 17280; i += 256) ws[i] = w3[i];
  if (tid < 48) { ssum[tid] = 0.f; ssq[tid] = 0.f; }
  __syncthreads();
  for (int idx = tid; idx < 720; idx += 256) {
    int o = idx / 15, rem = idx % 15, i2 = rem / 3, u = rem % 3;
    int s = 1 << i2;
    float inv = 1.0f / (float)s;
    float mx = -1e30f;
    for (int t = 2 * u; t <= 2 * u + 1; ++t) {
      float acc = 0.f;
      for (int c = 0; c < 24; ++c)
        for (int h = 0; h < 3; ++h) {
          const float* ar = &a[(c * 7 + i2 + h) * 6];
          const float* wr = &ws[((o * 24 + c) * 3 + h) * 5];
#pragma unroll
          for (int j = 0; j < 5; ++j) {
            int tt = t + s * (j - 2);
            if (tt >= 0 && tt < 6) acc += ar[tt] * wr[j];
          }
        }
      mx = fmaxf(mx, acc * inv);
    }
    float v = fmaxf(mx, 0.f);
    r3[(size_t)b * 720 + idx] = v;
    atomicAdd(&ssum[o], v);
    atomicAdd(&ssq[o], v * v);
  }
  __syncthreads();
  if (tid < 48) { atomicAdd(&sum[tid], ssum[tid]); atomicAdd(&sq[tid], ssq[tid]); }
}

// ---------------- Stage 4: BN3-affine + gg_conv(w4) + pool + relu + stats ----------
// r3: (B,48,5,3); w4: (96,48,3,3); out r4: (B,96,3) ; 4 batch elems / block
__global__ __launch_bounds__(256) void k_stage4(const float* __restrict__ r3,
    const float* __restrict__ w4, const float* __restrict__ sc, const float* __restrict__ sh,
    float* __restrict__ r4, float* __restrict__ sum, float* __restrict__ sq) {
  __shared__ float a[4][720];
  __shared__ float ws[24 * 48 * 3 * 3];  // 41.5 KB chunk (24 of 96 out-channels)
  __shared__ float ssum[96], ssq[96];
  int b0 = blockIdx.x * 4, tid = threadIdx.x;
  for (int i = tid; i < 4 * 720; i += 256) {
    int bb = i / 720, f = i % 720, c = f / 15;
    a[bb][f] = r3[(size_t)(b0 + bb) * 720 + f] * sc[c] + sh[c];
  }
  if (tid < 96) { ssum[tid] = 0.f; ssq[tid] = 0.f; }
  __syncthreads();
  for (int chunk = 0; chunk < 4; ++chunk) {
    for (int i = tid; i < 10368; i += 256) ws[i] = w4[chunk * 10368 + i];
    __syncthreads();
    // outputs: 4b x 24o x 3i, pooled over t in {0,1} (t=2 dropped by pool)
    for (int idx = tid; idx < 288; idx += 256) {
      int bb = idx / 72, rem = idx % 72, oo = rem / 3, i2 = rem % 3;
      int o = chunk * 24 + oo;
      int s = 1 << i2;
      float inv = 1.0f / (float)s;
      float mx = -1e30f;
      for (int t = 0; t <= 1; ++t) {
        float acc = 0.f;
        for (int c = 0; c < 48; ++c)
          for (int h = 0; h < 3; ++h) {
            const float* ar = &a[bb][(c * 5 + i2 + h) * 3];
            const float* wr = &ws[((oo * 48 + c) * 3 + h) * 3];
#pragma unroll
            for (int j = 0; j < 3; ++j) {
              int tt = t + s * (j - 1);
              if (tt >= 0 && tt < 3) acc += ar[tt] * wr[j];
            }
          }
        mx = fmaxf(mx, acc * inv);
      }
      float v = fmaxf(mx, 0.f);
      r4[(size_t)(b0 + bb) * 288 + o * 3 + i2] = v;
      atomicAdd(&ssum[o], v);
      atomicAdd(&ssq[o], v * v);
    }
    __syncthreads();
  }
  if (tid < 96) { atomicAdd(&sum[tid], ssum[tid]); atomicAdd(&sq[tid], ssq[tid]); }
}

// ---------------- FC head: BN4-affine + 288->96->48->6 ----------------
__global__ __launch_bounds__(256) void k_fc(const float* __restrict__ r4,
    const float* __restrict__ sc, const float* __restrict__ sh,
    const float* __restrict__ f1w, const float* __restrict__ f1b,
    const float* __restrict__ f2w, const float* __restrict__ f2b,
    const float* __restrict__ f3w, const float* __restrict__ f3b,
    float* __restrict__ out) {
  __shared__ float v[4][288];
  __shared__ float h1[4][96];
  __shared__ float h2[4][48];
  int b0 = blockIdx.x * 4, tid = threadIdx.x;
  for (int i = tid; i < 4 * 288; i += 256) {
    int bb = i / 288, f = i % 288, c = f / 3;
    v[bb][f] = r4[(size_t)(b0 + bb) * 288 + f] * sc[c] + sh[c];
  }
  __syncthreads();
  for (int d = tid; d < 384; d += 256) {
    int o = d >> 2, bb = d & 3;
    const float* wr = &f1w[o * 288];
    const float* vv = v[bb];
    float acc = f1b[o];
    for (int f = 0; f < 288; ++f) acc += wr[f] * vv[f];
    h1[bb][o] = acc;
  }
  __syncthreads();
  if (tid < 192) {
    int o = tid >> 2, bb = tid & 3;
    const float* wr = &f2w[o * 96];
    float acc = f2b[o];
    for (int f = 0; f < 96; ++f) acc += wr[f] * h1[bb][f];
    h2[bb][o] = acc;
  }
  __syncthreads();
  if (tid < 24) {
    int o = tid >> 2, bb = tid & 3;
    const float* wr = &f3w[o * 48];
    float acc = f3b[o];
    for (int f = 0; f < 48; ++f) acc += wr[f] * h2[bb][f];
    out[(size_t)(b0 + bb) * 6 + o] = acc;
  }
}

extern "C" void kernel_launch(void* const* d_in, const int* in_sizes, int n_in,
                              void* d_out, int out_size, void* d_ws, size_t ws_size,
                              hipStream_t stream) {
  const float* x   = (const float*)d_in[0];
  const float* w1  = (const float*)d_in[1];
  const float* w2  = (const float*)d_in[2];
  const float* w3  = (const float*)d_in[3];
  const float* w4  = (const float*)d_in[4];
  const float* g1  = (const float*)d_in[5];
  const float* b1  = (const float*)d_in[6];
  const float* g2  = (const float*)d_in[7];
  const float* b2  = (const float*)d_in[8];
  const float* g3  = (const float*)d_in[9];
  const float* b3  = (const float*)d_in[10];
  const float* g4  = (const float*)d_in[11];
  const float* b4  = (const float*)d_in[12];
  const float* f1w = (const float*)d_in[13];
  const float* f1b = (const float*)d_in[14];
  const float* f2w = (const float*)d_in[15];
  const float* f2b = (const float*)d_in[16];
  const float* f3w = (const float*)d_in[17];
  const float* f3b = (const float*)d_in[18];
  float* out = (float*)d_out;
  float* ws = (float*)d_ws;

  const int B = 4096;
  // stats layout (floats)
  float* SUM1 = ws + 0;   float* SQ1 = ws + 12;
  float* SUM2 = ws + 24;  float* SQ2 = ws + 48;
  float* SUM3 = ws + 72;  float* SQ3 = ws + 120;
  float* SUM4 = ws + 168; float* SQ4 = ws + 264;
  float* SC1 = ws + 384;  float* SH1 = ws + 396;
  float* SC2 = ws + 408;  float* SH2 = ws + 432;
  float* SC3 = ws + 456;  float* SH3 = ws + 504;
  float* SC4 = ws + 552;  float* SH4 = ws + 648;
  float* R1 = ws + 1024;                    // B*5400 floats
  float* R2 = ws + 1024 + (size_t)B * 5400; // B*2016 floats
  float* R3 = ws + 1024;                    // aliases R1 (dead after stage2)
  float* R4 = ws + 1024 + (size_t)B * 720;  // B*288 floats, still inside old R1

  hipMemsetAsync(d_ws, 0, 384 * sizeof(float), stream);

  k_lift<<<B, 256, 0, stream>>>(x, w1, R1, SUM1, SQ1);
  k_bnstat<<<1, 128, 0, stream>>>(SUM1, SQ1, g1, b1, SC1, SH1, 12, 1.0f / (float)(B * 450));
  k_stage2<<<B, 256, 0, stream>>>(R1, w2, SC1, SH1, R2, SUM2, SQ2);
  k_bnstat<<<1, 128, 0, stream>>>(SUM2, SQ2, g2, b2, SC2, SH2, 24, 1.0f / (float)(B * 84));
  k_stage3<<<B, 256, 0, stream>>>(R2, w3, SC2, SH2, R3, SUM3, SQ3);
  k_bnstat<<<1, 128, 0, stream>>>(SUM3, SQ3, g3, b3, SC3, SH3, 48, 1.0f / (float)(B * 15));
  k_stage4<<<B / 4, 256, 0, stream>>>(R3, w4, SC3, SH3, R4, SUM4, SQ4);
  k_bnstat<<<1, 128, 0, stream>>>(SUM4, SQ4, g4, b4, SC4, SH4, 96, 1.0f / (float)(B * 3));
  k_fc<<<B / 4, 256, 0, stream>>>(R4, SC4, SH4, f1w, f1b, f2w, f2b, f3w, f3b, out);
}

// Round 2
// 1172.907 us; speedup vs baseline: 2.3369x; 2.3369x over previous
//
#include <hip/hip_runtime.h>

#define EPSBN 2e-5f

__device__ __forceinline__ float lread(const float* __restrict__ p, int i, int n) {
  bool ok = (unsigned)i < (unsigned)n;
  float v = p[ok ? i : 0];
  return ok ? v : 0.f;
}

// ---------------- Stage 1: lift_conv + pool + relu + stats ----------------
// x: (B,100,6)  w1: (12,6,7)  out r1: (B,12,9,50) = relu(maxpool2(lift_conv/s))
#define NB1 4
__global__ __launch_bounds__(256) void k_lift(const float* __restrict__ x,
    const float* __restrict__ w1, float* __restrict__ r1,
    float* __restrict__ sum, float* __restrict__ sq) {
  __shared__ float xs[NB1][600];   // [c*100+t]
  __shared__ float ws[504];
  __shared__ float ssum[12], ssq[12];
  int b0 = blockIdx.x * NB1, tid = threadIdx.x;
  for (int i = tid; i < NB1 * 600; i += 256) {
    int bb = i / 600, f = i % 600;
    int t = f / 6, c = f % 6;
    xs[bb][c * 100 + t] = x[(size_t)(b0 + bb) * 600 + f];
  }
  for (int i = tid; i < 504; i += 256) ws[i] = w1[i];
  if (tid < 12) { ssum[tid] = 0.f; ssq[tid] = 0.f; }
  __syncthreads();
  // tasks: (bb, ot(6 x o-tile2), si(9), tc(10 x t-chunk10)) = NB1*540
  for (int task = tid; task < NB1 * 540; task += 256) {
    int bb = task / 540, rem = task % 540;
    int ot = rem / 90; rem %= 90;
    int si = rem / 10, tc = rem % 10;
    int o0 = ot * 2, t0 = tc * 10;
    int s = 1 << si;
    float inv = 1.0f / (float)s;
    float acc0[10], acc1[10];
#pragma unroll
    for (int k = 0; k < 10; ++k) { acc0[k] = 0.f; acc1[k] = 0.f; }
    const float* xb = xs[bb];
    for (int c = 0; c < 6; ++c) {
      const float* xr = xb + c * 100;
      const float* wr0 = ws + (o0 * 6 + c) * 7;
#pragma unroll
      for (int j = 0; j < 7; ++j) {
        int off = s * (j - 3) + t0;
        float w0 = wr0[j], w1v = wr0[j + 42];
#pragma unroll
        for (int k = 0; k < 10; ++k) {
          float av = lread(xr, off + k, 100);
          acc0[k] += av * w0;
          acc1[k] += av * w1v;
        }
      }
    }
    float s0 = 0.f, q0 = 0.f, s1 = 0.f, q1 = 0.f;
    size_t rb = ((size_t)(b0 + bb) * 12 + o0) * 9 + si;
#pragma unroll
    for (int u = 0; u < 5; ++u) {
      float v0 = fmaxf(fmaxf(acc0[2 * u], acc0[2 * u + 1]) * inv, 0.f);
      float v1 = fmaxf(fmaxf(acc1[2 * u], acc1[2 * u + 1]) * inv, 0.f);
      r1[rb * 50 + t0 / 2 + u] = v0;
      r1[(rb + 9) * 50 + t0 / 2 + u] = v1;
      s0 += v0; q0 += v0 * v0; s1 += v1; q1 += v1 * v1;
    }
    atomicAdd(&ssum[o0], s0); atomicAdd(&ssq[o0], q0);
    atomicAdd(&ssum[o0 + 1], s1); atomicAdd(&ssq[o0 + 1], q1);
  }
  __syncthreads();
  if (tid < 12) { atomicAdd(&sum[tid], ssum[tid]); atomicAdd(&sq[tid], ssq[tid]); }
}

// ---------------- BN stats -> scale/shift ----------------
__global__ void k_bnstat(const float* __restrict__ sum, const float* __restrict__ sq,
    const float* __restrict__ g, const float* __restrict__ bb,
    float* __restrict__ sc, float* __restrict__ sh, int C, float invN) {
  int c = threadIdx.x;
  if (c < C) {
    float m = sum[c] * invN;
    float v = sq[c] * invN - m * m;
    float scale = g[c] * rsqrtf(v + EPSBN);
    sc[c] = scale;
    sh[c] = bb[c] - m * scale;
  }
}

// ---------------- Stage 2: BN1-affine + pool + gg_conv(w2) + pool + relu + stats ----
// r1: (B,12,9,50) -> a(12,9,25); w2: (24,12,3,5); out r2: (B,24,7,12)
#define NB2 3
__global__ __launch_bounds__(256) void k_stage2(const float* __restrict__ r1,
    const float* __restrict__ w2, const float* __restrict__ sc, const float* __restrict__ sh,
    float* __restrict__ r2, float* __restrict__ sum, float* __restrict__ sq, int B) {
  __shared__ float as[NB2][2700];  // (c*9+si)*25+x
  __shared__ float ws[4320];
  __shared__ float ssum[24], ssq[24];
  int b0 = blockIdx.x * NB2, tid = threadIdx.x;
  for (int i = tid; i < NB2 * 2700; i += 256) {
    int bb = i / 2700, f = i % 2700;
    if (b0 + bb < B) {
      const float2* src = (const float2*)(r1 + (size_t)(b0 + bb) * 5400);
      float2 p = src[f];
      int c = f / 225;
      as[bb][f] = fmaxf(p.x, p.y) * sc[c] + sh[c];
    }
  }
  for (int i = tid; i < 4320; i += 256) ws[i] = w2[i];
  if (tid < 24) { ssum[tid] = 0.f; ssq[tid] = 0.f; }
  __syncthreads();
  // tasks: (bb, ot(12 x o-tile2), i2(7)) = NB2*84
  for (int task = tid; task < NB2 * 84; task += 256) {
    int bb = task / 84, rem = task % 84;
    if (b0 + bb >= B) continue;
    int ot = rem / 7, i2 = rem % 7;
    int o0 = ot * 2;
    int s = 1 << i2;
    float inv = 1.0f / (float)s;
    float acc0[24], acc1[24];
#pragma unroll
    for (int t = 0; t < 24; ++t) { acc0[t] = 0.f; acc1[t] = 0.f; }
    for (int c = 0; c < 12; ++c) {
#pragma unroll
      for (int h = 0; h < 3; ++h) {
        const float* ar = as[bb] + (c * 9 + i2 + h) * 25;
        const float* wr = ws + ((o0 * 12 + c) * 3 + h) * 5;
#pragma unroll
        for (int j = 0; j < 5; ++j) {
          int off = s * (j - 2);
          float w0 = wr[j], w1v = wr[j + 180];
#pragma unroll
          for (int t = 0; t < 24; ++t) {
            float av = lread(ar, t + off, 25);
            acc0[t] += av * w0;
            acc1[t] += av * w1v;
          }
        }
      }
    }
    float s0 = 0.f, q0 = 0.f, s1 = 0.f, q1 = 0.f;
    size_t rb = ((size_t)(b0 + bb) * 24 + o0) * 84 + i2 * 12;
#pragma unroll
    for (int u = 0; u < 12; ++u) {
      float v0 = fmaxf(fmaxf(acc0[2 * u], acc0[2 * u + 1]) * inv, 0.f);
      float v1 = fmaxf(fmaxf(acc1[2 * u], acc1[2 * u + 1]) * inv, 0.f);
      r2[rb + u] = v0;
      r2[rb + 84 + u] = v1;
      s0 += v0; q0 += v0 * v0; s1 += v1; q1 += v1 * v1;
    }
    atomicAdd(&ssum[o0], s0); atomicAdd(&ssq[o0], q0);
    atomicAdd(&ssum[o0 + 1], s1); atomicAdd(&ssq[o0 + 1], q1);
  }
  __syncthreads();
  if (tid < 24) { atomicAdd(&sum[tid], ssum[tid]); atomicAdd(&sq[tid], ssq[tid]); }
}

// ---------------- Stage 3: BN2-affine + pool + gg_conv(w3) + pool + relu + stats ----
// r2: (B,24,7,12) -> a(24,7,6); w3: (48,24,3,5); out r3: (B,48,5,3)
#define NB3 8
__global__ __launch_bounds__(256) void k_stage3(const float* __restrict__ r2,
    const float* __restrict__ w3, const float* __restrict__ sc, const float* __restrict__ sh,
    float* __restrict__ r3, float* __restrict__ sum, float* __restrict__ sq) {
  __shared__ float as[NB3][1008];  // (c*7+i2)*6+x
  __shared__ float ws[8640];       // 24-o chunk of w3
  __shared__ float ssum[48], ssq[48];
  int b0 = blockIdx.x * NB3, tid = threadIdx.x;
  for (int i = tid; i < NB3 * 1008; i += 256) {
    int bb = i / 1008, f = i % 1008;
    const float2* src = (const float2*)(r2 + (size_t)(b0 + bb) * 2016);
    float2 p = src[f];
    int c = f / 42;
    as[bb][f] = fmaxf(p.x, p.y) * sc[c] + sh[c];
  }
  if (tid < 48) { ssum[tid] = 0.f; ssq[tid] = 0.f; }
  for (int chunk = 0; chunk < 2; ++chunk) {
    __syncthreads();
    for (int i = tid; i < 8640; i += 256) ws[i] = w3[chunk * 8640 + i];
    __syncthreads();
    // tasks: (bb, ot(6 x o-tile4), i2(5)) = 240
    for (int task = tid; task < NB3 * 30; task += 256) {
      int bb = task / 30, rem = task % 30;
      int ot = rem / 5, i2 = rem % 5;
      int s = 1 << i2;
      float inv = 1.0f / (float)s;
      float acc[4][6];
#pragma unroll
      for (int oo = 0; oo < 4; ++oo)
#pragma unroll
        for (int t = 0; t < 6; ++t) acc[oo][t] = 0.f;
      for (int c = 0; c < 24; ++c) {
#pragma unroll
        for (int h = 0; h < 3; ++h) {
          const float* ar = as[bb] + (c * 7 + i2 + h) * 6;
          const float* wr = ws + ((ot * 4 * 24 + c) * 3 + h) * 5;
#pragma unroll
          for (int j = 0; j < 5; ++j) {
            int off = s * (j - 2);
            float w0 = wr[j], w1 = wr[j + 360], w2v = wr[j + 720], w3v = wr[j + 1080];
#pragma unroll
            for (int t = 0; t < 6; ++t) {
              float av = lread(ar, t + off, 6);
              acc[0][t] += av * w0;
              acc[1][t] += av * w1;
              acc[2][t] += av * w2v;
              acc[3][t] += av * w3v;
            }
          }
        }
      }
      int ob = chunk * 24 + ot * 4;
#pragma unroll
      for (int oo = 0; oo < 4; ++oo) {
        float ss = 0.f, qq = 0.f;
        size_t rb = ((size_t)(b0 + bb) * 48 + ob + oo) * 15 + i2 * 3;
#pragma unroll
        for (int u = 0; u < 3; ++u) {
          float v = fmaxf(fmaxf(acc[oo][2 * u], acc[oo][2 * u + 1]) * inv, 0.f);
          r3[rb + u] = v;
          ss += v; qq += v * v;
        }
        atomicAdd(&ssum[ob + oo], ss); atomicAdd(&ssq[ob + oo], qq);
      }
    }
  }
  __syncthreads();
  if (tid < 48) { atomicAdd(&sum[tid], ssum[tid]); atomicAdd(&sq[tid], ssq[tid]); }
}

// ---------------- Stage 4: BN3-affine + gg_conv(w4) + pool + relu + stats ----------
// r3: (B,48,5,3); w4: (96,48,3,3); out r4: (B,96,3)
#define NB4 8
__global__ __launch_bounds__(256) void k_stage4(const float* __restrict__ r3,
    const float* __restrict__ w4, const float* __restrict__ sc, const float* __restrict__ sh,
    float* __restrict__ r4, float* __restrict__ sum, float* __restrict__ sq) {
  __shared__ float as[NB4][720];   // (c*5+i2)*3+x
  __shared__ float ws[10368];      // 24-o chunk of w4
  __shared__ float ssum[96], ssq[96];
  int b0 = blockIdx.x * NB4, tid = threadIdx.x;
  for (int i = tid; i < NB4 * 720; i += 256) {
    int bb = i / 720, f = i % 720, c = f / 15;
    as[bb][f] = r3[(size_t)(b0 + bb) * 720 + f] * sc[c] + sh[c];
  }
  if (tid < 96) { ssum[tid] = 0.f; ssq[tid] = 0.f; }
  for (int chunk = 0; chunk < 4; ++chunk) {
    __syncthreads();
    for (int i = tid; i < 10368; i += 256) ws[i] = w4[chunk * 10368 + i];
    __syncthreads();
    // tasks: (bb, ot(12 x o-tile2), i2(3)) = 288
    for (int task = tid; task < NB4 * 36; task += 256) {
      int bb = task / 36, rem = task % 36;
      int ot = rem / 3, i2 = rem % 3;
      int s = 1 << i2;
      float inv = 1.0f / (float)s;
      float acc[2][2];
      acc[0][0] = acc[0][1] = acc[1][0] = acc[1][1] = 0.f;
      for (int c = 0; c < 48; ++c) {
#pragma unroll
        for (int h = 0; h < 3; ++h) {
          const float* ar = as[bb] + (c * 5 + i2 + h) * 3;
          const float* wr = ws + ((ot * 2 * 48 + c) * 3 + h) * 3;
#pragma unroll
          for (int j = 0; j < 3; ++j) {
            int off = s * (j - 1);
            float w0 = wr[j], w1 = wr[j + 432];
#pragma unroll
            for (int t = 0; t < 2; ++t) {
              float av = lread(ar, t + off, 3);
              acc[0][t] += av * w0;
              acc[1][t] += av * w1;
            }
          }
        }
      }
      int ob = chunk * 24 + ot * 2;
#pragma unroll
      for (int oo = 0; oo < 2; ++oo) {
        float v = fmaxf(fmaxf(acc[oo][0], acc[oo][1]) * inv, 0.f);
        r4[(size_t)(b0 + bb) * 288 + (ob + oo) * 3 + i2] = v;
        atomicAdd(&ssum[ob + oo], v); atomicAdd(&ssq[ob + oo], v * v);
      }
    }
  }
  __syncthreads();
  if (tid < 96) { atomicAdd(&sum[tid], ssum[tid]); atomicAdd(&sq[tid], ssq[tid]); }
}

// ---------------- FC head: BN4-affine + 288->96->48->6 ----------------
__global__ __launch_bounds__(256) void k_fc(const float* __restrict__ r4,
    const float* __restrict__ sc, const float* __restrict__ sh,
    const float* __restrict__ f1w, const float* __restrict__ f1b,
    const float* __restrict__ f2w, const float* __restrict__ f2b,
    const float* __restrict__ f3w, const float* __restrict__ f3b,
    float* __restrict__ out) {
  __shared__ float v[4][288];
  __shared__ float h1[4][96];
  __shared__ float h2[4][48];
  int b0 = blockIdx.x * 4, tid = threadIdx.x;
  for (int i = tid; i < 4 * 288; i += 256) {
    int bb = i / 288, f = i % 288, c = f / 3;
    v[bb][f] = r4[(size_t)(b0 + bb) * 288 + f] * sc[c] + sh[c];
  }
  __syncthreads();
  for (int d = tid; d < 384; d += 256) {
    int o = d >> 2, bb = d & 3;
    const float* wr = &f1w[o * 288];
    const float* vv = v[bb];
    float acc = f1b[o];
    for (int f = 0; f < 288; ++f) acc += wr[f] * vv[f];
    h1[bb][o] = acc;
  }
  __syncthreads();
  if (tid < 192) {
    int o = tid >> 2, bb = tid & 3;
    const float* wr = &f2w[o * 96];
    float acc = f2b[o];
    for (int f = 0; f < 96; ++f) acc += wr[f] * h1[bb][f];
    h2[bb][o] = acc;
  }
  __syncthreads();
  if (tid < 24) {
    int o = tid >> 2, bb = tid & 3;
    const float* wr = &f3w[o * 48];
    float acc = f3b[o];
    for (int f = 0; f < 48; ++f) acc += wr[f] * h2[bb][f];
    out[(size_t)(b0 + bb) * 6 + o] = acc;
  }
}

extern "C" void kernel_launch(void* const* d_in, const int* in_sizes, int n_in,
                              void* d_out, int out_size, void* d_ws, size_t ws_size,
                              hipStream_t stream) {
  const float* x   = (const float*)d_in[0];
  const float* w1  = (const float*)d_in[1];
  const float* w2  = (const float*)d_in[2];
  const float* w3  = (const float*)d_in[3];
  const float* w4  = (const float*)d_in[4];
  const float* g1  = (const float*)d_in[5];
  const float* b1  = (const float*)d_in[6];
  const float* g2  = (const float*)d_in[7];
  const float* b2  = (const float*)d_in[8];
  const float* g3  = (const float*)d_in[9];
  const float* b3  = (const float*)d_in[10];
  const float* g4  = (const float*)d_in[11];
  const float* b4  = (const float*)d_in[12];
  const float* f1w = (const float*)d_in[13];
  const float* f1b = (const float*)d_in[14];
  const float* f2w = (const float*)d_in[15];
  const float* f2b = (const float*)d_in[16];
  const float* f3w = (const float*)d_in[17];
  const float* f3b = (const float*)d_in[18];
  float* out = (float*)d_out;
  float* ws = (float*)d_ws;

  const int B = 4096;
  float* SUM1 = ws + 0;   float* SQ1 = ws + 12;
  float* SUM2 = ws + 24;  float* SQ2 = ws + 48;
  float* SUM3 = ws + 72;  float* SQ3 = ws + 120;
  float* SUM4 = ws + 168; float* SQ4 = ws + 264;
  float* SC1 = ws + 384;  float* SH1 = ws + 396;
  float* SC2 = ws + 408;  float* SH2 = ws + 432;
  float* SC3 = ws + 456;  float* SH3 = ws + 504;
  float* SC4 = ws + 552;  float* SH4 = ws + 648;
  float* R1 = ws + 1024;                    // B*5400 floats
  float* R2 = ws + 1024 + (size_t)B * 5400; // B*2016 floats
  float* R3 = ws + 1024;                    // aliases R1 (dead after stage2)
  float* R4 = ws + 1024 + (size_t)B * 720;  // B*288 floats

  hipMemsetAsync(d_ws, 0, 384 * sizeof(float), stream);

  k_lift<<<B / NB1, 256, 0, stream>>>(x, w1, R1, SUM1, SQ1);
  k_bnstat<<<1, 128, 0, stream>>>(SUM1, SQ1, g1, b1, SC1, SH1, 12, 1.0f / (float)(B * 450));
  k_stage2<<<(B + NB2 - 1) / NB2, 256, 0, stream>>>(R1, w2, SC1, SH1, R2, SUM2, SQ2, B);
  k_bnstat<<<1, 128, 0, stream>>>(SUM2, SQ2, g2, b2, SC2, SH2, 24, 1.0f / (float)(B * 84));
  k_stage3<<<B / NB3, 256, 0, stream>>>(R2, w3, SC2, SH2, R3, SUM3, SQ3);
  k_bnstat<<<1, 128, 0, stream>>>(SUM3, SQ3, g3, b3, SC3, SH3, 48, 1.0f / (float)(B * 15));
  k_stage4<<<B / NB4, 256, 0, stream>>>(R3, w4, SC3, SH3, R4, SUM4, SQ4);
  k_bnstat<<<1, 128, 0, stream>>>(SUM4, SQ4, g4, b4, SC4, SH4, 96, 1.0f / (float)(B * 3));
  k_fc<<<B / 4, 256, 0, stream>>>(R4, SC4, SH4, f1w, f1b, f2w, f2b, f3w, f3b, out);
}

// Round 3
// 904.804 us; speedup vs baseline: 3.0293x; 1.2963x over previous
//
#include <hip/hip_runtime.h>

#define EPSBN 2e-5f

__device__ __forceinline__ float lread(const float* __restrict__ p, int i, int n) {
  bool ok = (unsigned)i < (unsigned)n;
  float v = p[ok ? i : 0];
  return ok ? v : 0.f;
}

// ---------------- Stage 1: lift_conv + pool + relu + stats ----------------
// x: (B,100,6)  w1: (12,6,7)  out r1: (B,12,9,50) = relu(maxpool2(lift_conv/s))
#define NB1 4
__global__ __launch_bounds__(256) void k_lift(const float* __restrict__ x,
    const float* __restrict__ w1, float* __restrict__ r1,
    float* __restrict__ sum, float* __restrict__ sq) {
  __shared__ float xs[NB1][600];   // [c*100+t]
  __shared__ float ws[504];
  __shared__ float ssum[12], ssq[12];
  int b0 = blockIdx.x * NB1, tid = threadIdx.x;
  for (int i = tid; i < NB1 * 600; i += 256) {
    int bb = i / 600, f = i % 600;
    int t = f / 6, c = f % 6;
    xs[bb][c * 100 + t] = x[(size_t)(b0 + bb) * 600 + f];
  }
  for (int i = tid; i < 504; i += 256) ws[i] = w1[i];
  if (tid < 12) { ssum[tid] = 0.f; ssq[tid] = 0.f; }
  __syncthreads();
  // tasks: (bb, ot(6 x o-tile2), si(9), tc(10 x t-chunk10)) = NB1*540
  for (int task = tid; task < NB1 * 540; task += 256) {
    int bb = task / 540, rem = task % 540;
    int ot = rem / 90; rem %= 90;
    int si = rem / 10, tc = rem % 10;
    int o0 = ot * 2, t0 = tc * 10;
    int s = 1 << si;
    float inv = 1.0f / (float)s;
    float acc0[10], acc1[10];
#pragma unroll
    for (int k = 0; k < 10; ++k) { acc0[k] = 0.f; acc1[k] = 0.f; }
    const float* xb = xs[bb];
    for (int c = 0; c < 6; ++c) {
      const float* xr = xb + c * 100;
      const float* wr0 = ws + (o0 * 6 + c) * 7;
#pragma unroll
      for (int j = 0; j < 7; ++j) {
        int off = s * (j - 3) + t0;
        float w0 = wr0[j], w1v = wr0[j + 42];
#pragma unroll
        for (int k = 0; k < 10; ++k) {
          float av = lread(xr, off + k, 100);
          acc0[k] += av * w0;
          acc1[k] += av * w1v;
        }
      }
    }
    float s0 = 0.f, q0 = 0.f, s1 = 0.f, q1 = 0.f;
    size_t rb = ((size_t)(b0 + bb) * 12 + o0) * 9 + si;
#pragma unroll
    for (int u = 0; u < 5; ++u) {
      float v0 = fmaxf(fmaxf(acc0[2 * u], acc0[2 * u + 1]) * inv, 0.f);
      float v1 = fmaxf(fmaxf(acc1[2 * u], acc1[2 * u + 1]) * inv, 0.f);
      r1[rb * 50 + t0 / 2 + u] = v0;
      r1[(rb + 9) * 50 + t0 / 2 + u] = v1;
      s0 += v0; q0 += v0 * v0; s1 += v1; q1 += v1 * v1;
    }
    atomicAdd(&ssum[o0], s0); atomicAdd(&ssq[o0], q0);
    atomicAdd(&ssum[o0 + 1], s1); atomicAdd(&ssq[o0 + 1], q1);
  }
  __syncthreads();
  if (tid < 12) { atomicAdd(&sum[tid], ssum[tid]); atomicAdd(&sq[tid], ssq[tid]); }
}

// ---------------- BN stats -> scale/shift ----------------
__global__ void k_bnstat(const float* __restrict__ sum, const float* __restrict__ sq,
    const float* __restrict__ g, const float* __restrict__ bb,
    float* __restrict__ sc, float* __restrict__ sh, int C, float invN) {
  int c = threadIdx.x;
  if (c < C) {
    float m = sum[c] * invN;
    float v = sq[c] * invN - m * m;
    float scale = g[c] * rsqrtf(v + EPSBN);
    sc[c] = scale;
    sh[c] = bb[c] - m * scale;
  }
}

// ---------------- Stage 2: BN1-affine + pool + gg_conv(w2) + pool + relu + stats ----
// r1: (B,12,9,50) -> a(12,9,25); w2: (24,12,3,5); out r2: (B,24,7,12)
// ws re-laid out as [12 o-pairs][361] (pad: 361%32=9 -> distinct banks across ot)
#define NB2 3
__global__ __launch_bounds__(256) void k_stage2(const float* __restrict__ r1,
    const float* __restrict__ w2, const float* __restrict__ sc, const float* __restrict__ sh,
    float* __restrict__ r2, float* __restrict__ sum, float* __restrict__ sq, int B) {
  __shared__ float as[NB2][2700];  // (c*9+si)*25+x
  __shared__ float ws[12 * 361];
  __shared__ float ssum[24], ssq[24];
  int b0 = blockIdx.x * NB2, tid = threadIdx.x;
  for (int i = tid; i < NB2 * 2700; i += 256) {
    int bb = i / 2700, f = i % 2700;
    if (b0 + bb < B) {
      const float2* src = (const float2*)(r1 + (size_t)(b0 + bb) * 5400);
      float2 p = src[f];
      int c = f / 225;
      as[bb][f] = fmaxf(p.x, p.y) * sc[c] + sh[c];
    }
  }
  for (int i = tid; i < 4320; i += 256) {
    int ot = i / 360, r = i % 360;
    ws[ot * 361 + r] = w2[i];
  }
  if (tid < 24) { ssum[tid] = 0.f; ssq[tid] = 0.f; }
  __syncthreads();
  // tasks: (bb, ot(12 x o-tile2), i2(7)) = NB2*84
  for (int task = tid; task < NB2 * 84; task += 256) {
    int bb = task / 84, rem = task % 84;
    if (b0 + bb >= B) continue;
    int ot = rem / 7, i2 = rem % 7;
    int s = 1 << i2;
    float inv = 1.0f / (float)s;
    float acc0[24], acc1[24];
#pragma unroll
    for (int t = 0; t < 24; ++t) { acc0[t] = 0.f; acc1[t] = 0.f; }
    for (int c = 0; c < 12; ++c) {
#pragma unroll
      for (int h = 0; h < 3; ++h) {
        const float* ar = as[bb] + (c * 9 + i2 + h) * 25;
        const float* wr = ws + ot * 361 + (c * 3 + h) * 5;
#pragma unroll
        for (int j = 0; j < 5; ++j) {
          int off = s * (j - 2);
          float w0 = wr[j], w1v = wr[j + 180];
#pragma unroll
          for (int t = 0; t < 24; ++t) {
            float av = lread(ar, t + off, 25);
            acc0[t] += av * w0;
            acc1[t] += av * w1v;
          }
        }
      }
    }
    int o0 = ot * 2;
    float s0 = 0.f, q0 = 0.f, s1 = 0.f, q1 = 0.f;
    size_t rb = ((size_t)(b0 + bb) * 24 + o0) * 84 + i2 * 12;
#pragma unroll
    for (int u = 0; u < 12; ++u) {
      float v0 = fmaxf(fmaxf(acc0[2 * u], acc0[2 * u + 1]) * inv, 0.f);
      float v1 = fmaxf(fmaxf(acc1[2 * u], acc1[2 * u + 1]) * inv, 0.f);
      r2[rb + u] = v0;
      r2[rb + 84 + u] = v1;
      s0 += v0; q0 += v0 * v0; s1 += v1; q1 += v1 * v1;
    }
    atomicAdd(&ssum[o0], s0); atomicAdd(&ssq[o0], q0);
    atomicAdd(&ssum[o0 + 1], s1); atomicAdd(&ssq[o0 + 1], q1);
  }
  __syncthreads();
  if (tid < 24) { atomicAdd(&sum[tid], ssum[tid]); atomicAdd(&sq[tid], ssq[tid]); }
}

// ---------------- Stage 3: BN2-affine + pool + gg_conv(w3) + pool + relu + stats ----
// r2: (B,24,7,12) -> a(24,7,6); w3: (48,24,3,5); out r3: (B,48,5,3)
// pads: as rows 1008->1009 (bb*17 mod 32 distinct), ws rows 1440->1441 (ot distinct)
#define NB3 8
__global__ __launch_bounds__(256) void k_stage3(const float* __restrict__ r2,
    const float* __restrict__ w3, const float* __restrict__ sc, const float* __restrict__ sh,
    float* __restrict__ r3, float* __restrict__ sum, float* __restrict__ sq) {
  __shared__ float as[NB3 * 1009];  // bb*1009 + (c*7+i2)*6+x
  __shared__ float ws[6 * 1441];    // 24-o chunk: [6 o-quads][1441]
  __shared__ float ssum[48], ssq[48];
  int b0 = blockIdx.x * NB3, tid = threadIdx.x;
  for (int i = tid; i < NB3 * 1008; i += 256) {
    int bb = i / 1008, f = i % 1008;
    const float2* src = (const float2*)(r2 + (size_t)(b0 + bb) * 2016);
    float2 p = src[f];
    int c = f / 42;
    as[bb * 1009 + f] = fmaxf(p.x, p.y) * sc[c] + sh[c];
  }
  if (tid < 48) { ssum[tid] = 0.f; ssq[tid] = 0.f; }
  for (int chunk = 0; chunk < 2; ++chunk) {
    __syncthreads();
    for (int i = tid; i < 8640; i += 256) {
      int ot = i / 1440, r = i % 1440;
      ws[ot * 1441 + r] = w3[chunk * 8640 + i];
    }
    __syncthreads();
    // tasks: (bb, ot(6 x o-tile4), i2(5)) = 240
    for (int task = tid; task < NB3 * 30; task += 256) {
      int bb = task / 30, rem = task % 30;
      int ot = rem / 5, i2 = rem % 5;
      int s = 1 << i2;
      float inv = 1.0f / (float)s;
      float acc[4][6];
#pragma unroll
      for (int oo = 0; oo < 4; ++oo)
#pragma unroll
        for (int t = 0; t < 6; ++t) acc[oo][t] = 0.f;
      for (int c = 0; c < 24; ++c) {
#pragma unroll
        for (int h = 0; h < 3; ++h) {
          const float* ar = as + bb * 1009 + (c * 7 + i2 + h) * 6;
          const float* wr = ws + ot * 1441 + (c * 3 + h) * 5;
#pragma unroll
          for (int j = 0; j < 5; ++j) {
            int off = s * (j - 2);
            float w0 = wr[j], w1 = wr[j + 360], w2v = wr[j + 720], w3v = wr[j + 1080];
#pragma unroll
            for (int t = 0; t < 6; ++t) {
              float av = lread(ar, t + off, 6);
              acc[0][t] += av * w0;
              acc[1][t] += av * w1;
              acc[2][t] += av * w2v;
              acc[3][t] += av * w3v;
            }
          }
        }
      }
      int ob = chunk * 24 + ot * 4;
#pragma unroll
      for (int oo = 0; oo < 4; ++oo) {
        float ss = 0.f, qq = 0.f;
        size_t rb = ((size_t)(b0 + bb) * 48 + ob + oo) * 15 + i2 * 3;
#pragma unroll
        for (int u = 0; u < 3; ++u) {
          float v = fmaxf(fmaxf(acc[oo][2 * u], acc[oo][2 * u + 1]) * inv, 0.f);
          r3[rb + u] = v;
          ss += v; qq += v * v;
        }
        atomicAdd(&ssum[ob + oo], ss); atomicAdd(&ssq[ob + oo], qq);
      }
    }
  }
  __syncthreads();
  if (tid < 48) { atomicAdd(&sum[tid], ssum[tid]); atomicAdd(&sq[tid], ssq[tid]); }
}

// ---------------- Stage 4: BN3-affine + gg_conv(w4) + pool + relu + stats ----------
// r3: (B,48,5,3); w4: (96,48,3,3); out r4: (B,96,3)
// pads: as rows 720->721 (bb*17 mod 32 distinct), ws rows 864->865 (ot distinct)
#define NB4 8
__global__ __launch_bounds__(256) void k_stage4(const float* __restrict__ r3,
    const float* __restrict__ w4, const float* __restrict__ sc, const float* __restrict__ sh,
    float* __restrict__ r4, float* __restrict__ sum, float* __restrict__ sq) {
  __shared__ float as[NB4 * 721];   // bb*721 + (c*5+i2)*3+x
  __shared__ float ws[12 * 865];    // 24-o chunk: [12 o-pairs][865]
  __shared__ float ssum[96], ssq[96];
  int b0 = blockIdx.x * NB4, tid = threadIdx.x;
  for (int i = tid; i < NB4 * 720; i += 256) {
    int bb = i / 720, f = i % 720, c = f / 15;
    as[bb * 721 + f] = r3[(size_t)(b0 + bb) * 720 + f] * sc[c] + sh[c];
  }
  if (tid < 96) { ssum[tid] = 0.f; ssq[tid] = 0.f; }
  for (int chunk = 0; chunk < 4; ++chunk) {
    __syncthreads();
    for (int i = tid; i < 10368; i += 256) {
      int ot = i / 864, r = i % 864;
      ws[ot * 865 + r] = w4[chunk * 10368 + i];
    }
    __syncthreads();
    // tasks: (bb, ot(12 x o-tile2), i2(3)) = 288
    for (int task = tid; task < NB4 * 36; task += 256) {
      int bb = task / 36, rem = task % 36;
      int ot = rem / 3, i2 = rem % 3;
      int s = 1 << i2;
      float inv = 1.0f / (float)s;
      float acc[2][2];
      acc[0][0] = acc[0][1] = acc[1][0] = acc[1][1] = 0.f;
      for (int c = 0; c < 48; ++c) {
#pragma unroll
        for (int h = 0; h < 3; ++h) {
          const float* ar = as + bb * 721 + (c * 5 + i2 + h) * 3;
          const float* wr = ws + ot * 865 + (c * 3 + h) * 3;
#pragma unroll
          for (int j = 0; j < 3; ++j) {
            int off = s * (j - 1);
            float w0 = wr[j], w1 = wr[j + 432];
#pragma unroll
            for (int t = 0; t < 2; ++t) {
              float av = lread(ar, t + off, 3);
              acc[0][t] += av * w0;
              acc[1][t] += av * w1;
            }
          }
        }
      }
      int ob = chunk * 24 + ot * 2;
#pragma unroll
      for (int oo = 0; oo < 2; ++oo) {
        float v = fmaxf(fmaxf(acc[oo][0], acc[oo][1]) * inv, 0.f);
        r4[(size_t)(b0 + bb) * 288 + (ob + oo) * 3 + i2] = v;
        atomicAdd(&ssum[ob + oo], v); atomicAdd(&ssq[ob + oo], v * v);
      }
    }
  }
  __syncthreads();
  if (tid < 96) { atomicAdd(&sum[tid], ssum[tid]); atomicAdd(&sq[tid], ssq[tid]); }
}

// ---------------- FC head: BN4-affine + 288->96->48->6 ----------------
__global__ __launch_bounds__(256) void k_fc(const float* __restrict__ r4,
    const float* __restrict__ sc, const float* __restrict__ sh,
    const float* __restrict__ f1w, const float* __restrict__ f1b,
    const float* __restrict__ f2w, const float* __restrict__ f2b,
    const float* __restrict__ f3w, const float* __restrict__ f3b,
    float* __restrict__ out) {
  __shared__ float v[4][288];
  __shared__ float h1[4][96];
  __shared__ float h2[4][48];
  int b0 = blockIdx.x * 4, tid = threadIdx.x;
  for (int i = tid; i < 4 * 288; i += 256) {
    int bb = i / 288, f = i % 288, c = f / 3;
    v[bb][f] = r4[(size_t)(b0 + bb) * 288 + f] * sc[c] + sh[c];
  }
  __syncthreads();
  for (int d = tid; d < 384; d += 256) {
    int o = d >> 2, bb = d & 3;
    const float* wr = &f1w[o * 288];
    const float* vv = v[bb];
    float acc = f1b[o];
    for (int f = 0; f < 288; ++f) acc += wr[f] * vv[f];
    h1[bb][o] = acc;
  }
  __syncthreads();
  if (tid < 192) {
    int o = tid >> 2, bb = tid & 3;
    const float* wr = &f2w[o * 96];
    float acc = f2b[o];
    for (int f = 0; f < 96; ++f) acc += wr[f] * h1[bb][f];
    h2[bb][o] = acc;
  }
  __syncthreads();
  if (tid < 24) {
    int o = tid >> 2, bb = tid & 3;
    const float* wr = &f3w[o * 48];
    float acc = f3b[o];
    for (int f = 0; f < 48; ++f) acc += wr[f] * h2[bb][f];
    out[(size_t)(b0 + bb) * 6 + o] = acc;
  }
}

extern "C" void kernel_launch(void* const* d_in, const int* in_sizes, int n_in,
                              void* d_out, int out_size, void* d_ws, size_t ws_size,
                              hipStream_t stream) {
  const float* x   = (const float*)d_in[0];
  const float* w1  = (const float*)d_in[1];
  const float* w2  = (const float*)d_in[2];
  const float* w3  = (const float*)d_in[3];
  const float* w4  = (const float*)d_in[4];
  const float* g1  = (const float*)d_in[5];
  const float* b1  = (const float*)d_in[6];
  const float* g2  = (const float*)d_in[7];
  const float* b2  = (const float*)d_in[8];
  const float* g3  = (const float*)d_in[9];
  const float* b3  = (const float*)d_in[10];
  const float* g4  = (const float*)d_in[11];
  const float* b4  = (const float*)d_in[12];
  const float* f1w = (const float*)d_in[13];
  const float* f1b = (const float*)d_in[14];
  const float* f2w = (const float*)d_in[15];
  const float* f2b = (const float*)d_in[16];
  const float* f3w = (const float*)d_in[17];
  const float* f3b = (const float*)d_in[18];
  float* out = (float*)d_out;
  float* ws = (float*)d_ws;

  const int B = 4096;
  float* SUM1 = ws + 0;   float* SQ1 = ws + 12;
  float* SUM2 = ws + 24;  float* SQ2 = ws + 48;
  float* SUM3 = ws + 72;  float* SQ3 = ws + 120;
  float* SUM4 = ws + 168; float* SQ4 = ws + 264;
  float* SC1 = ws + 384;  float* SH1 = ws + 396;
  float* SC2 = ws + 408;  float* SH2 = ws + 432;
  float* SC3 = ws + 456;  float* SH3 = ws + 504;
  float* SC4 = ws + 552;  float* SH4 = ws + 648;
  float* R1 = ws + 1024;                    // B*5400 floats
  float* R2 = ws + 1024 + (size_t)B * 5400; // B*2016 floats
  float* R3 = ws + 1024;                    // aliases R1 (dead after stage2)
  float* R4 = ws + 1024 + (size_t)B * 720;  // B*288 floats

  hipMemsetAsync(d_ws, 0, 384 * sizeof(float), stream);

  k_lift<<<B / NB1, 256, 0, stream>>>(x, w1, R1, SUM1, SQ1);
  k_bnstat<<<1, 128, 0, stream>>>(SUM1, SQ1, g1, b1, SC1, SH1, 12, 1.0f / (float)(B * 450));
  k_stage2<<<(B + NB2 - 1) / NB2, 256, 0, stream>>>(R1, w2, SC1, SH1, R2, SUM2, SQ2, B);
  k_bnstat<<<1, 128, 0, stream>>>(SUM2, SQ2, g2, b2, SC2, SH2, 24, 1.0f / (float)(B * 84));
  k_stage3<<<B / NB3, 256, 0, stream>>>(R2, w3, SC2, SH2, R3, SUM3, SQ3);
  k_bnstat<<<1, 128, 0, stream>>>(SUM3, SQ3, g3, b3, SC3, SH3, 48, 1.0f / (float)(B * 15));
  k_stage4<<<B / NB4, 256, 0, stream>>>(R3, w4, SC3, SH3, R4, SUM4, SQ4);
  k_bnstat<<<1, 128, 0, stream>>>(SUM4, SQ4, g4, b4, SC4, SH4, 96, 1.0f / (float)(B * 3));
  k_fc<<<B / 4, 256, 0, stream>>>(R4, SC4, SH4, f1w, f1b, f2w, f2b, f3w, f3b, out);
}

// Round 4
// 654.902 us; speedup vs baseline: 4.1853x; 1.3816x over previous
//
#include <hip/hip_runtime.h>

#define EPSBN 2e-5f

// ============================ Stage 1: lift ============================
// x:(B,100,6) w1:(12,6,7) -> r1:(B,12,9,50) = relu(maxpool2(lift_conv/s))
// lanes: ot(6 o-pairs) x tc(10 t-chunks of 10);  waves own scale lists.
template<int S, int SI>
__device__ __forceinline__ void s1_do(const float* __restrict__ xs,
    const float* __restrict__ ws, bool act, int t0, int o0, int b,
    float* __restrict__ r1, float* __restrict__ ssum, float* __restrict__ ssq) {
  float acc0[10], acc1[10];
#pragma unroll
  for (int k = 0; k < 10; ++k) { acc0[k] = 0.f; acc1[k] = 0.f; }
  for (int c = 0; c < 6; ++c) {
    const float* xr = xs + c * 100;
    const float* wr = ws + o0 * 42 + c * 7;
#pragma unroll
    for (int j = 0; j < 7; ++j) {
      const int off = S * (j - 3);
      if (off <= -100 || off >= 100) continue;  // compile-time dead tap
      float w0 = wr[j], w1v = wr[j + 42];
      int base = t0 + off;
      if (base >= 0 && base + 9 < 100) {
        const float* xp = xr + base;
#pragma unroll
        for (int k = 0; k < 10; ++k) {
          float av = xp[k];
          acc0[k] += av * w0; acc1[k] += av * w1v;
        }
      } else if (base <= 99 && base + 9 >= 0) {
#pragma unroll
        for (int k = 0; k < 10; ++k) {
          int tt = base + k;
          if ((unsigned)tt < 100u) {
            float av = xr[tt];
            acc0[k] += av * w0; acc1[k] += av * w1v;
          }
        }
      }
    }
  }
  if (act) {
    const float inv = 1.0f / (float)S;
    float s0 = 0.f, q0 = 0.f, s1 = 0.f, q1 = 0.f;
    size_t rb = ((size_t)b * 12 + o0) * 9 + SI;
#pragma unroll
    for (int u = 0; u < 5; ++u) {
      float v0 = fmaxf(fmaxf(acc0[2 * u], acc0[2 * u + 1]) * inv, 0.f);
      float v1 = fmaxf(fmaxf(acc1[2 * u], acc1[2 * u + 1]) * inv, 0.f);
      r1[rb * 50 + (t0 >> 1) + u] = v0;
      r1[(rb + 9) * 50 + (t0 >> 1) + u] = v1;
      s0 += v0; q0 += v0 * v0; s1 += v1; q1 += v1 * v1;
    }
    atomicAdd(&ssum[o0], s0); atomicAdd(&ssq[o0], q0);
    atomicAdd(&ssum[o0 + 1], s1); atomicAdd(&ssq[o0 + 1], q1);
  }
}

__global__ __launch_bounds__(256) void k_lift(const float* __restrict__ x,
    const float* __restrict__ w1, float* __restrict__ r1,
    float* __restrict__ sum, float* __restrict__ sq) {
  __shared__ float xs[600];
  __shared__ float ws[504];
  __shared__ float ssum[12], ssq[12];
  int b = blockIdx.x, tid = threadIdx.x;
  for (int i = tid; i < 600; i += 256) {
    int t = i / 6, c = i % 6;
    xs[c * 100 + t] = x[(size_t)b * 600 + i];
  }
  for (int i = tid; i < 504; i += 256) ws[i] = w1[i];
  if (tid < 12) { ssum[tid] = 0.f; ssq[tid] = 0.f; }
  __syncthreads();
  int wv = tid >> 6, lane = tid & 63;
  int ot = lane / 10, tc = lane % 10;       // ot<6 valid
  bool base_act = lane < 60;
  if (ot > 5) ot = 5;
  int o0 = ot * 2, t0 = tc * 10;
  // schedule: w0{s=1, s=16 lo}, w1{s=2, s=16 hi}, w2{s=4, s=32}, w3{s=8,64,128,256}
  if (wv == 0) {
    s1_do<1, 0>(xs, ws, base_act, t0, o0, b, r1, ssum, ssq);
    s1_do<16, 4>(xs, ws, base_act && tc < 5, t0, o0, b, r1, ssum, ssq);
  } else if (wv == 1) {
    s1_do<2, 1>(xs, ws, base_act, t0, o0, b, r1, ssum, ssq);
    s1_do<16, 4>(xs, ws, base_act && tc >= 5, t0, o0, b, r1, ssum, ssq);
  } else if (wv == 2) {
    s1_do<4, 2>(xs, ws, base_act, t0, o0, b, r1, ssum, ssq);
    s1_do<32, 5>(xs, ws, base_act, t0, o0, b, r1, ssum, ssq);
  } else {
    s1_do<8, 3>(xs, ws, base_act, t0, o0, b, r1, ssum, ssq);
    s1_do<64, 6>(xs, ws, base_act, t0, o0, b, r1, ssum, ssq);
    s1_do<128, 7>(xs, ws, base_act, t0, o0, b, r1, ssum, ssq);
    s1_do<256, 8>(xs, ws, base_act, t0, o0, b, r1, ssum, ssq);
  }
  __syncthreads();
  if (tid < 12) { atomicAdd(&sum[tid], ssum[tid]); atomicAdd(&sq[tid], ssq[tid]); }
}

// ---------------- BN stats -> scale/shift ----------------
__global__ void k_bnstat(const float* __restrict__ sum, const float* __restrict__ sq,
    const float* __restrict__ g, const float* __restrict__ bb,
    float* __restrict__ sc, float* __restrict__ sh, int C, float invN) {
  int c = threadIdx.x;
  if (c < C) {
    float m = sum[c] * invN;
    float v = sq[c] * invN - m * m;
    float scale = g[c] * rsqrtf(v + EPSBN);
    sc[c] = scale;
    sh[c] = bb[c] - m * scale;
  }
}

// ============================ Stage 2 ============================
// r1:(B,12,9,50) -pool-> a(12,9,25); w2:(24,12,3,5); out r2:(B,24,7,12)
// lanes: bb(5) x ot(12 o-pairs). waves own i2 lists (balanced by valid terms).
#define NB2 5
template<int S, int I2>
__device__ __forceinline__ void s2_do(const float* __restrict__ ab,
    const float* __restrict__ wb, bool act, int b, int o0,
    float* __restrict__ r2, float* __restrict__ ssum, float* __restrict__ ssq) {
  float acc0[24], acc1[24];
#pragma unroll
  for (int t = 0; t < 24; ++t) { acc0[t] = 0.f; acc1[t] = 0.f; }
  for (int c = 0; c < 12; ++c) {
#pragma unroll
    for (int h = 0; h < 3; ++h) {
      const float* ar = ab + (c * 9 + I2 + h) * 25;
      const float* wr = wb + (c * 3 + h) * 5;
#pragma unroll
      for (int j = 0; j < 5; ++j) {
        const int off = S * (j - 2);
        if (off <= -25 || off >= 25) continue;
        float w0 = wr[j], w1v = wr[j + 180];
#pragma unroll
        for (int t = 0; t < 24; ++t) {
          if (t + off >= 0 && t + off < 25) {
            float av = ar[t + off];
            acc0[t] += av * w0; acc1[t] += av * w1v;
          }
        }
      }
    }
  }
  if (act) {
    const float inv = 1.0f / (float)S;
    float s0 = 0.f, q0 = 0.f, s1 = 0.f, q1 = 0.f;
    size_t rb = ((size_t)b * 24 + o0) * 84 + I2 * 12;
#pragma unroll
    for (int u = 0; u < 12; ++u) {
      float v0 = fmaxf(fmaxf(acc0[2 * u], acc0[2 * u + 1]) * inv, 0.f);
      float v1 = fmaxf(fmaxf(acc1[2 * u], acc1[2 * u + 1]) * inv, 0.f);
      r2[rb + u] = v0;
      r2[rb + 84 + u] = v1;
      s0 += v0; q0 += v0 * v0; s1 += v1; q1 += v1 * v1;
    }
    atomicAdd(&ssum[o0], s0); atomicAdd(&ssq[o0], q0);
    atomicAdd(&ssum[o0 + 1], s1); atomicAdd(&ssq[o0 + 1], q1);
  }
}

__global__ __launch_bounds__(256) void k_stage2(const float* __restrict__ r1,
    const float* __restrict__ w2, const float* __restrict__ sc, const float* __restrict__ sh,
    float* __restrict__ r2, float* __restrict__ sum, float* __restrict__ sq, int B) {
  __shared__ float as[NB2 * 2701];   // stride 2701 (mod32=13: bb banks distinct)
  __shared__ float ws[12 * 361];     // stride 361 (mod32=9: ot banks distinct)
  __shared__ float ssum[24], ssq[24];
  int b0 = blockIdx.x * NB2, tid = threadIdx.x;
  for (int i = tid; i < NB2 * 2700; i += 256) {
    int bb = i / 2700, f = i % 2700;
    if (b0 + bb < B) {
      float2 p = ((const float2*)(r1 + (size_t)(b0 + bb) * 5400))[f];
      int c = f / 225;
      as[bb * 2701 + f] = fmaxf(p.x, p.y) * sc[c] + sh[c];
    }
  }
  for (int i = tid; i < 4320; i += 256) {
    int ot = i / 360, r = i % 360;
    ws[ot * 361 + r] = w2[i];
  }
  if (tid < 24) { ssum[tid] = 0.f; ssq[tid] = 0.f; }
  __syncthreads();
  int wv = tid >> 6, lane = tid & 63;
  int bb = lane / 12, ot = lane % 12;  // bb<5 valid
  bool act = (lane < 60) && (b0 + bb < B);
  if (bb > NB2 - 1) bb = NB2 - 1;
  const float* ab = as + bb * 2701;
  const float* wb = ws + ot * 361;
  int b = b0 + bb, o0 = ot * 2;
  // schedule (valid-term counts): w0{i2=0}=116, w1{1,6}=134, w2{2,5}=122, w3{3,4}=115
  if (wv == 0) {
    s2_do<1, 0>(ab, wb, act, b, o0, r2, ssum, ssq);
  } else if (wv == 1) {
    s2_do<2, 1>(ab, wb, act, b, o0, r2, ssum, ssq);
    s2_do<64, 6>(ab, wb, act, b, o0, r2, ssum, ssq);
  } else if (wv == 2) {
    s2_do<4, 2>(ab, wb, act, b, o0, r2, ssum, ssq);
    s2_do<32, 5>(ab, wb, act, b, o0, r2, ssum, ssq);
  } else {
    s2_do<8, 3>(ab, wb, act, b, o0, r2, ssum, ssq);
    s2_do<16, 4>(ab, wb, act, b, o0, r2, ssum, ssq);
  }
  __syncthreads();
  if (tid < 24) { atomicAdd(&sum[tid], ssum[tid]); atomicAdd(&sq[tid], ssq[tid]); }
}

// ============================ Stage 3 ============================
// r2:(B,24,7,12) -pool-> a(24,7,6); w3:(48,24,3,5); out r3:(B,48,5,3)
// lanes: bb(10) x ot(6 o-quads of chunk); 2 weight chunks of 24 o sequential.
#define NB3 10
template<int S, int I2>
__device__ __forceinline__ void s3_do(const float* __restrict__ ab,
    const float* __restrict__ wb, bool act, int b, int obase,
    float* __restrict__ r3, float* __restrict__ ssum, float* __restrict__ ssq) {
  float acc[4][6];
#pragma unroll
  for (int oo = 0; oo < 4; ++oo)
#pragma unroll
    for (int t = 0; t < 6; ++t) acc[oo][t] = 0.f;
  for (int c = 0; c < 24; ++c) {
#pragma unroll
    for (int h = 0; h < 3; ++h) {
      const float* ar = ab + (c * 7 + I2 + h) * 6;
      const float* wr = wb + (c * 3 + h) * 5;
#pragma unroll
      for (int j = 0; j < 5; ++j) {
        const int off = S * (j - 2);
        if (off <= -6 || off >= 6) continue;
        float w0 = wr[j], w1 = wr[j + 360], w2v = wr[j + 720], w3v = wr[j + 1080];
#pragma unroll
        for (int t = 0; t < 6; ++t) {
          if (t + off >= 0 && t + off < 6) {
            float av = ar[t + off];
            acc[0][t] += av * w0; acc[1][t] += av * w1;
            acc[2][t] += av * w2v; acc[3][t] += av * w3v;
          }
        }
      }
    }
  }
  if (act) {
    const float inv = 1.0f / (float)S;
#pragma unroll
    for (int oo = 0; oo < 4; ++oo) {
      float ss = 0.f, qq = 0.f;
      size_t rb = ((size_t)b * 48 + obase + oo) * 15 + I2 * 3;
#pragma unroll
      for (int u = 0; u < 3; ++u) {
        float v = fmaxf(fmaxf(acc[oo][2 * u], acc[oo][2 * u + 1]) * inv, 0.f);
        r3[rb + u] = v;
        ss += v; qq += v * v;
      }
      atomicAdd(&ssum[obase + oo], ss); atomicAdd(&ssq[obase + oo], qq);
    }
  }
}

__global__ __launch_bounds__(256) void k_stage3(const float* __restrict__ r2,
    const float* __restrict__ w3, const float* __restrict__ sc, const float* __restrict__ sh,
    float* __restrict__ r3, float* __restrict__ sum, float* __restrict__ sq, int B) {
  __shared__ float as[NB3 * 1009];   // stride mod32=17: bb banks distinct
  __shared__ float ws[6 * 1441];     // stride mod32=1: ot banks distinct
  __shared__ float ssum[48], ssq[48];
  int b0 = blockIdx.x * NB3, tid = threadIdx.x;
  for (int i = tid; i < NB3 * 1008; i += 256) {
    int bb = i / 1008, f = i % 1008;
    if (b0 + bb < B) {
      float2 p = ((const float2*)(r2 + (size_t)(b0 + bb) * 2016))[f];
      int c = f / 42;
      as[bb * 1009 + f] = fmaxf(p.x, p.y) * sc[c] + sh[c];
    }
  }
  if (tid < 48) { ssum[tid] = 0.f; ssq[tid] = 0.f; }
  int wv = tid >> 6, lane = tid & 63;
  int bb = lane / 6, ot = lane % 6;  // bb<10 valid
  bool act = (lane < 60) && (b0 + bb < B);
  if (bb > NB3 - 1) bb = NB3 - 1;
  const float* ab = as + bb * 1009;
  const float* wb = ws + ot * 1441;
  int b = b0 + bb;
  for (int chunk = 0; chunk < 2; ++chunk) {
    __syncthreads();
    for (int i = tid; i < 8640; i += 256) {
      int o4 = i / 1440, r = i % 1440;
      ws[o4 * 1441 + r] = w3[chunk * 8640 + i];
    }
    __syncthreads();
    int obase = chunk * 24 + ot * 4;
    // schedule (valid terms): w0{0}=24, w1{1}=18, w2{2,3}=16, w3{4}=6
    if (wv == 0) {
      s3_do<1, 0>(ab, wb, act, b, obase, r3, ssum, ssq);
    } else if (wv == 1) {
      s3_do<2, 1>(ab, wb, act, b, obase, r3, ssum, ssq);
    } else if (wv == 2) {
      s3_do<4, 2>(ab, wb, act, b, obase, r3, ssum, ssq);
      s3_do<8, 3>(ab, wb, act, b, obase, r3, ssum, ssq);
    } else {
      s3_do<16, 4>(ab, wb, act, b, obase, r3, ssum, ssq);
    }
  }
  __syncthreads();
  if (tid < 48) { atomicAdd(&sum[tid], ssum[tid]); atomicAdd(&sq[tid], ssq[tid]); }
}

// ============================ Stage 4 ============================
// r3:(B,48,5,3); w4:(96,48,3,3); out r4:(B,96,3)
// lanes: bb(8) x ot(8 o-triples of chunk); 4 weight chunks of 24 o sequential.
#define NB4 8
template<int S, int I2>
__device__ __forceinline__ void s4_do(const float* __restrict__ ab,
    const float* __restrict__ wb, bool act, int b, int obase,
    float* __restrict__ r4, float* __restrict__ ssum, float* __restrict__ ssq) {
  float acc[3][2];
#pragma unroll
  for (int oo = 0; oo < 3; ++oo) { acc[oo][0] = 0.f; acc[oo][1] = 0.f; }
  for (int c = 0; c < 48; ++c) {
#pragma unroll
    for (int h = 0; h < 3; ++h) {
      const float* ar = ab + (c * 5 + I2 + h) * 3;
      const float* wr = wb + (c * 3 + h) * 3;
#pragma unroll
      for (int j = 0; j < 3; ++j) {
        const int off = S * (j - 1);
        if (off <= -3 || off >= 3) continue;
        float w0 = wr[j], w1 = wr[j + 432], w2v = wr[j + 864];
#pragma unroll
        for (int t = 0; t < 2; ++t) {
          if (t + off >= 0 && t + off < 3) {
            float av = ar[t + off];
            acc[0][t] += av * w0; acc[1][t] += av * w1; acc[2][t] += av * w2v;
          }
        }
      }
    }
  }
  if (act) {
    const float inv = 1.0f / (float)S;
#pragma unroll
    for (int oo = 0; oo < 3; ++oo) {
      float v = fmaxf(fmaxf(acc[oo][0], acc[oo][1]) * inv, 0.f);
      r4[(size_t)b * 288 + (obase + oo) * 3 + I2] = v;
      atomicAdd(&ssum[obase + oo], v); atomicAdd(&ssq[obase + oo], v * v);
    }
  }
}

__global__ __launch_bounds__(256) void k_stage4(const float* __restrict__ r3,
    const float* __restrict__ w4, const float* __restrict__ sc, const float* __restrict__ sh,
    float* __restrict__ r4, float* __restrict__ sum, float* __restrict__ sq) {
  __shared__ float as[NB4 * 721];    // stride mod32=17
  __shared__ float ws[8 * 1297];     // stride mod32=17
  __shared__ float ssum[96], ssq[96];
  int b0 = blockIdx.x * NB4, tid = threadIdx.x;
  for (int i = tid; i < NB4 * 720; i += 256) {
    int bb = i / 720, f = i % 720, c = f / 15;
    as[bb * 721 + f] = r3[(size_t)(b0 + bb) * 720 + f] * sc[c] + sh[c];
  }
  if (tid < 96) { ssum[tid] = 0.f; ssq[tid] = 0.f; }
  int wv = tid >> 6, lane = tid & 63;
  int bb = lane / 8, ot = lane % 8;
  const float* ab = as + bb * 721;
  const float* wb = ws + ot * 1297;
  int b = b0 + bb;
  for (int chunk = 0; chunk < 4; ++chunk) {
    __syncthreads();
    for (int i = tid; i < 10368; i += 256) {
      int o3 = i / 1296, r = i % 1296;
      ws[o3 * 1297 + r] = w4[chunk * 10368 + i];
    }
    __syncthreads();
    int obase = chunk * 24 + ot * 3;
    // schedule: w0{i2=0}, w1{1}, w2{2}, w3 idle
    if (wv == 0) {
      s4_do<1, 0>(ab, wb, true, b, obase, r4, ssum, ssq);
    } else if (wv == 1) {
      s4_do<2, 1>(ab, wb, true, b, obase, r4, ssum, ssq);
    } else if (wv == 2) {
      s4_do<4, 2>(ab, wb, true, b, obase, r4, ssum, ssq);
    }
  }
  __syncthreads();
  if (tid < 96) { atomicAdd(&sum[tid], ssum[tid]); atomicAdd(&sq[tid], ssq[tid]); }
}

// ---------------- FC head: BN4-affine + 288->96->48->6 ----------------
__global__ __launch_bounds__(256) void k_fc(const float* __restrict__ r4,
    const float* __restrict__ sc, const float* __restrict__ sh,
    const float* __restrict__ f1w, const float* __restrict__ f1b,
    const float* __restrict__ f2w, const float* __restrict__ f2b,
    const float* __restrict__ f3w, const float* __restrict__ f3b,
    float* __restrict__ out) {
  __shared__ float v[4][288];
  __shared__ float h1[4][96];
  __shared__ float h2[4][48];
  int b0 = blockIdx.x * 4, tid = threadIdx.x;
  for (int i = tid; i < 4 * 288; i += 256) {
    int bb = i / 288, f = i % 288, c = f / 3;
    v[bb][f] = r4[(size_t)(b0 + bb) * 288 + f] * sc[c] + sh[c];
  }
  __syncthreads();
  for (int d = tid; d < 384; d += 256) {
    int o = d >> 2, bb = d & 3;
    const float* wr = &f1w[o * 288];
    const float* vv = v[bb];
    float acc = f1b[o];
    for (int f = 0; f < 288; ++f) acc += wr[f] * vv[f];
    h1[bb][o] = acc;
  }
  __syncthreads();
  if (tid < 192) {
    int o = tid >> 2, bb = tid & 3;
    const float* wr = &f2w[o * 96];
    float acc = f2b[o];
    for (int f = 0; f < 96; ++f) acc += wr[f] * h1[bb][f];
    h2[bb][o] = acc;
  }
  __syncthreads();
  if (tid < 24) {
    int o = tid >> 2, bb = tid & 3;
    const float* wr = &f3w[o * 48];
    float acc = f3b[o];
    for (int f = 0; f < 48; ++f) acc += wr[f] * h2[bb][f];
    out[(size_t)(b0 + bb) * 6 + o] = acc;
  }
}

extern "C" void kernel_launch(void* const* d_in, const int* in_sizes, int n_in,
                              void* d_out, int out_size, void* d_ws, size_t ws_size,
                              hipStream_t stream) {
  const float* x   = (const float*)d_in[0];
  const float* w1  = (const float*)d_in[1];
  const float* w2  = (const float*)d_in[2];
  const float* w3  = (const float*)d_in[3];
  const float* w4  = (const float*)d_in[4];
  const float* g1  = (const float*)d_in[5];
  const float* b1  = (const float*)d_in[6];
  const float* g2  = (const float*)d_in[7];
  const float* b2  = (const float*)d_in[8];
  const float* g3  = (const float*)d_in[9];
  const float* b3  = (const float*)d_in[10];
  const float* g4  = (const float*)d_in[11];
  const float* b4  = (const float*)d_in[12];
  const float* f1w = (const float*)d_in[13];
  const float* f1b = (const float*)d_in[14];
  const float* f2w = (const float*)d_in[15];
  const float* f2b = (const float*)d_in[16];
  const float* f3w = (const float*)d_in[17];
  const float* f3b = (const float*)d_in[18];
  float* out = (float*)d_out;
  float* ws = (float*)d_ws;

  const int B = 4096;
  float* SUM1 = ws + 0;   float* SQ1 = ws + 12;
  float* SUM2 = ws + 24;  float* SQ2 = ws + 48;
  float* SUM3 = ws + 72;  float* SQ3 = ws + 120;
  float* SUM4 = ws + 168; float* SQ4 = ws + 264;
  float* SC1 = ws + 384;  float* SH1 = ws + 396;
  float* SC2 = ws + 408;  float* SH2 = ws + 432;
  float* SC3 = ws + 456;  float* SH3 = ws + 504;
  float* SC4 = ws + 552;  float* SH4 = ws + 648;
  float* R1 = ws + 1024;                    // B*5400 floats
  float* R2 = ws + 1024 + (size_t)B * 5400; // B*2016 floats
  float* R3 = ws + 1024;                    // aliases R1 (dead after stage2)
  float* R4 = ws + 1024 + (size_t)B * 720;  // B*288 floats

  hipMemsetAsync(d_ws, 0, 384 * sizeof(float), stream);

  k_lift<<<B, 256, 0, stream>>>(x, w1, R1, SUM1, SQ1);
  k_bnstat<<<1, 128, 0, stream>>>(SUM1, SQ1, g1, b1, SC1, SH1, 12, 1.0f / (float)(B * 450));
  k_stage2<<<(B + NB2 - 1) / NB2, 256, 0, stream>>>(R1, w2, SC1, SH1, R2, SUM2, SQ2, B);
  k_bnstat<<<1, 128, 0, stream>>>(SUM2, SQ2, g2, b2, SC2, SH2, 24, 1.0f / (float)(B * 84));
  k_stage3<<<(B + NB3 - 1) / NB3, 256, 0, stream>>>(R2, w3, SC2, SH2, R3, SUM3, SQ3, B);
  k_bnstat<<<1, 128, 0, stream>>>(SUM3, SQ3, g3, b3, SC3, SH3, 48, 1.0f / (float)(B * 15));
  k_stage4<<<B / NB4, 256, 0, stream>>>(R3, w4, SC3, SH3, R4, SUM4, SQ4);
  k_bnstat<<<1, 128, 0, stream>>>(SUM4, SQ4, g4, b4, SC4, SH4, 96, 1.0f / (float)(B * 3));
  k_fc<<<B / 4, 256, 0, stream>>>(R4, SC4, SH4, f1w, f1b, f2w, f2b, f3w, f3b, out);
}

// Round 5
// 627.484 us; speedup vs baseline: 4.3682x; 1.0437x over previous
//
#include <hip/hip_runtime.h>

#define EPSBN 2e-5f

// ============================ Stage 1: lift ============================
// x:(B,100,6) w1:(12,6,7) -> r1:(B,12,9,50) = relu(maxpool2(lift_conv/s))
// Zero-padded LDS rows (96 each side) => no bounds checks, no divergence.
#define NB1 4
__global__ __launch_bounds__(256) void k_lift(const float* __restrict__ x,
    const float* __restrict__ w1, float* __restrict__ r1,
    float* __restrict__ sum, float* __restrict__ sq) {
  __shared__ float xs[NB1 * 6 * 293];  // row: [96 zero | 100 data | 97 zero], stride 293
  __shared__ float ws[504];
  __shared__ float ssum[12], ssq[12];
  int b0 = blockIdx.x * NB1, tid = threadIdx.x;
  for (int i = tid; i < NB1 * 6 * 293; i += 256) xs[i] = 0.f;
  for (int i = tid; i < 504; i += 256) ws[i] = w1[i];
  if (tid < 12) { ssum[tid] = 0.f; ssq[tid] = 0.f; }
  __syncthreads();
  for (int i = tid; i < NB1 * 600; i += 256) {
    int bb = i / 600, f = i % 600, t = f / 6, c = f % 6;
    xs[(bb * 6 + c) * 293 + 96 + t] = x[(size_t)(b0 + bb) * 600 + f];
  }
  __syncthreads();
  // lane task: (bb4, op6, tc10) = 240 of 256
  bool act = tid < 240;
  int task = act ? tid : 0;
  int bb = task / 60, r = task % 60;
  int op = r / 10, tc = r % 10;
  int o0 = op * 2, t0 = tc * 10;
  int b = b0 + bb;
  float ts0 = 0.f, tq0 = 0.f, ts1 = 0.f, tq1 = 0.f;
  for (int si = 0; si < 9; ++si) {
    int s = 1 << si;
    float inv = 1.0f / (float)s;
    float acc0[10], acc1[10];
#pragma unroll
    for (int k = 0; k < 10; ++k) { acc0[k] = 0.f; acc1[k] = 0.f; }
    for (int c = 0; c < 6; ++c) {
      const float* xr = xs + (bb * 6 + c) * 293 + 96 + t0;
      const float* wr = ws + (o0 * 6 + c) * 7;
      for (int j = 0; j < 7; ++j) {
        int off = s * (j - 3);
        if (off < -97 || off > 97) continue;   // wave-uniform skip of dead taps
        float w0 = wr[j], w1v = wr[j + 42];
        const float* xp = xr + off;
#pragma unroll
        for (int k = 0; k < 10; ++k) {
          float av = xp[k];
          acc0[k] += av * w0; acc1[k] += av * w1v;
        }
      }
    }
    if (act) {
      size_t rb = ((size_t)b * 12 + o0) * 9 + si;
#pragma unroll
      for (int u = 0; u < 5; ++u) {
        float v0 = fmaxf(fmaxf(acc0[2 * u], acc0[2 * u + 1]) * inv, 0.f);
        float v1 = fmaxf(fmaxf(acc1[2 * u], acc1[2 * u + 1]) * inv, 0.f);
        r1[rb * 50 + (t0 >> 1) + u] = v0;
        r1[(rb + 9) * 50 + (t0 >> 1) + u] = v1;
        ts0 += v0; tq0 += v0 * v0; ts1 += v1; tq1 += v1 * v1;
      }
    }
  }
  if (act) {
    atomicAdd(&ssum[o0], ts0); atomicAdd(&ssq[o0], tq0);
    atomicAdd(&ssum[o0 + 1], ts1); atomicAdd(&ssq[o0 + 1], tq1);
  }
  __syncthreads();
  if (tid < 12) { atomicAdd(&sum[tid], ssum[tid]); atomicAdd(&sq[tid], ssq[tid]); }
}

// ---------------- BN stats -> scale/shift ----------------
__global__ void k_bnstat(const float* __restrict__ sum, const float* __restrict__ sq,
    const float* __restrict__ g, const float* __restrict__ bb,
    float* __restrict__ sc, float* __restrict__ sh, int C, float invN) {
  int c = threadIdx.x;
  if (c < C) {
    float m = sum[c] * invN;
    float v = sq[c] * invN - m * m;
    float scale = g[c] * rsqrtf(v + EPSBN);
    sc[c] = scale;
    sh[c] = bb[c] - m * scale;
  }
}

// ============================ Stage 2 ============================
// r1:(B,12,9,50) -pool-> a(12,9,25); w2:(24,12,3,5); out r2:(B,24,7,12)
// Register-resident rows; taps constant-folded per (S,I2) template.
#define NB2 5
template<int S, int I2>
__device__ __forceinline__ void s2_do(const float* __restrict__ ab,
    const float* __restrict__ wsl, int ot, bool act, int b,
    float* __restrict__ r2, float& ts0, float& tq0, float& ts1, float& tq1) {
  float acc0[24], acc1[24];
#pragma unroll
  for (int t = 0; t < 24; ++t) { acc0[t] = 0.f; acc1[t] = 0.f; }
  for (int c = 0; c < 12; ++c) {
    for (int h = 0; h < 3; ++h) {
      const float* ar = ab + (c * 9 + I2 + h) * 25;
      float rr[25];
#pragma unroll
      for (int t = 0; t < 25; ++t) rr[t] = ar[t];
      const float* wp = wsl + (c * 3 + h) * 5 * 24 + ot * 2;
#pragma unroll
      for (int j = 0; j < 5; ++j) {
        const int off = S * (j - 2);
        if (off <= -25 || off >= 25) continue;
        float2 wv = *(const float2*)(wp + j * 24);
#pragma unroll
        for (int t = 0; t < 24; ++t) {
          if (t + off >= 0 && t + off < 25) {
            acc0[t] += rr[t + off] * wv.x;
            acc1[t] += rr[t + off] * wv.y;
          }
        }
      }
    }
  }
  if (act) {
    const float inv = 1.0f / (float)S;
    int o0 = ot * 2;
    size_t rb = ((size_t)b * 24 + o0) * 84 + I2 * 12;
#pragma unroll
    for (int u = 0; u < 12; ++u) {
      float v0 = fmaxf(fmaxf(acc0[2 * u], acc0[2 * u + 1]) * inv, 0.f);
      float v1 = fmaxf(fmaxf(acc1[2 * u], acc1[2 * u + 1]) * inv, 0.f);
      r2[rb + u] = v0; r2[rb + 84 + u] = v1;
      ts0 += v0; tq0 += v0 * v0; ts1 += v1; tq1 += v1 * v1;
    }
  }
}

__global__ __launch_bounds__(256) void k_stage2(const float* __restrict__ r1,
    const float* __restrict__ w2, const float* __restrict__ sc, const float* __restrict__ sh,
    float* __restrict__ r2, float* __restrict__ sum, float* __restrict__ sq, int B) {
  __shared__ float as[NB2 * 2701];   // stride 2701 (mod32=13)
  __shared__ float wsl[4320];        // [c][h][j][o24]
  __shared__ float ssum[24], ssq[24];
  int b0 = blockIdx.x * NB2, tid = threadIdx.x;
  for (int i = tid; i < NB2 * 2700; i += 256) {
    int bb = i / 2700, f = i % 2700;
    if (b0 + bb < B) {
      float2 p = ((const float2*)(r1 + (size_t)(b0 + bb) * 5400))[f];
      int c = f / 225;
      as[bb * 2701 + f] = fmaxf(p.x, p.y) * sc[c] + sh[c];
    }
  }
  for (int i = tid; i < 4320; i += 256) {
    int o = i / 180, rem = i % 180, c = rem / 15, h = (rem % 15) / 5, j = rem % 5;
    wsl[((c * 3 + h) * 5 + j) * 24 + o] = w2[i];
  }
  if (tid < 24) { ssum[tid] = 0.f; ssq[tid] = 0.f; }
  __syncthreads();
  int wv = tid >> 6, lane = tid & 63;
  int bb = lane / 12, ot = lane % 12;
  bool act = (lane < 60) && (b0 + bb < B);
  if (bb > 4) bb = 4;
  const float* ab = as + bb * 2701;
  int b = b0 + bb;
  float ts0 = 0.f, tq0 = 0.f, ts1 = 0.f, tq1 = 0.f;
  // balanced schedule by valid-term count
  if (wv == 0) {
    s2_do<1, 0>(ab, wsl, ot, act, b, r2, ts0, tq0, ts1, tq1);
  } else if (wv == 1) {
    s2_do<2, 1>(ab, wsl, ot, act, b, r2, ts0, tq0, ts1, tq1);
    s2_do<64, 6>(ab, wsl, ot, act, b, r2, ts0, tq0, ts1, tq1);
  } else if (wv == 2) {
    s2_do<4, 2>(ab, wsl, ot, act, b, r2, ts0, tq0, ts1, tq1);
    s2_do<32, 5>(ab, wsl, ot, act, b, r2, ts0, tq0, ts1, tq1);
  } else {
    s2_do<8, 3>(ab, wsl, ot, act, b, r2, ts0, tq0, ts1, tq1);
    s2_do<16, 4>(ab, wsl, ot, act, b, r2, ts0, tq0, ts1, tq1);
  }
  if (act) {
    int o0 = ot * 2;
    atomicAdd(&ssum[o0], ts0); atomicAdd(&ssq[o0], tq0);
    atomicAdd(&ssum[o0 + 1], ts1); atomicAdd(&ssq[o0 + 1], tq1);
  }
  __syncthreads();
  if (tid < 24) { atomicAdd(&sum[tid], ssum[tid]); atomicAdd(&sq[tid], ssq[tid]); }
}

// ============================ Stage 3 ============================
// r2:(B,24,7,12) -pool-> a(24,7,6); w3:(48,24,3,5); out r3:(B,48,5,3)
#define NB3 10
template<int S, int I2>
__device__ __forceinline__ void s3_do(const float* __restrict__ ab,
    const float* __restrict__ wsl, int ot, bool act, int b, int obase,
    float* __restrict__ r3, float& ts0, float& tq0, float& ts1, float& tq1) {
  float acc0[6], acc1[6];
#pragma unroll
  for (int t = 0; t < 6; ++t) { acc0[t] = 0.f; acc1[t] = 0.f; }
  for (int c = 0; c < 24; ++c) {
    for (int h = 0; h < 3; ++h) {
      const float* ar = ab + (c * 7 + I2 + h) * 6;
      float rr[6];
#pragma unroll
      for (int t = 0; t < 6; ++t) rr[t] = ar[t];
      const float* wp = wsl + (c * 3 + h) * 5 * 24 + ot * 2;
#pragma unroll
      for (int j = 0; j < 5; ++j) {
        const int off = S * (j - 2);
        if (off <= -6 || off >= 6) continue;
        float2 wv = *(const float2*)(wp + j * 24);
#pragma unroll
        for (int t = 0; t < 6; ++t) {
          if (t + off >= 0 && t + off < 6) {
            acc0[t] += rr[t + off] * wv.x;
            acc1[t] += rr[t + off] * wv.y;
          }
        }
      }
    }
  }
  if (act) {
    const float inv = 1.0f / (float)S;
    size_t rb0 = ((size_t)b * 48 + obase) * 15 + I2 * 3;
    size_t rb1 = rb0 + 15;
#pragma unroll
    for (int u = 0; u < 3; ++u) {
      float v0 = fmaxf(fmaxf(acc0[2 * u], acc0[2 * u + 1]) * inv, 0.f);
      float v1 = fmaxf(fmaxf(acc1[2 * u], acc1[2 * u + 1]) * inv, 0.f);
      r3[rb0 + u] = v0; r3[rb1 + u] = v1;
      ts0 += v0; tq0 += v0 * v0; ts1 += v1; tq1 += v1 * v1;
    }
  }
}

__global__ __launch_bounds__(256) void k_stage3(const float* __restrict__ r2,
    const float* __restrict__ w3, const float* __restrict__ sc, const float* __restrict__ sh,
    float* __restrict__ r3, float* __restrict__ sum, float* __restrict__ sq, int B) {
  __shared__ float as[NB3 * 1009];   // stride mod32=17
  __shared__ float wsl[8640];        // chunk: [c][h][j][o24]
  __shared__ float ssum[48], ssq[48];
  int b0 = blockIdx.x * NB3, tid = threadIdx.x;
  for (int i = tid; i < NB3 * 1008; i += 256) {
    int bb = i / 1008, f = i % 1008;
    if (b0 + bb < B) {
      float2 p = ((const float2*)(r2 + (size_t)(b0 + bb) * 2016))[f];
      int c = f / 42;
      as[bb * 1009 + f] = fmaxf(p.x, p.y) * sc[c] + sh[c];
    }
  }
  if (tid < 48) { ssum[tid] = 0.f; ssq[tid] = 0.f; }
  int wv = tid >> 6, lane = tid & 63;
  int bbh = lane / 12, ot = lane % 12;
  if (bbh > 4) bbh = 4;
  int bb = ((wv == 1) || (wv == 3)) ? bbh + 5 : bbh;
  bool act = (lane < 60) && (b0 + bb < B);
  const float* ab = as + bb * 1009;
  int b = b0 + bb;
  for (int chunk = 0; chunk < 2; ++chunk) {
    __syncthreads();
    for (int i = tid; i < 8640; i += 256) {
      int oo = i / 360, rem = i % 360, c = rem / 15, h = (rem % 15) / 5, j = rem % 5;
      wsl[((c * 3 + h) * 5 + j) * 24 + oo] = w3[chunk * 8640 + i];
    }
    __syncthreads();
    int obase = chunk * 24 + ot * 2;
    float ts0 = 0.f, tq0 = 0.f, ts1 = 0.f, tq1 = 0.f;
    if (wv < 2) {   // {i2=0, i2=3}
      s3_do<1, 0>(ab, wsl, ot, act, b, obase, r3, ts0, tq0, ts1, tq1);
      s3_do<8, 3>(ab, wsl, ot, act, b, obase, r3, ts0, tq0, ts1, tq1);
    } else {        // {i2=1, i2=2, i2=4}
      s3_do<2, 1>(ab, wsl, ot, act, b, obase, r3, ts0, tq0, ts1, tq1);
      s3_do<4, 2>(ab, wsl, ot, act, b, obase, r3, ts0, tq0, ts1, tq1);
      s3_do<16, 4>(ab, wsl, ot, act, b, obase, r3, ts0, tq0, ts1, tq1);
    }
    if (act) {
      atomicAdd(&ssum[obase], ts0); atomicAdd(&ssq[obase], tq0);
      atomicAdd(&ssum[obase + 1], ts1); atomicAdd(&ssq[obase + 1], tq1);
    }
  }
  __syncthreads();
  if (tid < 48) { atomicAdd(&sum[tid], ssum[tid]); atomicAdd(&sq[tid], ssq[tid]); }
}

// ============================ Stage 4 ============================
// r3:(B,48,5,3); w4:(96,48,3,3); out r4:(B,96,3)
#define NB4 8
template<int S, int I2>
__device__ __forceinline__ void s4_do(const float* __restrict__ ab,
    const float* __restrict__ wsl, int ot, bool act, int b, int obase,
    float* __restrict__ r4, float& ts0, float& tq0, float& ts1, float& tq1) {
  float a00 = 0.f, a01 = 0.f, a10 = 0.f, a11 = 0.f;
  for (int c = 0; c < 48; ++c) {
    for (int h = 0; h < 3; ++h) {
      const float* ar = ab + (c * 5 + I2 + h) * 3;
      float r0 = ar[0], r1v = ar[1], r2v = ar[2];
      const float* wp = wsl + (c * 3 + h) * 3 * 24 + ot * 2;
#pragma unroll
      for (int j = 0; j < 3; ++j) {
        const int off = S * (j - 1);
        if (off <= -3 || off >= 3) continue;
        float2 wv = *(const float2*)(wp + j * 24);
        // t = 0
        if (off >= 0) { float av = (off == 0) ? r0 : ((off == 1) ? r1v : r2v);
                        a00 += av * wv.x; a10 += av * wv.y; }
        // t = 1
        { const int i1 = 1 + off;
          if (i1 >= 0 && i1 < 3) { float av = (i1 == 0) ? r0 : ((i1 == 1) ? r1v : r2v);
                                   a01 += av * wv.x; a11 += av * wv.y; } }
      }
    }
  }
  if (act) {
    const float inv = 1.0f / (float)S;
    float v0 = fmaxf(fmaxf(a00, a01) * inv, 0.f);
    float v1 = fmaxf(fmaxf(a10, a11) * inv, 0.f);
    r4[(size_t)b * 288 + obase * 3 + I2] = v0;
    r4[(size_t)b * 288 + (obase + 1) * 3 + I2] = v1;
    ts0 += v0; tq0 += v0 * v0; ts1 += v1; tq1 += v1 * v1;
  }
}

__global__ __launch_bounds__(256) void k_stage4(const float* __restrict__ r3,
    const float* __restrict__ w4, const float* __restrict__ sc, const float* __restrict__ sh,
    float* __restrict__ r4, float* __restrict__ sum, float* __restrict__ sq) {
  __shared__ float as[NB4 * 721];    // stride mod32=17
  __shared__ float wsl[10368];       // chunk: [c][h][j][o24]
  __shared__ float ssum[96], ssq[96];
  int b0 = blockIdx.x * NB4, tid = threadIdx.x;
  for (int i = tid; i < NB4 * 720; i += 256) {
    int bb = i / 720, f = i % 720, c = f / 15;
    as[bb * 721 + f] = r3[(size_t)(b0 + bb) * 720 + f] * sc[c] + sh[c];
  }
  if (tid < 96) { ssum[tid] = 0.f; ssq[tid] = 0.f; }
  int wv = tid >> 6, lane = tid & 63;
  int bbh = lane / 12, ot = lane % 12;
  bool act = lane < 48;
  if (bbh > 3) bbh = 3;
  int bb = ((wv == 1) || (wv == 3)) ? bbh + 4 : bbh;
  const float* ab = as + bb * 721;
  int b = b0 + bb;
  for (int chunk = 0; chunk < 4; ++chunk) {
    __syncthreads();
    for (int i = tid; i < 10368; i += 256) {
      int oo = i / 432, rem = i % 432, c = rem / 9, h = (rem % 9) / 3, j = rem % 3;
      wsl[((c * 3 + h) * 3 + j) * 24 + oo] = w4[chunk * 10368 + i];
    }
    __syncthreads();
    int obase = chunk * 24 + ot * 2;
    float ts0 = 0.f, tq0 = 0.f, ts1 = 0.f, tq1 = 0.f;
    if (wv < 2) {   // {i2=0}
      s4_do<1, 0>(ab, wsl, ot, act, b, obase, r4, ts0, tq0, ts1, tq1);
    } else {        // {i2=1, i2=2}
      s4_do<2, 1>(ab, wsl, ot, act, b, obase, r4, ts0, tq0, ts1, tq1);
      s4_do<4, 2>(ab, wsl, ot, act, b, obase, r4, ts0, tq0, ts1, tq1);
    }
    if (act) {
      atomicAdd(&ssum[obase], ts0); atomicAdd(&ssq[obase], tq0);
      atomicAdd(&ssum[obase + 1], ts1); atomicAdd(&ssq[obase + 1], tq1);
    }
  }
  __syncthreads();
  if (tid < 96) { atomicAdd(&sum[tid], ssum[tid]); atomicAdd(&sq[tid], ssq[tid]); }
}

// ---------------- FC head: BN4-affine + 288->96->48->6 ----------------
__global__ __launch_bounds__(256) void k_fc(const float* __restrict__ r4,
    const float* __restrict__ sc, const float* __restrict__ sh,
    const float* __restrict__ f1w, const float* __restrict__ f1b,
    const float* __restrict__ f2w, const float* __restrict__ f2b,
    const float* __restrict__ f3w, const float* __restrict__ f3b,
    float* __restrict__ out) {
  __shared__ float v[4][288];
  __shared__ float h1[4][96];
  __shared__ float h2[4][48];
  int b0 = blockIdx.x * 4, tid = threadIdx.x;
  for (int i = tid; i < 4 * 288; i += 256) {
    int bb = i / 288, f = i % 288, c = f / 3;
    v[bb][f] = r4[(size_t)(b0 + bb) * 288 + f] * sc[c] + sh[c];
  }
  __syncthreads();
  for (int d = tid; d < 384; d += 256) {
    int o = d >> 2, bb = d & 3;
    const float* wr = &f1w[o * 288];
    const float* vv = v[bb];
    float acc = f1b[o];
    for (int f = 0; f < 288; ++f) acc += wr[f] * vv[f];
    h1[bb][o] = acc;
  }
  __syncthreads();
  if (tid < 192) {
    int o = tid >> 2, bb = tid & 3;
    const float* wr = &f2w[o * 96];
    float acc = f2b[o];
    for (int f = 0; f < 96; ++f) acc += wr[f] * h1[bb][f];
    h2[bb][o] = acc;
  }
  __syncthreads();
  if (tid < 24) {
    int o = tid >> 2, bb = tid & 3;
    const float* wr = &f3w[o * 48];
    float acc = f3b[o];
    for (int f = 0; f < 48; ++f) acc += wr[f] * h2[bb][f];
    out[(size_t)(b0 + bb) * 6 + o] = acc;
  }
}

extern "C" void kernel_launch(void* const* d_in, const int* in_sizes, int n_in,
                              void* d_out, int out_size, void* d_ws, size_t ws_size,
                              hipStream_t stream) {
  const float* x   = (const float*)d_in[0];
  const float* w1  = (const float*)d_in[1];
  const float* w2  = (const float*)d_in[2];
  const float* w3  = (const float*)d_in[3];
  const float* w4  = (const float*)d_in[4];
  const float* g1  = (const float*)d_in[5];
  const float* b1  = (const float*)d_in[6];
  const float* g2  = (const float*)d_in[7];
  const float* b2  = (const float*)d_in[8];
  const float* g3  = (const float*)d_in[9];
  const float* b3  = (const float*)d_in[10];
  const float* g4  = (const float*)d_in[11];
  const float* b4  = (const float*)d_in[12];
  const float* f1w = (const float*)d_in[13];
  const float* f1b = (const float*)d_in[14];
  const float* f2w = (const float*)d_in[15];
  const float* f2b = (const float*)d_in[16];
  const float* f3w = (const float*)d_in[17];
  const float* f3b = (const float*)d_in[18];
  float* out = (float*)d_out;
  float* ws = (float*)d_ws;

  const int B = 4096;
  float* SUM1 = ws + 0;   float* SQ1 = ws + 12;
  float* SUM2 = ws + 24;  float* SQ2 = ws + 48;
  float* SUM3 = ws + 72;  float* SQ3 = ws + 120;
  float* SUM4 = ws + 168; float* SQ4 = ws + 264;
  float* SC1 = ws + 384;  float* SH1 = ws + 396;
  float* SC2 = ws + 408;  float* SH2 = ws + 432;
  float* SC3 = ws + 456;  float* SH3 = ws + 504;
  float* SC4 = ws + 552;  float* SH4 = ws + 648;
  float* R1 = ws + 1024;                    // B*5400 floats
  float* R2 = ws + 1024 + (size_t)B * 5400; // B*2016 floats
  float* R3 = ws + 1024;                    // aliases R1 (dead after stage2)
  float* R4 = ws + 1024 + (size_t)B * 720;  // B*288 floats

  hipMemsetAsync(d_ws, 0, 384 * sizeof(float), stream);

  k_lift<<<B / NB1, 256, 0, stream>>>(x, w1, R1, SUM1, SQ1);
  k_bnstat<<<1, 128, 0, stream>>>(SUM1, SQ1, g1, b1, SC1, SH1, 12, 1.0f / (float)(B * 450));
  k_stage2<<<(B + NB2 - 1) / NB2, 256, 0, stream>>>(R1, w2, SC1, SH1, R2, SUM2, SQ2, B);
  k_bnstat<<<1, 128, 0, stream>>>(SUM2, SQ2, g2, b2, SC2, SH2, 24, 1.0f / (float)(B * 84));
  k_stage3<<<(B + NB3 - 1) / NB3, 256, 0, stream>>>(R2, w3, SC2, SH2, R3, SUM3, SQ3, B);
  k_bnstat<<<1, 128, 0, stream>>>(SUM3, SQ3, g3, b3, SC3, SH3, 48, 1.0f / (float)(B * 15));
  k_stage4<<<B / NB4, 256, 0, stream>>>(R3, w4, SC3, SH3, R4, SUM4, SQ4);
  k_bnstat<<<1, 128, 0, stream>>>(SUM4, SQ4, g4, b4, SC4, SH4, 96, 1.0f / (float)(B * 3));
  k_fc<<<B / 4, 256, 0, stream>>>(R4, SC4, SH4, f1w, f1b, f2w, f2b, f3w, f3b, out);
}

// Round 6
// 511.600 us; speedup vs baseline: 5.3576x; 1.2265x over previous
//
#include <hip/hip_runtime.h>

#define EPSBN 2e-5f

// ============================ Stage 1: lift ============================
// x:(B,100,6) w1:(12,6,7) -> r1:(B,12,9,50) = relu(maxpool2(lift_conv/s))
// Zero-padded LDS rows (stride 294, 96 left pad). Thread = (bb8, og2: 6 o, tc10: 10 t).
#define NB1 8
template<int SI>
__device__ __forceinline__ void s1_si(const float* __restrict__ xs, int bb, int t0,
    const float* __restrict__ wl, int ob, bool act, int b, float* __restrict__ r1,
    float* st, float* sqv) {
  constexpr int S = 1 << SI;
  float acc[6][10];
#pragma unroll
  for (int o = 0; o < 6; ++o)
#pragma unroll
    for (int k = 0; k < 10; ++k) acc[o][k] = 0.f;
#pragma unroll 1
  for (int c = 0; c < 6; ++c) {
    const float* xr = xs + (bb * 6 + c) * 294 + 96 + t0;   // even base
    const float* wp = wl + c * 84 + ob;
#pragma unroll
    for (int j = 0; j < 7; ++j) {
      const int off = S * (j - 3);
      if (off < -97 || off > 97) continue;                 // compile-time dead tap
      const int offE = off & ~1;                           // floor-even
      const int sh = off & 1;
      float xv[12];
#pragma unroll
      for (int k = 0; k < 6; ++k)
        *(float2*)&xv[2 * k] = *(const float2*)(xr + offE + 2 * k);
      float wv[6];
#pragma unroll
      for (int q = 0; q < 3; ++q)
        *(float2*)&wv[2 * q] = *(const float2*)(wp + j * 12 + 2 * q);
#pragma unroll
      for (int k = 0; k < 10; ++k) {
        float av = xv[sh + k];
#pragma unroll
        for (int o = 0; o < 6; ++o) acc[o][k] += av * wv[o];
      }
    }
  }
  if (act) {
    const float inv = 1.0f / (float)S;
#pragma unroll
    for (int o = 0; o < 6; ++o) {
      size_t rb = ((size_t)b * 12 + ob + o) * 9 + SI;
#pragma unroll
      for (int u = 0; u < 5; ++u) {
        float v = fmaxf(fmaxf(acc[o][2 * u], acc[o][2 * u + 1]) * inv, 0.f);
        r1[rb * 50 + (t0 >> 1) + u] = v;
        st[o] += v; sqv[o] += v * v;
      }
    }
  }
}

__global__ __launch_bounds__(256) void k_lift(const float* __restrict__ x,
    const float* __restrict__ w1, float* __restrict__ r1,
    float* __restrict__ sum, float* __restrict__ sq) {
  __shared__ float xs[NB1 * 6 * 294];   // 56.4 KB
  __shared__ float wl[504];             // [c6][j7][o12]
  __shared__ float ssum[12], ssq[12];
  int b0 = blockIdx.x * NB1, tid = threadIdx.x;
  for (int i = tid; i < NB1 * 6 * 294; i += 256) xs[i] = 0.f;
  for (int i = tid; i < 504; i += 256) {
    int o = i / 42, c = (i % 42) / 7, j = i % 7;
    wl[(c * 7 + j) * 12 + o] = w1[i];
  }
  if (tid < 12) { ssum[tid] = 0.f; ssq[tid] = 0.f; }
  __syncthreads();
  for (int i = tid; i < NB1 * 600; i += 256) {
    int bb = i / 600, f = i % 600, t = f / 6, c = f % 6;
    xs[(bb * 6 + c) * 294 + 96 + t] = x[(size_t)(b0 + bb) * 600 + f];
  }
  __syncthreads();
  bool act = tid < 160;
  if (act) {
    int bb = tid / 20, r = tid % 20;
    int og = r / 10, tc = r % 10;
    int ob = og * 6, t0 = tc * 10;
    int b = b0 + bb;
    float st[6], sqv[6];
#pragma unroll
    for (int o = 0; o < 6; ++o) { st[o] = 0.f; sqv[o] = 0.f; }
    s1_si<0>(xs, bb, t0, wl, ob, act, b, r1, st, sqv);
    s1_si<1>(xs, bb, t0, wl, ob, act, b, r1, st, sqv);
    s1_si<2>(xs, bb, t0, wl, ob, act, b, r1, st, sqv);
    s1_si<3>(xs, bb, t0, wl, ob, act, b, r1, st, sqv);
    s1_si<4>(xs, bb, t0, wl, ob, act, b, r1, st, sqv);
    s1_si<5>(xs, bb, t0, wl, ob, act, b, r1, st, sqv);
    s1_si<6>(xs, bb, t0, wl, ob, act, b, r1, st, sqv);
    s1_si<7>(xs, bb, t0, wl, ob, act, b, r1, st, sqv);
    s1_si<8>(xs, bb, t0, wl, ob, act, b, r1, st, sqv);
#pragma unroll
    for (int o = 0; o < 6; ++o) {
      atomicAdd(&ssum[ob + o], st[o]); atomicAdd(&ssq[ob + o], sqv[o]);
    }
  }
  __syncthreads();
  if (tid < 12) { atomicAdd(&sum[tid], ssum[tid]); atomicAdd(&sq[tid], ssq[tid]); }
}

// ---------------- BN stats -> scale/shift ----------------
__global__ void k_bnstat(const float* __restrict__ sum, const float* __restrict__ sq,
    const float* __restrict__ g, const float* __restrict__ bb,
    float* __restrict__ sc, float* __restrict__ sh, int C, float invN) {
  int c = threadIdx.x;
  if (c < C) {
    float m = sum[c] * invN;
    float v = sq[c] * invN - m * m;
    float scale = g[c] * rsqrtf(v + EPSBN);
    sc[c] = scale;
    sh[c] = bb[c] - m * scale;
  }
}

// ============================ Stage 2 ============================
// r1:(B,12,9,50) -pool-> a(12,9,25) rows stride 26; w2 LDS [c][h][j][op12][2].
// Thread = (bb5, op12); waves own i2 lists (balanced by valid-term counts).
#define NB2 5
template<int S, int I2>
__device__ __forceinline__ void s2_do(const float* __restrict__ ab,
    const float* __restrict__ wsl, int op, bool act, int b,
    float* __restrict__ r2, float& ts0, float& tq0, float& ts1, float& tq1) {
  float acc0[24], acc1[24];
#pragma unroll
  for (int t = 0; t < 24; ++t) { acc0[t] = 0.f; acc1[t] = 0.f; }
#pragma unroll 1
  for (int c = 0; c < 12; ++c) {
#pragma unroll
    for (int h = 0; h < 3; ++h) {
      const float* ar = ab + (c * 9 + I2 + h) * 26;
      float rr[26];
#pragma unroll
      for (int k = 0; k < 13; ++k)
        *(float2*)&rr[2 * k] = *(const float2*)(ar + 2 * k);
#pragma unroll
      for (int j = 0; j < 5; ++j) {
        const int off = S * (j - 2);
        if (off <= -25 || off >= 25) continue;
        float2 w = *(const float2*)(wsl + ((c * 3 + h) * 5 + j) * 24 + op * 2);
#pragma unroll
        for (int t = 0; t < 24; ++t) {
          if (t + off >= 0 && t + off < 25) {
            float av = rr[t + off];
            acc0[t] += av * w.x; acc1[t] += av * w.y;
          }
        }
      }
    }
  }
  if (act) {
    const float inv = 1.0f / (float)S;
    int o0 = op * 2;
    size_t rb = ((size_t)b * 24 + o0) * 84 + I2 * 12;
#pragma unroll
    for (int u = 0; u < 12; ++u) {
      float v0 = fmaxf(fmaxf(acc0[2 * u], acc0[2 * u + 1]) * inv, 0.f);
      float v1 = fmaxf(fmaxf(acc1[2 * u], acc1[2 * u + 1]) * inv, 0.f);
      r2[rb + u] = v0; r2[rb + 84 + u] = v1;
      ts0 += v0; tq0 += v0 * v0; ts1 += v1; tq1 += v1 * v1;
    }
  }
}

__global__ __launch_bounds__(256) void k_stage2(const float* __restrict__ r1,
    const float* __restrict__ w2, const float* __restrict__ sc, const float* __restrict__ sh,
    float* __restrict__ r2, float* __restrict__ sum, float* __restrict__ sq, int B) {
  __shared__ float as[NB2 * 2810];   // rows stride 26, bb stride 2810 (even, banks distinct)
  __shared__ float wsl[4320];        // [c][h][j][op12][2]
  __shared__ float ssum[24], ssq[24];
  int b0 = blockIdx.x * NB2, tid = threadIdx.x;
  for (int i = tid; i < NB2 * 2700; i += 256) {
    int bb = i / 2700, f = i % 2700;
    if (b0 + bb < B) {
      float2 p = ((const float2*)(r1 + (size_t)(b0 + bb) * 5400))[f];
      int c = f / 225, r = (f % 225) / 25, xp = f % 25;
      as[bb * 2810 + (c * 9 + r) * 26 + xp] = fmaxf(p.x, p.y) * sc[c] + sh[c];
    }
  }
  for (int i = tid; i < 4320; i += 256) {
    int o = i / 180, c = (i % 180) / 15, h = (i % 15) / 5, j = i % 5;
    wsl[((c * 3 + h) * 5 + j) * 24 + o] = w2[i];
  }
  if (tid < 24) { ssum[tid] = 0.f; ssq[tid] = 0.f; }
  __syncthreads();
  int wv = tid >> 6, lane = tid & 63;
  int bb = lane / 12, op = lane % 12;
  bool act = (lane < 60) && (b0 + bb < B);
  if (bb > 4) bb = 4;
  const float* ab = as + bb * 2810;
  int b = b0 + bb;
  float ts0 = 0.f, tq0 = 0.f, ts1 = 0.f, tq1 = 0.f;
  // valid-term counts: i2: 116,110,98,74,41,24,24 -> {0}=116, {1,6}=134, {2,5}=122, {3,4}=115
  if (wv == 0) {
    s2_do<1, 0>(ab, wsl, op, act, b, r2, ts0, tq0, ts1, tq1);
  } else if (wv == 1) {
    s2_do<2, 1>(ab, wsl, op, act, b, r2, ts0, tq0, ts1, tq1);
    s2_do<64, 6>(ab, wsl, op, act, b, r2, ts0, tq0, ts1, tq1);
  } else if (wv == 2) {
    s2_do<4, 2>(ab, wsl, op, act, b, r2, ts0, tq0, ts1, tq1);
    s2_do<32, 5>(ab, wsl, op, act, b, r2, ts0, tq0, ts1, tq1);
  } else {
    s2_do<8, 3>(ab, wsl, op, act, b, r2, ts0, tq0, ts1, tq1);
    s2_do<16, 4>(ab, wsl, op, act, b, r2, ts0, tq0, ts1, tq1);
  }
  if (act) {
    int o0 = op * 2;
    atomicAdd(&ssum[o0], ts0); atomicAdd(&ssq[o0], tq0);
    atomicAdd(&ssum[o0 + 1], ts1); atomicAdd(&ssq[o0 + 1], tq1);
  }
  __syncthreads();
  if (tid < 24) { atomicAdd(&sum[tid], ssum[tid]); atomicAdd(&sq[tid], ssq[tid]); }
}

// ============================ Stage 3 ============================
// r2:(B,24,7,12) -pool-> a(24,7,6); w3:(48,24,3,5); out r3:(B,48,5,3)
// Thread = (bb16, op12 of 24-o chunk), loops ALL i2; rr/w hoisted per c.
#define NB3 16
template<int I2>
__device__ __forceinline__ void s3_acc(const float* __restrict__ rr,
    const float2* __restrict__ wr, float* __restrict__ acc) {
  constexpr int S = 1 << I2;
#pragma unroll
  for (int h = 0; h < 3; ++h) {
    const int base = (I2 + h) * 6;
#pragma unroll
    for (int j = 0; j < 5; ++j) {
      const int off = S * (j - 2);
      if (off <= -6 || off >= 6) continue;
      float2 w = wr[h * 5 + j];
#pragma unroll
      for (int t = 0; t < 6; ++t) {
        if (t + off >= 0 && t + off < 6) {
          float av = rr[base + t + off];
          acc[t] += av * w.x; acc[6 + t] += av * w.y;
        }
      }
    }
  }
}

__global__ __launch_bounds__(256) void k_stage3(const float* __restrict__ r2,
    const float* __restrict__ w3, const float* __restrict__ sc, const float* __restrict__ sh,
    float* __restrict__ r3, float* __restrict__ sum, float* __restrict__ sq) {
  __shared__ float as[NB3 * 1010];   // bb stride 1010 (even, banks distinct)
  __shared__ float wsl[8640];        // chunk: [c][h][j][op12][2]
  __shared__ float ssum[48], ssq[48];
  int b0 = blockIdx.x * NB3, tid = threadIdx.x;
  for (int i = tid; i < NB3 * 1008; i += 256) {
    int bb = i / 1008, f = i % 1008;
    float2 p = ((const float2*)(r2 + (size_t)(b0 + bb) * 2016))[f];
    int c = f / 42;
    as[bb * 1010 + f] = fmaxf(p.x, p.y) * sc[c] + sh[c];
  }
  if (tid < 48) { ssum[tid] = 0.f; ssq[tid] = 0.f; }
  bool act = tid < 192;
  int bb = act ? tid / 12 : 0, op = tid % 12;
  const float* ab = as + bb * 1010;
  int b = b0 + bb;
  for (int chunk = 0; chunk < 2; ++chunk) {
    __syncthreads();
    for (int i = tid; i < 8640; i += 256) {
      int oo = i / 360, c = (i % 360) / 15, h = (i % 15) / 5, j = i % 5;
      wsl[((c * 3 + h) * 5 + j) * 24 + oo] = w3[chunk * 8640 + i];
    }
    __syncthreads();
    if (act) {
      float acc[60];   // [i2 5][o2][t6]
#pragma unroll
      for (int k = 0; k < 60; ++k) acc[k] = 0.f;
#pragma unroll 1
      for (int c = 0; c < 24; ++c) {
        float rr[42];
        const float* ar = ab + c * 42;
#pragma unroll
        for (int k = 0; k < 21; ++k)
          *(float2*)&rr[2 * k] = *(const float2*)(ar + 2 * k);
        float2 wr[15];
#pragma unroll
        for (int hj = 0; hj < 15; ++hj)
          wr[hj] = *(const float2*)(wsl + (c * 15 + hj) * 24 + op * 2);
        s3_acc<0>(rr, wr, acc);
        s3_acc<1>(rr, wr, acc + 12);
        s3_acc<2>(rr, wr, acc + 24);
        s3_acc<3>(rr, wr, acc + 36);
        s3_acc<4>(rr, wr, acc + 48);
      }
      float ts0 = 0.f, tq0 = 0.f, ts1 = 0.f, tq1 = 0.f;
      int ob = chunk * 24 + op * 2;
#pragma unroll
      for (int i2 = 0; i2 < 5; ++i2) {
        const float inv = 1.0f / (float)(1 << i2);
        size_t rb0 = ((size_t)b * 48 + ob) * 15 + i2 * 3;
#pragma unroll
        for (int u = 0; u < 3; ++u) {
          float v0 = fmaxf(fmaxf(acc[i2 * 12 + 2 * u], acc[i2 * 12 + 2 * u + 1]) * inv, 0.f);
          float v1 = fmaxf(fmaxf(acc[i2 * 12 + 6 + 2 * u], acc[i2 * 12 + 7 + 2 * u]) * inv, 0.f);
          r3[rb0 + u] = v0; r3[rb0 + 15 + u] = v1;
          ts0 += v0; tq0 += v0 * v0; ts1 += v1; tq1 += v1 * v1;
        }
      }
      atomicAdd(&ssum[ob], ts0); atomicAdd(&ssq[ob], tq0);
      atomicAdd(&ssum[ob + 1], ts1); atomicAdd(&ssq[ob + 1], tq1);
    }
  }
  __syncthreads();
  if (tid < 48) { atomicAdd(&sum[tid], ssum[tid]); atomicAdd(&sq[tid], ssq[tid]); }
}

// ============================ Stage 4 ============================
// r3:(B,48,5,3); w4:(96,48,3,3); out r4:(B,96,3)
// Thread = (bb16, oq12 of 48-o chunk), loops all i2; rr/w hoisted per c.
#define NB4 16
template<int I2>
__device__ __forceinline__ void s4_acc(const float* __restrict__ rr,
    const float4* __restrict__ wr, float* __restrict__ acc) {
  constexpr int S = 1 << I2;
#pragma unroll
  for (int h = 0; h < 3; ++h) {
    const int base = (I2 + h) * 3;
#pragma unroll
    for (int j = 0; j < 3; ++j) {
      const int off = S * (j - 1);
      if (off <= -3 || off >= 3) continue;
      float4 w = wr[h * 3 + j];
      if (off >= 0) {
        float av = rr[base + off];
        acc[0] += av * w.x; acc[2] += av * w.y; acc[4] += av * w.z; acc[6] += av * w.w;
      }
      if (1 + off >= 0 && 1 + off < 3) {
        float av = rr[base + 1 + off];
        acc[1] += av * w.x; acc[3] += av * w.y; acc[5] += av * w.z; acc[7] += av * w.w;
      }
    }
  }
}

__global__ __launch_bounds__(256) void k_stage4(const float* __restrict__ r3,
    const float* __restrict__ w4, const float* __restrict__ sc, const float* __restrict__ sh,
    float* __restrict__ r4, float* __restrict__ sum, float* __restrict__ sq) {
  __shared__ float as[NB4 * 722];    // bb stride 722 (banks distinct)
  __shared__ float wsl[20736];       // chunk(48 o): [c][h][j][oq12][4]
  __shared__ float ssum[96], ssq[96];
  int b0 = blockIdx.x * NB4, tid = threadIdx.x;
  for (int i = tid; i < NB4 * 720; i += 256) {
    int bb = i / 720, f = i % 720, c = f / 15;
    as[bb * 722 + f] = r3[(size_t)(b0 + bb) * 720 + f] * sc[c] + sh[c];
  }
  if (tid < 96) { ssum[tid] = 0.f; ssq[tid] = 0.f; }
  bool act = tid < 192;
  int bb = act ? tid / 12 : 0, oq = tid % 12;
  const float* ab = as + bb * 722;
  int b = b0 + bb;
  for (int chunk = 0; chunk < 2; ++chunk) {
    __syncthreads();
    for (int i = tid; i < 20736; i += 256) {
      int oo = i / 432, c = (i % 432) / 9, h = (i % 9) / 3, j = i % 3;
      wsl[((c * 3 + h) * 3 + j) * 48 + oo] = w4[chunk * 20736 + i];
    }
    __syncthreads();
    if (act) {
      float acc[24];   // [i2 3][o4][t2]
#pragma unroll
      for (int k = 0; k < 24; ++k) acc[k] = 0.f;
#pragma unroll 1
      for (int c = 0; c < 48; ++c) {
        float rr[15];
        const float* ar = ab + c * 15;
#pragma unroll
        for (int k = 0; k < 15; ++k) rr[k] = ar[k];
        float4 wr[9];
#pragma unroll
        for (int hj = 0; hj < 9; ++hj)
          wr[hj] = *(const float4*)(wsl + (c * 9 + hj) * 48 + oq * 4);
        s4_acc<0>(rr, wr, acc);
        s4_acc<1>(rr, wr, acc + 8);
        s4_acc<2>(rr, wr, acc + 16);
      }
      float ts[4] = {0.f, 0.f, 0.f, 0.f}, tq[4] = {0.f, 0.f, 0.f, 0.f};
      int ob = chunk * 48 + oq * 4;
#pragma unroll
      for (int i2 = 0; i2 < 3; ++i2) {
        const float inv = 1.0f / (float)(1 << i2);
#pragma unroll
        for (int o = 0; o < 4; ++o) {
          float v = fmaxf(fmaxf(acc[i2 * 8 + o * 2], acc[i2 * 8 + o * 2 + 1]) * inv, 0.f);
          r4[(size_t)b * 288 + (ob + o) * 3 + i2] = v;
          ts[o] += v; tq[o] += v * v;
        }
      }
#pragma unroll
      for (int o = 0; o < 4; ++o) {
        atomicAdd(&ssum[ob + o], ts[o]); atomicAdd(&ssq[ob + o], tq[o]);
      }
    }
  }
  __syncthreads();
  if (tid < 96) { atomicAdd(&sum[tid], ssum[tid]); atomicAdd(&sq[tid], ssq[tid]); }
}

// ---------------- FC head: BN4-affine + 288->96->48->6 ----------------
__global__ __launch_bounds__(256) void k_fc(const float* __restrict__ r4,
    const float* __restrict__ sc, const float* __restrict__ sh,
    const float* __restrict__ f1w, const float* __restrict__ f1b,
    const float* __restrict__ f2w, const float* __restrict__ f2b,
    const float* __restrict__ f3w, const float* __restrict__ f3b,
    float* __restrict__ out) {
  __shared__ float v[4][288];
  __shared__ float h1[4][96];
  __shared__ float h2[4][48];
  int b0 = blockIdx.x * 4, tid = threadIdx.x;
  for (int i = tid; i < 4 * 288; i += 256) {
    int bb = i / 288, f = i % 288, c = f / 3;
    v[bb][f] = r4[(size_t)(b0 + bb) * 288 + f] * sc[c] + sh[c];
  }
  __syncthreads();
  for (int d = tid; d < 384; d += 256) {
    int o = d >> 2, bb = d & 3;
    const float* wr = &f1w[o * 288];
    const float* vv = v[bb];
    float acc = f1b[o];
    for (int f = 0; f < 288; ++f) acc += wr[f] * vv[f];
    h1[bb][o] = acc;
  }
  __syncthreads();
  if (tid < 192) {
    int o = tid >> 2, bb = tid & 3;
    const float* wr = &f2w[o * 96];
    float acc = f2b[o];
    for (int f = 0; f < 96; ++f) acc += wr[f] * h1[bb][f];
    h2[bb][o] = acc;
  }
  __syncthreads();
  if (tid < 24) {
    int o = tid >> 2, bb = tid & 3;
    const float* wr = &f3w[o * 48];
    float acc = f3b[o];
    for (int f = 0; f < 48; ++f) acc += wr[f] * h2[bb][f];
    out[(size_t)(b0 + bb) * 6 + o] = acc;
  }
}

extern "C" void kernel_launch(void* const* d_in, const int* in_sizes, int n_in,
                              void* d_out, int out_size, void* d_ws, size_t ws_size,
                              hipStream_t stream) {
  const float* x   = (const float*)d_in[0];
  const float* w1  = (const float*)d_in[1];
  const float* w2  = (const float*)d_in[2];
  const float* w3  = (const float*)d_in[3];
  const float* w4  = (const float*)d_in[4];
  const float* g1  = (const float*)d_in[5];
  const float* b1  = (const float*)d_in[6];
  const float* g2  = (const float*)d_in[7];
  const float* b2  = (const float*)d_in[8];
  const float* g3  = (const float*)d_in[9];
  const float* b3  = (const float*)d_in[10];
  const float* g4  = (const float*)d_in[11];
  const float* b4  = (const float*)d_in[12];
  const float* f1w = (const float*)d_in[13];
  const float* f1b = (const float*)d_in[14];
  const float* f2w = (const float*)d_in[15];
  const float* f2b = (const float*)d_in[16];
  const float* f3w = (const float*)d_in[17];
  const float* f3b = (const float*)d_in[18];
  float* out = (float*)d_out;
  float* ws = (float*)d_ws;

  const int B = 4096;
  float* SUM1 = ws + 0;   float* SQ1 = ws + 12;
  float* SUM2 = ws + 24;  float* SQ2 = ws + 48;
  float* SUM3 = ws + 72;  float* SQ3 = ws + 120;
  float* SUM4 = ws + 168; float* SQ4 = ws + 264;
  float* SC1 = ws + 384;  float* SH1 = ws + 396;
  float* SC2 = ws + 408;  float* SH2 = ws + 432;
  float* SC3 = ws + 456;  float* SH3 = ws + 504;
  float* SC4 = ws + 552;  float* SH4 = ws + 648;
  float* R1 = ws + 1024;                    // B*5400 floats
  float* R2 = ws + 1024 + (size_t)B * 5400; // B*2016 floats
  float* R3 = ws + 1024;                    // aliases R1 (dead after stage2)
  float* R4 = ws + 1024 + (size_t)B * 720;  // B*288 floats

  hipMemsetAsync(d_ws, 0, 384 * sizeof(float), stream);

  k_lift<<<B / NB1, 256, 0, stream>>>(x, w1, R1, SUM1, SQ1);
  k_bnstat<<<1, 128, 0, stream>>>(SUM1, SQ1, g1, b1, SC1, SH1, 12, 1.0f / (float)(B * 450));
  k_stage2<<<(B + NB2 - 1) / NB2, 256, 0, stream>>>(R1, w2, SC1, SH1, R2, SUM2, SQ2, B);
  k_bnstat<<<1, 128, 0, stream>>>(SUM2, SQ2, g2, b2, SC2, SH2, 24, 1.0f / (float)(B * 84));
  k_stage3<<<B / NB3, 256, 0, stream>>>(R2, w3, SC2, SH2, R3, SUM3, SQ3);
  k_bnstat<<<1, 128, 0, stream>>>(SUM3, SQ3, g3, b3, SC3, SH3, 48, 1.0f / (float)(B * 15));
  k_stage4<<<B / NB4, 256, 0, stream>>>(R3, w4, SC3, SH3, R4, SUM4, SQ4);
  k_bnstat<<<1, 128, 0, stream>>>(SUM4, SQ4, g4, b4, SC4, SH4, 96, 1.0f / (float)(B * 3));
  k_fc<<<B / 4, 256, 0, stream>>>(R4, SC4, SH4, f1w, f1b, f2w, f2b, f3w, f3b, out);
}

// Round 7
// 449.759 us; speedup vs baseline: 6.0943x; 1.1375x over previous
//
#include <hip/hip_runtime.h>
#include <hip/hip_fp16.h>

#define EPSBN 2e-5f

// ============================ Stage 1: lift ============================
// x:(B,100,6) w1:(12,6,7) -> r1:(B,12,9,50) fp16 = relu(maxpool2(lift_conv/s))
// Zero-padded fp32 LDS rows (stride 294, 96 left pad). Thread=(bb4, op6, tc10)=240.
#define NB1 4
template<int SI>
__device__ __forceinline__ void s1_si(const float* __restrict__ xb,
    const float* __restrict__ wl, int o0, int t0, bool act, int b,
    __half* __restrict__ r1, float& ts0, float& tq0, float& ts1, float& tq1) {
  constexpr int S = 1 << SI;
  float a0[10], a1[10];
#pragma unroll
  for (int k = 0; k < 10; ++k) { a0[k] = 0.f; a1[k] = 0.f; }
#pragma unroll 1
  for (int c = 0; c < 6; ++c) {
    const float* xr = xb + c * 294 + 96 + t0;
    const float* wp = wl + c * 84 + o0;   // [(c*7+j)*12 + o]
#pragma unroll
    for (int j = 0; j < 7; ++j) {
      const int off = S * (j - 3);
      if (off < -96 || off > 96) continue;     // compile-time dead tap
      const int offE = off & ~1, sh = off & 1;
      float xv[12];
#pragma unroll
      for (int k = 0; k < 6; ++k)
        *(float2*)&xv[2 * k] = *(const float2*)(xr + offE + 2 * k);
      float2 w = *(const float2*)(wp + j * 12);
#pragma unroll
      for (int k = 0; k < 10; ++k) {
        float av = xv[sh + k];
        a0[k] += av * w.x; a1[k] += av * w.y;
      }
    }
  }
  if (act) {
    const float inv = 1.0f / (float)S;
    size_t rb = ((size_t)b * 12 + o0) * 9 + SI;
#pragma unroll
    for (int u = 0; u < 5; ++u) {
      float v0 = fmaxf(fmaxf(a0[2 * u], a0[2 * u + 1]) * inv, 0.f);
      float v1 = fmaxf(fmaxf(a1[2 * u], a1[2 * u + 1]) * inv, 0.f);
      r1[rb * 50 + (t0 >> 1) + u] = __float2half_rn(v0);
      r1[(rb + 9) * 50 + (t0 >> 1) + u] = __float2half_rn(v1);
      ts0 += v0; tq0 += v0 * v0; ts1 += v1; tq1 += v1 * v1;
    }
  }
}

__global__ __launch_bounds__(256) void k_lift(const float* __restrict__ x,
    const float* __restrict__ w1, __half* __restrict__ r1,
    float* __restrict__ sum, float* __restrict__ sq) {
  __shared__ float xs[NB1 * 6 * 294];   // 28.2 KB
  __shared__ float wl[504];             // [c6][j7][o12]
  __shared__ float ssum[12], ssq[12];
  int b0 = blockIdx.x * NB1, tid = threadIdx.x;
  for (int i = tid; i < NB1 * 6 * 294; i += 256) xs[i] = 0.f;
  for (int i = tid; i < 504; i += 256) {
    int o = i / 42, c = (i % 42) / 7, j = i % 7;
    wl[(c * 7 + j) * 12 + o] = w1[i];
  }
  if (tid < 12) { ssum[tid] = 0.f; ssq[tid] = 0.f; }
  __syncthreads();
  for (int i = tid; i < NB1 * 600; i += 256) {
    int bb = i / 600, f = i % 600, t = f / 6, c = f % 6;
    xs[(bb * 6 + c) * 294 + 96 + t] = x[(size_t)(b0 + bb) * 600 + f];
  }
  __syncthreads();
  bool act = tid < 240;
  int task = act ? tid : 0;
  int bb = task / 60, r = task % 60;
  int op = r / 10, tc = r % 10;
  int o0 = op * 2, t0 = tc * 10;
  int b = b0 + bb;
  const float* xb = xs + bb * 6 * 294;
  float ts0 = 0.f, tq0 = 0.f, ts1 = 0.f, tq1 = 0.f;
  s1_si<0>(xb, wl, o0, t0, act, b, r1, ts0, tq0, ts1, tq1);
  s1_si<1>(xb, wl, o0, t0, act, b, r1, ts0, tq0, ts1, tq1);
  s1_si<2>(xb, wl, o0, t0, act, b, r1, ts0, tq0, ts1, tq1);
  s1_si<3>(xb, wl, o0, t0, act, b, r1, ts0, tq0, ts1, tq1);
  s1_si<4>(xb, wl, o0, t0, act, b, r1, ts0, tq0, ts1, tq1);
  s1_si<5>(xb, wl, o0, t0, act, b, r1, ts0, tq0, ts1, tq1);
  s1_si<6>(xb, wl, o0, t0, act, b, r1, ts0, tq0, ts1, tq1);
  s1_si<7>(xb, wl, o0, t0, act, b, r1, ts0, tq0, ts1, tq1);
  s1_si<8>(xb, wl, o0, t0, act, b, r1, ts0, tq0, ts1, tq1);
  if (act) {
    atomicAdd(&ssum[o0], ts0); atomicAdd(&ssq[o0], tq0);
    atomicAdd(&ssum[o0 + 1], ts1); atomicAdd(&ssq[o0 + 1], tq1);
  }
  __syncthreads();
  if (tid < 12) { atomicAdd(&sum[tid], ssum[tid]); atomicAdd(&sq[tid], ssq[tid]); }
}

// ---------------- BN stats -> scale/shift ----------------
__global__ void k_bnstat(const float* __restrict__ sum, const float* __restrict__ sq,
    const float* __restrict__ g, const float* __restrict__ bb,
    float* __restrict__ sc, float* __restrict__ sh, int C, float invN) {
  int c = threadIdx.x;
  if (c < C) {
    float m = sum[c] * invN;
    float v = sq[c] * invN - m * m;
    float scale = g[c] * rsqrtf(v + EPSBN);
    sc[c] = scale;
    sh[c] = bb[c] - m * scale;
  }
}

// ============================ Stage 2 ============================
// r1 fp16 -pool+affine-> LDS fp16 a(12,9,25) rows stride 26; w2 fp16 [c][h][j][o24].
// Out: r2p fp16 (B,24,7,6) = pooled-6; stats from 12-wide values.
#define NB2 5
template<int S, int I2>
__device__ __forceinline__ void s2_do(const __half* __restrict__ ab,
    const __half* __restrict__ wsl, int op, bool act, int b,
    __half* __restrict__ r2p, float& ts0, float& tq0, float& ts1, float& tq1) {
  float acc0[24], acc1[24];
#pragma unroll
  for (int t = 0; t < 24; ++t) { acc0[t] = 0.f; acc1[t] = 0.f; }
#pragma unroll 1
  for (int c = 0; c < 12; ++c) {
#pragma unroll
    for (int h = 0; h < 3; ++h) {
      const __half2* ar = (const __half2*)(ab + (c * 9 + I2 + h) * 26);
      float rr[26];
#pragma unroll
      for (int k = 0; k < 13; ++k) {
        float2 f2 = __half22float2(ar[k]);
        rr[2 * k] = f2.x; rr[2 * k + 1] = f2.y;
      }
#pragma unroll
      for (int j = 0; j < 5; ++j) {
        const int off = S * (j - 2);
        if (off <= -25 || off >= 25) continue;
        float2 w = __half22float2(*(const __half2*)(wsl + ((c * 3 + h) * 5 + j) * 24 + op * 2));
#pragma unroll
        for (int t = 0; t < 24; ++t) {
          if (t + off >= 0 && t + off < 25) {
            float av = rr[t + off];
            acc0[t] += av * w.x; acc1[t] += av * w.y;
          }
        }
      }
    }
  }
  if (act) {
    const float inv = 1.0f / (float)S;
    int o0 = op * 2;
    __half* p0 = r2p + ((size_t)b * 24 + o0) * 42 + I2 * 6;
    __half* p1 = p0 + 42;
    float m0 = 0.f, m1 = 0.f;
#pragma unroll
    for (int u = 0; u < 12; ++u) {
      float v0 = fmaxf(fmaxf(acc0[2 * u], acc0[2 * u + 1]) * inv, 0.f);
      float v1 = fmaxf(fmaxf(acc1[2 * u], acc1[2 * u + 1]) * inv, 0.f);
      ts0 += v0; tq0 += v0 * v0; ts1 += v1; tq1 += v1 * v1;
      if ((u & 1) == 0) { m0 = v0; m1 = v1; }
      else {
        p0[u >> 1] = __float2half_rn(fmaxf(m0, v0));
        p1[u >> 1] = __float2half_rn(fmaxf(m1, v1));
      }
    }
  }
}

__global__ __launch_bounds__(256) void k_stage2(const __half* __restrict__ r1,
    const float* __restrict__ w2, const float* __restrict__ sc, const float* __restrict__ sh,
    __half* __restrict__ r2p, float* __restrict__ sum, float* __restrict__ sq, int B) {
  __shared__ __half as[NB2 * 2810];   // 28.1 KB, bb word-stride 1405 (odd)
  __shared__ __half wsl[4320];        // 8.6 KB, [c][h][j][o24]
  __shared__ float ssum[24], ssq[24];
  int b0 = blockIdx.x * NB2, tid = threadIdx.x;
  for (int i = tid; i < NB2 * 2700; i += 256) {
    int bb = i / 2700, f = i % 2700;
    if (b0 + bb < B) {
      float2 p = __half22float2(((const __half2*)(r1 + (size_t)(b0 + bb) * 5400))[f]);
      int c = f / 225, rw = (f % 225) / 25, xp = f % 25;
      float v = fmaxf(p.x, p.y) * sc[c] + sh[c];
      as[bb * 2810 + (c * 9 + rw) * 26 + xp] = __float2half_rn(v);
    }
  }
  for (int i = tid; i < 4320; i += 256) {
    int o = i / 180, c = (i % 180) / 15, h = (i % 15) / 5, j = i % 5;
    wsl[((c * 3 + h) * 5 + j) * 24 + o] = __float2half_rn(w2[i]);
  }
  if (tid < 24) { ssum[tid] = 0.f; ssq[tid] = 0.f; }
  __syncthreads();
  int wv = tid >> 6, lane = tid & 63;
  int bb = lane / 12, op = lane % 12;
  bool act = (lane < 60) && (b0 + bb < B);
  if (bb > 4) bb = 4;
  const __half* ab = as + bb * 2810;
  int b = b0 + bb;
  float ts0 = 0.f, tq0 = 0.f, ts1 = 0.f, tq1 = 0.f;
  // valid-term balance: {0}=116, {1,6}=134, {2,5}=122, {3,4}=115
  if (wv == 0) {
    s2_do<1, 0>(ab, wsl, op, act, b, r2p, ts0, tq0, ts1, tq1);
  } else if (wv == 1) {
    s2_do<2, 1>(ab, wsl, op, act, b, r2p, ts0, tq0, ts1, tq1);
    s2_do<64, 6>(ab, wsl, op, act, b, r2p, ts0, tq0, ts1, tq1);
  } else if (wv == 2) {
    s2_do<4, 2>(ab, wsl, op, act, b, r2p, ts0, tq0, ts1, tq1);
    s2_do<32, 5>(ab, wsl, op, act, b, r2p, ts0, tq0, ts1, tq1);
  } else {
    s2_do<8, 3>(ab, wsl, op, act, b, r2p, ts0, tq0, ts1, tq1);
    s2_do<16, 4>(ab, wsl, op, act, b, r2p, ts0, tq0, ts1, tq1);
  }
  if (act) {
    int o0 = op * 2;
    atomicAdd(&ssum[o0], ts0); atomicAdd(&ssq[o0], tq0);
    atomicAdd(&ssum[o0 + 1], ts1); atomicAdd(&ssq[o0 + 1], tq1);
  }
  __syncthreads();
  if (tid < 24) { atomicAdd(&sum[tid], ssum[tid]); atomicAdd(&sq[tid], ssq[tid]); }
}

// ============================ Stage 3 ============================
// r2p fp16 (B,24,7,6) -affine-> LDS fp16; w3 fp16 full [c24][h3][j5][o48].
// Thread=(bb8, op24)=192; out r3 fp16 (B,48,5,3).
#define NB3 8
template<int I2>
__device__ __forceinline__ void s3_acc(const float* __restrict__ rr,
    const float2* __restrict__ wr, float* __restrict__ acc) {
  constexpr int S = 1 << I2;
#pragma unroll
  for (int h = 0; h < 3; ++h) {
    const int base = (I2 + h) * 6;
#pragma unroll
    for (int j = 0; j < 5; ++j) {
      const int off = S * (j - 2);
      if (off <= -6 || off >= 6) continue;
      float2 w = wr[h * 5 + j];
#pragma unroll
      for (int t = 0; t < 6; ++t) {
        if (t + off >= 0 && t + off < 6) {
          float av = rr[base + t + off];
          acc[t] += av * w.x; acc[6 + t] += av * w.y;
        }
      }
    }
  }
}

__global__ __launch_bounds__(256) void k_stage3(const __half* __restrict__ r2p,
    const float* __restrict__ w3, const float* __restrict__ sc, const float* __restrict__ sh,
    __half* __restrict__ r3, float* __restrict__ sum, float* __restrict__ sq) {
  __shared__ __half as[NB3 * 1010];   // 16.2 KB, bb word-stride 505
  __shared__ __half wsl[17280];       // 34.6 KB full weights
  __shared__ float ssum[48], ssq[48];
  int b0 = blockIdx.x * NB3, tid = threadIdx.x;
  for (int i = tid; i < NB3 * 504; i += 256) {
    int bb = i / 504, f = i % 504;
    float2 p = __half22float2(((const __half2*)(r2p + (size_t)(b0 + bb) * 1008))[f]);
    int c = f / 21;
    ((__half2*)(as + bb * 1010))[f] = __floats2half2_rn(p.x * sc[c] + sh[c], p.y * sc[c] + sh[c]);
  }
  for (int i = tid; i < 17280; i += 256) {
    int o = i / 360, c = (i % 360) / 15, hj = i % 15;
    wsl[(c * 15 + hj) * 48 + o] = __float2half_rn(w3[i]);
  }
  if (tid < 48) { ssum[tid] = 0.f; ssq[tid] = 0.f; }
  __syncthreads();
  bool act = tid < 192;
  int bb = act ? tid / 24 : 0, op = tid % 24;
  const __half* ab = as + bb * 1010;
  int b = b0 + bb;
  if (act) {
    float acc[60];   // [i2 5][o2][t6]
#pragma unroll
    for (int k = 0; k < 60; ++k) acc[k] = 0.f;
#pragma unroll 1
    for (int c = 0; c < 24; ++c) {
      float rr[42];
      const __half2* ar = (const __half2*)(ab + c * 42);
#pragma unroll
      for (int k = 0; k < 21; ++k) {
        float2 f2 = __half22float2(ar[k]);
        rr[2 * k] = f2.x; rr[2 * k + 1] = f2.y;
      }
      float2 wr[15];
#pragma unroll
      for (int hj = 0; hj < 15; ++hj)
        wr[hj] = __half22float2(*(const __half2*)(wsl + (c * 15 + hj) * 48 + op * 2));
      s3_acc<0>(rr, wr, acc);
      s3_acc<1>(rr, wr, acc + 12);
      s3_acc<2>(rr, wr, acc + 24);
      s3_acc<3>(rr, wr, acc + 36);
      s3_acc<4>(rr, wr, acc + 48);
    }
    float ts0 = 0.f, tq0 = 0.f, ts1 = 0.f, tq1 = 0.f;
    int ob = op * 2;
#pragma unroll
    for (int i2 = 0; i2 < 5; ++i2) {
      const float inv = 1.0f / (float)(1 << i2);
      size_t rb0 = ((size_t)b * 48 + ob) * 15 + i2 * 3;
#pragma unroll
      for (int u = 0; u < 3; ++u) {
        float v0 = fmaxf(fmaxf(acc[i2 * 12 + 2 * u], acc[i2 * 12 + 2 * u + 1]) * inv, 0.f);
        float v1 = fmaxf(fmaxf(acc[i2 * 12 + 6 + 2 * u], acc[i2 * 12 + 7 + 2 * u]) * inv, 0.f);
        r3[rb0 + u] = __float2half_rn(v0);
        r3[rb0 + 15 + u] = __float2half_rn(v1);
        ts0 += v0; tq0 += v0 * v0; ts1 += v1; tq1 += v1 * v1;
      }
    }
    atomicAdd(&ssum[ob], ts0); atomicAdd(&ssq[ob], tq0);
    atomicAdd(&ssum[ob + 1], ts1); atomicAdd(&ssq[ob + 1], tq1);
  }
  __syncthreads();
  if (tid < 48) { atomicAdd(&sum[tid], ssum[tid]); atomicAdd(&sq[tid], ssq[tid]); }
}

// ============================ Stage 4 ============================
// r3 fp16 (B,48,5,3) -affine-> LDS fp16 rows c*16; w4 fp16 48-o chunks.
// Thread=(bb4, ox48)=192, o-single; out r4 fp32 (B,96,3).
#define NB4 4
template<int I2>
__device__ __forceinline__ void s4_acc(const float* __restrict__ rr,
    const float* __restrict__ wv, float* __restrict__ acc) {
  constexpr int S = 1 << I2;
#pragma unroll
  for (int h = 0; h < 3; ++h) {
    const int base = (I2 + h) * 3;
#pragma unroll
    for (int j = 0; j < 3; ++j) {
      const int off = S * (j - 1);
      if (off <= -3 || off >= 3) continue;
      float w = wv[h * 3 + j];
      if (off >= 0) acc[0] += rr[base + off] * w;
      const int i1 = 1 + off;
      if (i1 >= 0 && i1 < 3) acc[1] += rr[base + i1] * w;
    }
  }
}

__global__ __launch_bounds__(256) void k_stage4(const __half* __restrict__ r3,
    const float* __restrict__ w4, const float* __restrict__ sc, const float* __restrict__ sh,
    float* __restrict__ r4, float* __restrict__ sum, float* __restrict__ sq) {
  __shared__ __half as[NB4 * 770];    // 6.2 KB, bb word-stride 385
  __shared__ __half wsl[20736];       // 41.5 KB, 48-o chunk: [c][h][j][o48]
  __shared__ float ssum[96], ssq[96];
  int b0 = blockIdx.x * NB4, tid = threadIdx.x;
  for (int i = tid; i < NB4 * 720; i += 256) {
    int bb = i / 720, f = i % 720, c = f / 15;
    float v = __half2float(r3[(size_t)(b0 + bb) * 720 + f]) * sc[c] + sh[c];
    as[bb * 770 + c * 16 + (f % 15)] = __float2half_rn(v);
  }
  if (tid < 96) { ssum[tid] = 0.f; ssq[tid] = 0.f; }
  bool act = tid < 192;
  int bb = act ? tid / 48 : 0, ox = tid % 48;
  const __half* ab = as + bb * 770;
  int b = b0 + bb;
  for (int chunk = 0; chunk < 2; ++chunk) {
    __syncthreads();
    for (int i = tid; i < 20736; i += 256) {
      int oo = i / 432, c = (i % 432) / 9, hj = i % 9;
      wsl[(c * 9 + hj) * 48 + oo] = __float2half_rn(w4[(size_t)chunk * 20736 + i]);
    }
    __syncthreads();
    if (act) {
      float acc[6];   // [i2 3][t2]
#pragma unroll
      for (int k = 0; k < 6; ++k) acc[k] = 0.f;
#pragma unroll 1
      for (int c = 0; c < 48; ++c) {
        float rr[16];
        const __half2* ar = (const __half2*)(ab + c * 16);
#pragma unroll
        for (int k = 0; k < 8; ++k) {
          float2 f2 = __half22float2(ar[k]);
          rr[2 * k] = f2.x; rr[2 * k + 1] = f2.y;
        }
        float wv[9];
        const __half* wp = wsl + c * 9 * 48 + ox;
#pragma unroll
        for (int hj = 0; hj < 9; ++hj) wv[hj] = __half2float(wp[hj * 48]);
        s4_acc<0>(rr, wv, acc);
        s4_acc<1>(rr, wv, acc + 2);
        s4_acc<2>(rr, wv, acc + 4);
      }
      int o = chunk * 48 + ox;
      float ts = 0.f, tq = 0.f;
#pragma unroll
      for (int i2 = 0; i2 < 3; ++i2) {
        const float inv = 1.0f / (float)(1 << i2);
        float v = fmaxf(fmaxf(acc[i2 * 2], acc[i2 * 2 + 1]) * inv, 0.f);
        r4[(size_t)b * 288 + o * 3 + i2] = v;
        ts += v; tq += v * v;
      }
      atomicAdd(&ssum[o], ts); atomicAdd(&ssq[o], tq);
    }
  }
  __syncthreads();
  if (tid < 96) { atomicAdd(&sum[tid], ssum[tid]); atomicAdd(&sq[tid], ssq[tid]); }
}

// ---------------- FC head: BN4-affine + 288->96->48->6 ----------------
__global__ __launch_bounds__(256) void k_fc(const float* __restrict__ r4,
    const float* __restrict__ sc, const float* __restrict__ sh,
    const float* __restrict__ f1w, const float* __restrict__ f1b,
    const float* __restrict__ f2w, const float* __restrict__ f2b,
    const float* __restrict__ f3w, const float* __restrict__ f3b,
    float* __restrict__ out) {
  __shared__ float v[4][288];
  __shared__ float h1[4][96];
  __shared__ float h2[4][48];
  int b0 = blockIdx.x * 4, tid = threadIdx.x;
  for (int i = tid; i < 4 * 288; i += 256) {
    int bb = i / 288, f = i % 288, c = f / 3;
    v[bb][f] = r4[(size_t)(b0 + bb) * 288 + f] * sc[c] + sh[c];
  }
  __syncthreads();
  for (int d = tid; d < 384; d += 256) {
    int o = d >> 2, bb = d & 3;
    const float* wr = &f1w[o * 288];
    const float* vv = v[bb];
    float acc = f1b[o];
    for (int f = 0; f < 288; ++f) acc += wr[f] * vv[f];
    h1[bb][o] = acc;
  }
  __syncthreads();
  if (tid < 192) {
    int o = tid >> 2, bb = tid & 3;
    const float* wr = &f2w[o * 96];
    float acc = f2b[o];
    for (int f = 0; f < 96; ++f) acc += wr[f] * h1[bb][f];
    h2[bb][o] = acc;
  }
  __syncthreads();
  if (tid < 24) {
    int o = tid >> 2, bb = tid & 3;
    const float* wr = &f3w[o * 48];
    float acc = f3b[o];
    for (int f = 0; f < 48; ++f) acc += wr[f] * h2[bb][f];
    out[(size_t)(b0 + bb) * 6 + o] = acc;
  }
}

extern "C" void kernel_launch(void* const* d_in, const int* in_sizes, int n_in,
                              void* d_out, int out_size, void* d_ws, size_t ws_size,
                              hipStream_t stream) {
  const float* x   = (const float*)d_in[0];
  const float* w1  = (const float*)d_in[1];
  const float* w2  = (const float*)d_in[2];
  const float* w3  = (const float*)d_in[3];
  const float* w4  = (const float*)d_in[4];
  const float* g1  = (const float*)d_in[5];
  const float* b1  = (const float*)d_in[6];
  const float* g2  = (const float*)d_in[7];
  const float* b2  = (const float*)d_in[8];
  const float* g3  = (const float*)d_in[9];
  const float* b3  = (const float*)d_in[10];
  const float* g4  = (const float*)d_in[11];
  const float* b4  = (const float*)d_in[12];
  const float* f1w = (const float*)d_in[13];
  const float* f1b = (const float*)d_in[14];
  const float* f2w = (const float*)d_in[15];
  const float* f2b = (const float*)d_in[16];
  const float* f3w = (const float*)d_in[17];
  const float* f3b = (const float*)d_in[18];
  float* out = (float*)d_out;
  float* ws = (float*)d_ws;

  const int B = 4096;
  float* SUM1 = ws + 0;   float* SQ1 = ws + 12;
  float* SUM2 = ws + 24;  float* SQ2 = ws + 48;
  float* SUM3 = ws + 72;  float* SQ3 = ws + 120;
  float* SUM4 = ws + 168; float* SQ4 = ws + 264;
  float* SC1 = ws + 384;  float* SH1 = ws + 396;
  float* SC2 = ws + 408;  float* SH2 = ws + 432;
  float* SC3 = ws + 456;  float* SH3 = ws + 504;
  float* SC4 = ws + 552;  float* SH4 = ws + 648;
  __half* R1h = (__half*)(ws + 1024);                 // B*5400 halfs
  __half* R2p = R1h + (size_t)B * 5400;               // B*1008 halfs
  __half* R3h = R1h;                                  // alias (R1 dead after stage2)
  float*  R4  = (float*)(R2p + (size_t)B * 1008);     // B*288 floats

  hipMemsetAsync(d_ws, 0, 384 * sizeof(float), stream);

  k_lift<<<B / NB1, 256, 0, stream>>>(x, w1, R1h, SUM1, SQ1);
  k_bnstat<<<1, 128, 0, stream>>>(SUM1, SQ1, g1, b1, SC1, SH1, 12, 1.0f / (float)(B * 450));
  k_stage2<<<(B + NB2 - 1) / NB2, 256, 0, stream>>>(R1h, w2, SC1, SH1, R2p, SUM2, SQ2, B);
  k_bnstat<<<1, 128, 0, stream>>>(SUM2, SQ2, g2, b2, SC2, SH2, 24, 1.0f / (float)(B * 84));
  k_stage3<<<B / NB3, 256, 0, stream>>>(R2p, w3, SC2, SH2, R3h, SUM3, SQ3);
  k_bnstat<<<1, 128, 0, stream>>>(SUM3, SQ3, g3, b3, SC3, SH3, 48, 1.0f / (float)(B * 15));
  k_stage4<<<B / NB4, 256, 0, stream>>>(R3h, w4, SC3, SH3, R4, SUM4, SQ4);
  k_bnstat<<<1, 128, 0, stream>>>(SUM4, SQ4, g4, b4, SC4, SH4, 96, 1.0f / (float)(B * 3));
  k_fc<<<B / 4, 256, 0, stream>>>(R4, SC4, SH4, f1w, f1b, f2w, f2b, f3w, f3b, out);
}

// Round 8
// 321.290 us; speedup vs baseline: 8.5311x; 1.3999x over previous
//
#include <hip/hip_runtime.h>
#include <hip/hip_fp16.h>

#define EPSBN 2e-5f

typedef _Float16 hf2 __attribute__((ext_vector_type(2)));

static __device__ __forceinline__ float fdot2h(hf2 a, hf2 b, float c) {
  return __builtin_amdgcn_fdot2(a, b, c, false);
}
static __device__ __forceinline__ unsigned pk(float a, float b) {
  union { __half2 h; unsigned u; } u;
  u.h = __floats2half2_rn(a, b);
  return u.u;
}

// ============ Prep: pack weights to fp16 channel-pair layouts ============
// W1P [cp3][j7][o12][2]  W2P [cp6][h3][j5][o24][2]
// W3P [cp12][h3][j5][o48][2]  W4P [chunk2][cp24][h3][j3][o48][2]
__global__ __launch_bounds__(256) void k_prep(const float* __restrict__ w1,
    const float* __restrict__ w2, const float* __restrict__ w3, const float* __restrict__ w4,
    __half* __restrict__ W1P, __half* __restrict__ W2P,
    __half* __restrict__ W3P, __half* __restrict__ W4P) {
  int i = blockIdx.x * 256 + threadIdx.x;
  if (i < 504) {
    int ci = i & 1, r = i >> 1, o = r % 12, j = (r / 12) % 7, cp = r / 84, c = 2 * cp + ci;
    W1P[i] = __float2half_rn(w1[(o * 6 + c) * 7 + j]);
  }
  if (i < 4320) {
    int ci = i & 1, r = i >> 1, o = r % 24, j = (r / 24) % 5, h = (r / 120) % 3, cp = r / 360;
    int c = 2 * cp + ci;
    W2P[i] = __float2half_rn(w2[((o * 12 + c) * 3 + h) * 5 + j]);
  }
  if (i < 17280) {
    int ci = i & 1, r = i >> 1, o = r % 48, j = (r / 48) % 5, h = (r / 240) % 3, cp = r / 720;
    int c = 2 * cp + ci;
    W3P[i] = __float2half_rn(w3[((o * 24 + c) * 3 + h) * 5 + j]);
  }
  if (i < 41472) {
    int ci = i & 1, r = i >> 1, o48 = r % 48, j = (r / 48) % 3, h = (r / 144) % 3;
    int cp = (r / 432) % 24, ch = r / 10368, c = 2 * cp + ci, o = ch * 48 + o48;
    W4P[i] = __float2half_rn(w4[((o * 48 + c) * 3 + h) * 3 + j]);
  }
}

// ============================ Stage 1: lift ============================
// x:(B,100,6) -> LDS half2 c-pairs, zero-padded rows (stride 295 dw, 96 left pad).
// Thread=(bb4, op6, tc10)=240. r1 fp16 (B,12,9,50).
#define NB1 4
template<int SI>
__device__ __forceinline__ void s1_si(const unsigned* __restrict__ xsu, int bb, int t0,
    const unsigned* __restrict__ wlu, int o0, bool act, int b,
    __half* __restrict__ r1, float& ts0, float& tq0, float& ts1, float& tq1) {
  constexpr int S = 1 << SI;
  float a0[10], a1[10];
#pragma unroll
  for (int k = 0; k < 10; ++k) { a0[k] = 0.f; a1[k] = 0.f; }
#pragma unroll 1
  for (int cp = 0; cp < 3; ++cp) {
    const hf2* xr = (const hf2*)xsu + (bb * 3 + cp) * 295 + 96 + t0;
    const unsigned* wp = wlu + cp * 84;   // dword idx (cp*7+j)*12+o
#pragma unroll
    for (int j = 0; j < 7; ++j) {
      const int off = S * (j - 3);
      if (off < -96 || off > 98) continue;   // compile-time dead tap (zero-pad covers rest)
      hf2 w0 = *(const hf2*)(wp + j * 12 + o0);
      hf2 w1 = *(const hf2*)(wp + j * 12 + o0 + 1);
      hf2 xv[10];
#pragma unroll
      for (int k = 0; k < 10; ++k) xv[k] = xr[off + k];
#pragma unroll
      for (int k = 0; k < 10; ++k) {
        a0[k] = fdot2h(xv[k], w0, a0[k]);
        a1[k] = fdot2h(xv[k], w1, a1[k]);
      }
    }
  }
  if (act) {
    const float inv = 1.0f / (float)S;
    size_t rb = ((size_t)b * 12 + o0) * 9 + SI;
#pragma unroll
    for (int u = 0; u < 5; ++u) {
      float v0 = fmaxf(fmaxf(a0[2 * u], a0[2 * u + 1]) * inv, 0.f);
      float v1 = fmaxf(fmaxf(a1[2 * u], a1[2 * u + 1]) * inv, 0.f);
      r1[rb * 50 + (t0 >> 1) + u] = __float2half_rn(v0);
      r1[(rb + 9) * 50 + (t0 >> 1) + u] = __float2half_rn(v1);
      ts0 += v0; tq0 += v0 * v0; ts1 += v1; tq1 += v1 * v1;
    }
  }
}

__global__ __launch_bounds__(256) void k_lift(const float* __restrict__ x,
    const __half* __restrict__ W1P, __half* __restrict__ r1,
    float* __restrict__ sum, float* __restrict__ sq) {
  __shared__ unsigned xsu[NB1 * 885];   // 14.2 KB: [bb][cp3][295 dw]
  __shared__ unsigned wlu[252];
  __shared__ float ssum[12], ssq[12];
  int b0 = blockIdx.x * NB1, tid = threadIdx.x;
  for (int i = tid; i < NB1 * 885; i += 256) xsu[i] = 0u;
  for (int i = tid; i < 252; i += 256) wlu[i] = ((const unsigned*)W1P)[i];
  if (tid < 12) { ssum[tid] = 0.f; ssq[tid] = 0.f; }
  __syncthreads();
  __half* xsh = (__half*)xsu;
  for (int i = tid; i < NB1 * 600; i += 256) {
    int bb = i / 600, f = i % 600, t = f / 6, c = f % 6;
    xsh[((bb * 3 + (c >> 1)) * 295 + 96 + t) * 2 + (c & 1)] =
        __float2half_rn(x[(size_t)(b0 + bb) * 600 + f]);
  }
  __syncthreads();
  bool act = tid < 240;
  int task = act ? tid : 0;
  int bb = task / 60, r = task % 60;
  int op = r / 10, tc = r % 10;
  int o0 = op * 2, t0 = tc * 10;
  int b = b0 + bb;
  float ts0 = 0.f, tq0 = 0.f, ts1 = 0.f, tq1 = 0.f;
  s1_si<0>(xsu, bb, t0, wlu, o0, act, b, r1, ts0, tq0, ts1, tq1);
  s1_si<1>(xsu, bb, t0, wlu, o0, act, b, r1, ts0, tq0, ts1, tq1);
  s1_si<2>(xsu, bb, t0, wlu, o0, act, b, r1, ts0, tq0, ts1, tq1);
  s1_si<3>(xsu, bb, t0, wlu, o0, act, b, r1, ts0, tq0, ts1, tq1);
  s1_si<4>(xsu, bb, t0, wlu, o0, act, b, r1, ts0, tq0, ts1, tq1);
  s1_si<5>(xsu, bb, t0, wlu, o0, act, b, r1, ts0, tq0, ts1, tq1);
  s1_si<6>(xsu, bb, t0, wlu, o0, act, b, r1, ts0, tq0, ts1, tq1);
  s1_si<7>(xsu, bb, t0, wlu, o0, act, b, r1, ts0, tq0, ts1, tq1);
  s1_si<8>(xsu, bb, t0, wlu, o0, act, b, r1, ts0, tq0, ts1, tq1);
  if (act) {
    atomicAdd(&ssum[o0], ts0); atomicAdd(&ssq[o0], tq0);
    atomicAdd(&ssum[o0 + 1], ts1); atomicAdd(&ssq[o0 + 1], tq1);
  }
  __syncthreads();
  if (tid < 12) { atomicAdd(&sum[tid], ssum[tid]); atomicAdd(&sq[tid], ssq[tid]); }
}

// ---------------- BN stats -> scale/shift ----------------
__global__ void k_bnstat(const float* __restrict__ sum, const float* __restrict__ sq,
    const float* __restrict__ g, const float* __restrict__ bb,
    float* __restrict__ sc, float* __restrict__ sh, int C, float invN) {
  int c = threadIdx.x;
  if (c < C) {
    float m = sum[c] * invN;
    float v = sq[c] * invN - m * m;
    float scale = g[c] * rsqrtf(v + EPSBN);
    sc[c] = scale;
    sh[c] = bb[c] - m * scale;
  }
}

// ============================ Stage 2 ============================
// LDS act: [bb][cp6][row9][t26] half2 (c-pair), dword stride/bb 1405.
// Out r2p fp16 (B,24,7,6) pooled-6; stats from 12-wide values.
#define NB2 5
template<int S, int I2>
__device__ __forceinline__ void s2_do(const unsigned* __restrict__ abu,
    const unsigned* __restrict__ wlu, int op, bool act, int b,
    __half* __restrict__ r2p, float& ts0, float& tq0, float& ts1, float& tq1) {
  float acc0[24], acc1[24];
#pragma unroll
  for (int t = 0; t < 24; ++t) { acc0[t] = 0.f; acc1[t] = 0.f; }
#pragma unroll 1
  for (int cp = 0; cp < 6; ++cp) {
#pragma unroll
    for (int h = 0; h < 3; ++h) {
      const hf2* ar = (const hf2*)(abu + (cp * 9 + I2 + h) * 26);
      hf2 rr[25];
#pragma unroll
      for (int t = 0; t < 25; ++t) rr[t] = ar[t];
      const unsigned* wp = wlu + ((cp * 3 + h) * 5) * 24 + op * 2;
#pragma unroll
      for (int j = 0; j < 5; ++j) {
        const int off = S * (j - 2);
        if (off <= -25 || off >= 25) continue;
        hf2 w0 = *(const hf2*)(wp + j * 24);
        hf2 w1 = *(const hf2*)(wp + j * 24 + 1);
#pragma unroll
        for (int t = 0; t < 24; ++t) {
          if (t + off >= 0 && t + off < 25) {
            acc0[t] = fdot2h(rr[t + off], w0, acc0[t]);
            acc1[t] = fdot2h(rr[t + off], w1, acc1[t]);
          }
        }
      }
    }
  }
  if (act) {
    const float inv = 1.0f / (float)S;
    int o0 = op * 2;
    __half* p0 = r2p + ((size_t)b * 24 + o0) * 42 + I2 * 6;
    __half* p1 = p0 + 42;
    float m0 = 0.f, m1 = 0.f;
#pragma unroll
    for (int u = 0; u < 12; ++u) {
      float v0 = fmaxf(fmaxf(acc0[2 * u], acc0[2 * u + 1]) * inv, 0.f);
      float v1 = fmaxf(fmaxf(acc1[2 * u], acc1[2 * u + 1]) * inv, 0.f);
      ts0 += v0; tq0 += v0 * v0; ts1 += v1; tq1 += v1 * v1;
      if ((u & 1) == 0) { m0 = v0; m1 = v1; }
      else {
        p0[u >> 1] = __float2half_rn(fmaxf(m0, v0));
        p1[u >> 1] = __float2half_rn(fmaxf(m1, v1));
      }
    }
  }
}

__global__ __launch_bounds__(256) void k_stage2(const __half* __restrict__ r1,
    const __half* __restrict__ W2P, const float* __restrict__ sc, const float* __restrict__ sh,
    __half* __restrict__ r2p, float* __restrict__ sum, float* __restrict__ sq, int B) {
  __shared__ unsigned asu[NB2 * 1405];  // 28.1 KB
  __shared__ unsigned wlu[2160];        // 8.6 KB
  __shared__ float ssum[24], ssq[24];
  int b0 = blockIdx.x * NB2, tid = threadIdx.x;
  for (int i = tid; i < NB2 * 1350; i += 256) {
    int bb = i / 1350, s = i % 1350;
    if (b0 + bb < B) {
      int cp = s / 225, rem = s % 225, row = rem / 25, t = rem % 25;
      int c0 = 2 * cp, c1 = c0 + 1;
      float2 a0 = __half22float2(*(const __half2*)(r1 +
          (((size_t)(b0 + bb) * 12 + c0) * 9 + row) * 50 + 2 * t));
      float2 a1 = __half22float2(*(const __half2*)(r1 +
          (((size_t)(b0 + bb) * 12 + c1) * 9 + row) * 50 + 2 * t));
      float v0 = fmaxf(a0.x, a0.y) * sc[c0] + sh[c0];
      float v1 = fmaxf(a1.x, a1.y) * sc[c1] + sh[c1];
      asu[bb * 1405 + (cp * 9 + row) * 26 + t] = pk(v0, v1);
    }
  }
  for (int i = tid; i < 540; i += 256)
    ((uint4*)wlu)[i] = ((const uint4*)W2P)[i];
  if (tid < 24) { ssum[tid] = 0.f; ssq[tid] = 0.f; }
  __syncthreads();
  int wv = tid >> 6, lane = tid & 63;
  int bb = lane / 12, op = lane % 12;
  bool act = (lane < 60) && (b0 + bb < B);
  if (bb > 4) bb = 4;
  const unsigned* abu = asu + bb * 1405;
  int b = b0 + bb;
  float ts0 = 0.f, tq0 = 0.f, ts1 = 0.f, tq1 = 0.f;
  if (wv == 0) {
    s2_do<1, 0>(abu, wlu, op, act, b, r2p, ts0, tq0, ts1, tq1);
  } else if (wv == 1) {
    s2_do<2, 1>(abu, wlu, op, act, b, r2p, ts0, tq0, ts1, tq1);
    s2_do<64, 6>(abu, wlu, op, act, b, r2p, ts0, tq0, ts1, tq1);
  } else if (wv == 2) {
    s2_do<4, 2>(abu, wlu, op, act, b, r2p, ts0, tq0, ts1, tq1);
    s2_do<32, 5>(abu, wlu, op, act, b, r2p, ts0, tq0, ts1, tq1);
  } else {
    s2_do<8, 3>(abu, wlu, op, act, b, r2p, ts0, tq0, ts1, tq1);
    s2_do<16, 4>(abu, wlu, op, act, b, r2p, ts0, tq0, ts1, tq1);
  }
  if (act) {
    int o0 = op * 2;
    atomicAdd(&ssum[o0], ts0); atomicAdd(&ssq[o0], tq0);
    atomicAdd(&ssum[o0 + 1], ts1); atomicAdd(&ssq[o0 + 1], tq1);
  }
  __syncthreads();
  if (tid < 24) { atomicAdd(&sum[tid], ssum[tid]); atomicAdd(&sq[tid], ssq[tid]); }
}

// ============================ Stage 3 ============================
// LDS act [bb8][cp12][row7][t6] half2, dw stride/bb 505; full W3P in LDS.
// Thread=(bb8, op24)=192; out r3 fp16 (B,48,5,3).
#define NB3 8
template<int I2>
__device__ __forceinline__ void s3h(const hf2* __restrict__ rr, int h,
    const hf2* __restrict__ w0, const hf2* __restrict__ w1, float* __restrict__ acc) {
  constexpr int S = 1 << I2;
  const int base = (I2 + h) * 6;
#pragma unroll
  for (int j = 0; j < 5; ++j) {
    const int off = S * (j - 2);
    if (off <= -6 || off >= 6) continue;
#pragma unroll
    for (int t = 0; t < 6; ++t) {
      if (t + off >= 0 && t + off < 6) {
        acc[t] = fdot2h(rr[base + t + off], w0[j], acc[t]);
        acc[6 + t] = fdot2h(rr[base + t + off], w1[j], acc[6 + t]);
      }
    }
  }
}

__global__ __launch_bounds__(256) void k_stage3(const __half* __restrict__ r2p,
    const __half* __restrict__ W3P, const float* __restrict__ sc, const float* __restrict__ sh,
    __half* __restrict__ r3, float* __restrict__ sum, float* __restrict__ sq) {
  __shared__ unsigned asu[NB3 * 505];   // 16.2 KB
  __shared__ unsigned wlu[8640];        // 34.6 KB
  __shared__ float ssum[48], ssq[48];
  int b0 = blockIdx.x * NB3, tid = threadIdx.x;
  for (int i = tid; i < NB3 * 252; i += 256) {
    int bb = i / 252, s = i % 252;
    int cp = s / 21, rem = s % 21, row = rem / 3, tp = rem % 3;
    int c0 = 2 * cp, c1 = c0 + 1;
    float2 a0 = __half22float2(*(const __half2*)(r2p +
        (((size_t)(b0 + bb) * 24 + c0) * 7 + row) * 6 + 2 * tp));
    float2 a1 = __half22float2(*(const __half2*)(r2p +
        (((size_t)(b0 + bb) * 24 + c1) * 7 + row) * 6 + 2 * tp));
    float v00 = a0.x * sc[c0] + sh[c0], v01 = a0.y * sc[c0] + sh[c0];
    float v10 = a1.x * sc[c1] + sh[c1], v11 = a1.y * sc[c1] + sh[c1];
    int di = bb * 505 + (cp * 7 + row) * 6 + 2 * tp;
    asu[di] = pk(v00, v10);
    asu[di + 1] = pk(v01, v11);
  }
  for (int i = tid; i < 2160; i += 256)
    ((uint4*)wlu)[i] = ((const uint4*)W3P)[i];
  if (tid < 48) { ssum[tid] = 0.f; ssq[tid] = 0.f; }
  __syncthreads();
  bool act = tid < 192;
  int bb = act ? tid / 24 : 0, op = tid % 24;
  int b = b0 + bb;
  if (act) {
    float acc[60];
#pragma unroll
    for (int k = 0; k < 60; ++k) acc[k] = 0.f;
#pragma unroll 1
    for (int cp = 0; cp < 12; ++cp) {
      const hf2* ar = (const hf2*)(asu + bb * 505 + cp * 42);
      hf2 rr[42];
#pragma unroll
      for (int k = 0; k < 42; ++k) rr[k] = ar[k];
#pragma unroll
      for (int h = 0; h < 3; ++h) {
        const unsigned* wp = wlu + (cp * 15 + h * 5) * 48 + op * 2;
        hf2 w0[5], w1[5];
#pragma unroll
        for (int j = 0; j < 5; ++j) {
          w0[j] = *(const hf2*)(wp + j * 48);
          w1[j] = *(const hf2*)(wp + j * 48 + 1);
        }
        s3h<0>(rr, h, w0, w1, acc);
        s3h<1>(rr, h, w0, w1, acc + 12);
        s3h<2>(rr, h, w0, w1, acc + 24);
        s3h<3>(rr, h, w0, w1, acc + 36);
        s3h<4>(rr, h, w0, w1, acc + 48);
      }
    }
    float ts0 = 0.f, tq0 = 0.f, ts1 = 0.f, tq1 = 0.f;
    int ob = op * 2;
#pragma unroll
    for (int i2 = 0; i2 < 5; ++i2) {
      const float inv = 1.0f / (float)(1 << i2);
      size_t rb0 = ((size_t)b * 48 + ob) * 15 + i2 * 3;
#pragma unroll
      for (int u = 0; u < 3; ++u) {
        float v0 = fmaxf(fmaxf(acc[i2 * 12 + 2 * u], acc[i2 * 12 + 2 * u + 1]) * inv, 0.f);
        float v1 = fmaxf(fmaxf(acc[i2 * 12 + 6 + 2 * u], acc[i2 * 12 + 7 + 2 * u]) * inv, 0.f);
        r3[rb0 + u] = __float2half_rn(v0);
        r3[rb0 + 15 + u] = __float2half_rn(v1);
        ts0 += v0; tq0 += v0 * v0; ts1 += v1; tq1 += v1 * v1;
      }
    }
    atomicAdd(&ssum[ob], ts0); atomicAdd(&ssq[ob], tq0);
    atomicAdd(&ssum[ob + 1], ts1); atomicAdd(&ssq[ob + 1], tq1);
  }
  __syncthreads();
  if (tid < 48) { atomicAdd(&sum[tid], ssum[tid]); atomicAdd(&sq[tid], ssq[tid]); }
}

// ============================ Stage 4 ============================
// LDS act [bb8][cp24][row5][t3] half2, dw stride/bb 361; W4P per 48-o chunk.
// Thread=(bb8, op24)=192; out r4 fp32 (B,96,3).
#define NB4 8
template<int I2>
__device__ __forceinline__ void s4h(const hf2* __restrict__ rr, int h,
    const hf2* __restrict__ w0, const hf2* __restrict__ w1, float* __restrict__ acc) {
  constexpr int S = 1 << I2;
  const int base = (I2 + h) * 3;
#pragma unroll
  for (int j = 0; j < 3; ++j) {
    const int off = S * (j - 1);
    if (off <= -3 || off >= 3) continue;
    if (off >= 0) {
      acc[0] = fdot2h(rr[base + off], w0[j], acc[0]);
      acc[2] = fdot2h(rr[base + off], w1[j], acc[2]);
    }
    const int i1 = 1 + off;
    if (i1 >= 0 && i1 < 3) {
      acc[1] = fdot2h(rr[base + i1], w0[j], acc[1]);
      acc[3] = fdot2h(rr[base + i1], w1[j], acc[3]);
    }
  }
}

__global__ __launch_bounds__(256) void k_stage4(const __half* __restrict__ r3,
    const __half* __restrict__ W4P, const float* __restrict__ sc, const float* __restrict__ sh,
    float* __restrict__ r4, float* __restrict__ sum, float* __restrict__ sq) {
  __shared__ unsigned asu[NB4 * 361];   // 11.6 KB
  __shared__ unsigned wlu[10368];       // 41.5 KB
  __shared__ float ssum[96], ssq[96];
  int b0 = blockIdx.x * NB4, tid = threadIdx.x;
  for (int i = tid; i < NB4 * 360; i += 256) {
    int bb = i / 360, s = i % 360;
    int cp = s / 15, rem = s % 15, row = rem / 3, t = rem % 3;
    int c0 = 2 * cp, c1 = c0 + 1;
    float v0 = __half2float(r3[(((size_t)(b0 + bb) * 48 + c0) * 5 + row) * 3 + t]) * sc[c0] + sh[c0];
    float v1 = __half2float(r3[(((size_t)(b0 + bb) * 48 + c1) * 5 + row) * 3 + t]) * sc[c1] + sh[c1];
    asu[bb * 361 + (cp * 5 + row) * 3 + t] = pk(v0, v1);
  }
  if (tid < 96) { ssum[tid] = 0.f; ssq[tid] = 0.f; }
  bool act = tid < 192;
  int bb = act ? tid / 24 : 0, op = tid % 24;
  int b = b0 + bb;
  for (int chunk = 0; chunk < 2; ++chunk) {
    __syncthreads();
    for (int i = tid; i < 2592; i += 256)
      ((uint4*)wlu)[i] = ((const uint4*)W4P)[chunk * 2592 + i];
    __syncthreads();
    if (act) {
      float acc[12];   // [i2 3][o2][t2]
#pragma unroll
      for (int k = 0; k < 12; ++k) acc[k] = 0.f;
#pragma unroll 1
      for (int cp = 0; cp < 24; ++cp) {
        const hf2* ar = (const hf2*)(asu + bb * 361 + cp * 15);
        hf2 rr[15];
#pragma unroll
        for (int k = 0; k < 15; ++k) rr[k] = ar[k];
#pragma unroll
        for (int h = 0; h < 3; ++h) {
          const unsigned* wp = wlu + ((cp * 3 + h) * 3) * 48 + op * 2;
          hf2 w0[3], w1[3];
#pragma unroll
          for (int j = 0; j < 3; ++j) {
            w0[j] = *(const hf2*)(wp + j * 48);
            w1[j] = *(const hf2*)(wp + j * 48 + 1);
          }
          s4h<0>(rr, h, w0, w1, acc);
          s4h<1>(rr, h, w0, w1, acc + 4);
          s4h<2>(rr, h, w0, w1, acc + 8);
        }
      }
      int o0 = chunk * 48 + op * 2;
#pragma unroll
      for (int oo = 0; oo < 2; ++oo) {
        float ts = 0.f, tq = 0.f;
#pragma unroll
        for (int i2 = 0; i2 < 3; ++i2) {
          const float inv = 1.0f / (float)(1 << i2);
          float v = fmaxf(fmaxf(acc[i2 * 4 + oo * 2], acc[i2 * 4 + oo * 2 + 1]) * inv, 0.f);
          r4[(size_t)b * 288 + (o0 + oo) * 3 + i2] = v;
          ts += v; tq += v * v;
        }
        atomicAdd(&ssum[o0 + oo], ts); atomicAdd(&ssq[o0 + oo], tq);
      }
    }
  }
  __syncthreads();
  if (tid < 96) { atomicAdd(&sum[tid], ssum[tid]); atomicAdd(&sq[tid], ssq[tid]); }
}

// ---------------- FC head: BN4-affine + 288->96->48->6 ----------------
__global__ __launch_bounds__(256) void k_fc(const float* __restrict__ r4,
    const float* __restrict__ sc, const float* __restrict__ sh,
    const float* __restrict__ f1w, const float* __restrict__ f1b,
    const float* __restrict__ f2w, const float* __restrict__ f2b,
    const float* __restrict__ f3w, const float* __restrict__ f3b,
    float* __restrict__ out) {
  __shared__ float v[4][288];
  __shared__ float h1[4][96];
  __shared__ float h2[4][48];
  int b0 = blockIdx.x * 4, tid = threadIdx.x;
  for (int i = tid; i < 4 * 288; i += 256) {
    int bb = i / 288, f = i % 288, c = f / 3;
    v[bb][f] = r4[(size_t)(b0 + bb) * 288 + f] * sc[c] + sh[c];
  }
  __syncthreads();
  for (int d = tid; d < 384; d += 256) {
    int o = d >> 2, bb = d & 3;
    const float* wr = &f1w[o * 288];
    const float* vv = v[bb];
    float acc = f1b[o];
    for (int f = 0; f < 288; ++f) acc += wr[f] * vv[f];
    h1[bb][o] = acc;
  }
  __syncthreads();
  if (tid < 192) {
    int o = tid >> 2, bb = tid & 3;
    const float* wr = &f2w[o * 96];
    float acc = f2b[o];
    for (int f = 0; f < 96; ++f) acc += wr[f] * h1[bb][f];
    h2[bb][o] = acc;
  }
  __syncthreads();
  if (tid < 24) {
    int o = tid >> 2, bb = tid & 3;
    const float* wr = &f3w[o * 48];
    float acc = f3b[o];
    for (int f = 0; f < 48; ++f) acc += wr[f] * h2[bb][f];
    out[(size_t)(b0 + bb) * 6 + o] = acc;
  }
}

extern "C" void kernel_launch(void* const* d_in, const int* in_sizes, int n_in,
                              void* d_out, int out_size, void* d_ws, size_t ws_size,
                              hipStream_t stream) {
  const float* x   = (const float*)d_in[0];
  const float* w1  = (const float*)d_in[1];
  const float* w2  = (const float*)d_in[2];
  const float* w3  = (const float*)d_in[3];
  const float* w4  = (const float*)d_in[4];
  const float* g1  = (const float*)d_in[5];
  const float* b1  = (const float*)d_in[6];
  const float* g2  = (const float*)d_in[7];
  const float* b2  = (const float*)d_in[8];
  const float* g3  = (const float*)d_in[9];
  const float* b3  = (const float*)d_in[10];
  const float* g4  = (const float*)d_in[11];
  const float* b4  = (const float*)d_in[12];
  const float* f1w = (const float*)d_in[13];
  const float* f1b = (const float*)d_in[14];
  const float* f2w = (const float*)d_in[15];
  const float* f2b = (const float*)d_in[16];
  const float* f3w = (const float*)d_in[17];
  const float* f3b = (const float*)d_in[18];
  float* out = (float*)d_out;
  float* ws = (float*)d_ws;

  const int B = 4096;
  float* SUM1 = ws + 0;   float* SQ1 = ws + 12;
  float* SUM2 = ws + 24;  float* SQ2 = ws + 48;
  float* SUM3 = ws + 72;  float* SQ3 = ws + 120;
  float* SUM4 = ws + 168; float* SQ4 = ws + 264;
  float* SC1 = ws + 384;  float* SH1 = ws + 396;
  float* SC2 = ws + 408;  float* SH2 = ws + 432;
  float* SC3 = ws + 456;  float* SH3 = ws + 504;
  float* SC4 = ws + 552;  float* SH4 = ws + 648;
  __half* H0  = (__half*)(ws + 1024);
  __half* W1P = H0;                 // 504   (16B-aligned offsets)
  __half* W2P = H0 + 512;           // 4320
  __half* W3P = H0 + 4864;          // 17280
  __half* W4P = H0 + 22272;         // 41472
  __half* R1h = H0 + 65536;                 // B*5400
  __half* R2p = R1h + (size_t)B * 5400;     // B*1008
  __half* R3h = R1h;                        // alias (r1 dead after stage2)
  float*  R4  = (float*)(R2p + (size_t)B * 1008);  // B*288

  hipMemsetAsync(d_ws, 0, 384 * sizeof(float), stream);

  k_prep<<<162, 256, 0, stream>>>(w1, w2, w3, w4, W1P, W2P, W3P, W4P);
  k_lift<<<B / NB1, 256, 0, stream>>>(x, W1P, R1h, SUM1, SQ1);
  k_bnstat<<<1, 128, 0, stream>>>(SUM1, SQ1, g1, b1, SC1, SH1, 12, 1.0f / (float)(B * 450));
  k_stage2<<<(B + NB2 - 1) / NB2, 256, 0, stream>>>(R1h, W2P, SC1, SH1, R2p, SUM2, SQ2, B);
  k_bnstat<<<1, 128, 0, stream>>>(SUM2, SQ2, g2, b2, SC2, SH2, 24, 1.0f / (float)(B * 84));
  k_stage3<<<B / NB3, 256, 0, stream>>>(R2p, W3P, SC2, SH2, R3h, SUM3, SQ3);
  k_bnstat<<<1, 128, 0, stream>>>(SUM3, SQ3, g3, b3, SC3, SH3, 48, 1.0f / (float)(B * 15));
  k_stage4<<<B / NB4, 256, 0, stream>>>(R3h, W4P, SC3, SH3, R4, SUM4, SQ4);
  k_bnstat<<<1, 128, 0, stream>>>(SUM4, SQ4, g4, b4, SC4, SH4, 96, 1.0f / (float)(B * 3));
  k_fc<<<B / 4, 256, 0, stream>>>(R4, SC4, SH4, f1w, f1b, f2w, f2b, f3w, f3b, out);
}

// Round 9
// 299.537 us; speedup vs baseline: 9.1506x; 1.0726x over previous
//
#include <hip/hip_runtime.h>
#include <hip/hip_fp16.h>

#define EPSBN 2e-5f

typedef _Float16 hf2 __attribute__((ext_vector_type(2)));

static __device__ __forceinline__ float fdot2h(hf2 a, hf2 b, float c) {
  return __builtin_amdgcn_fdot2(a, b, c, false);
}
static __device__ __forceinline__ unsigned pk(float a, float b) {
  union { __half2 h; unsigned u; } u;
  u.h = __floats2half2_rn(a, b);
  return u.u;
}
static __device__ __forceinline__ float2 uph(unsigned v) {
  union { unsigned u; __half2 h; } x; x.u = v;
  return __half22float2(x.h);
}

// ============================ Stage 1: lift (+ folded weight prep) ============
// x:(B,100,6) -> LDS half2 c-pairs, zero-padded rows (stride 295 dw, 96 left pad).
// Thread=(bb4, op6, tc10)=240. r1 fp16 (B,12,9,50).
// Also packs W2P/W3P/W4P (fp16 c-pair layouts) for later stages, one elem/thread.
#define NB1 4
template<int SI>
__device__ __forceinline__ void s1_si(const unsigned* __restrict__ xsu, int bb, int t0,
    const unsigned* __restrict__ wlu, int o0, bool act, int b,
    __half* __restrict__ r1, float& ts0, float& tq0, float& ts1, float& tq1) {
  constexpr int S = 1 << SI;
  float a0[10], a1[10];
#pragma unroll
  for (int k = 0; k < 10; ++k) { a0[k] = 0.f; a1[k] = 0.f; }
#pragma unroll 1
  for (int cp = 0; cp < 3; ++cp) {
    const hf2* xr = (const hf2*)xsu + (bb * 3 + cp) * 295 + 96 + t0;
    const unsigned* wp = wlu + cp * 84;   // dword idx (cp*7+j)*12+o
#pragma unroll
    for (int j = 0; j < 7; ++j) {
      const int off = S * (j - 3);
      if (off < -96 || off > 98) continue;   // compile-time dead tap
      hf2 w0 = *(const hf2*)(wp + j * 12 + o0);
      hf2 w1 = *(const hf2*)(wp + j * 12 + o0 + 1);
      hf2 xv[10];
#pragma unroll
      for (int k = 0; k < 10; ++k) xv[k] = xr[off + k];
#pragma unroll
      for (int k = 0; k < 10; ++k) {
        a0[k] = fdot2h(xv[k], w0, a0[k]);
        a1[k] = fdot2h(xv[k], w1, a1[k]);
      }
    }
  }
  if (act) {
    const float inv = 1.0f / (float)S;
    size_t rb = ((size_t)b * 12 + o0) * 9 + SI;
#pragma unroll
    for (int u = 0; u < 5; ++u) {
      float v0 = fmaxf(fmaxf(a0[2 * u], a0[2 * u + 1]) * inv, 0.f);
      float v1 = fmaxf(fmaxf(a1[2 * u], a1[2 * u + 1]) * inv, 0.f);
      r1[rb * 50 + (t0 >> 1) + u] = __float2half_rn(v0);
      r1[(rb + 9) * 50 + (t0 >> 1) + u] = __float2half_rn(v1);
      ts0 += v0; tq0 += v0 * v0; ts1 += v1; tq1 += v1 * v1;
    }
  }
}

__global__ __launch_bounds__(256) void k_lift(const float* __restrict__ x,
    const float* __restrict__ w1, const float* __restrict__ w2,
    const float* __restrict__ w3, const float* __restrict__ w4,
    __half* __restrict__ W2P, __half* __restrict__ W3P, __half* __restrict__ W4P,
    __half* __restrict__ r1, float* __restrict__ sum, float* __restrict__ sq) {
  __shared__ __align__(16) unsigned xsu[NB1 * 885];   // [bb][cp3][295 dw]
  __shared__ __align__(16) unsigned wlu[252];
  __shared__ float ssum[12], ssq[12];
  int b0 = blockIdx.x * NB1, tid = threadIdx.x;
  // ---- folded weight prep: one element per thread grid-wide ----
  {
    int gi = blockIdx.x * 256 + tid;
    if (gi < 4320) {
      int ci = gi & 1, r = gi >> 1, o = r % 24, j = (r / 24) % 5, h = (r / 120) % 3, cp = r / 360;
      int c = 2 * cp + ci;
      W2P[gi] = __float2half_rn(w2[((o * 12 + c) * 3 + h) * 5 + j]);
    } else if (gi < 21600) {
      int k = gi - 4320;
      int ci = k & 1, r = k >> 1, o = r % 48, j = (r / 48) % 5, h = (r / 240) % 3, cp = r / 720;
      int c = 2 * cp + ci;
      W3P[k] = __float2half_rn(w3[((o * 24 + c) * 3 + h) * 5 + j]);
    } else if (gi < 63072) {
      int k = gi - 21600;
      int ci = k & 1, r = k >> 1, o48 = r % 48, j = (r / 48) % 3, h = (r / 144) % 3;
      int cp = (r / 432) % 24, ch = r / 10368, c = 2 * cp + ci, o = ch * 48 + o48;
      W4P[k] = __float2half_rn(w4[((o * 48 + c) * 3 + h) * 3 + j]);
    }
  }
  for (int i = tid; i < NB1 * 885; i += 256) xsu[i] = 0u;
  for (int i = tid; i < 252; i += 256) {
    int cp = i / 84, j = (i % 84) / 12, o = i % 12;
    wlu[i] = pk(w1[(o * 6 + 2 * cp) * 7 + j], w1[(o * 6 + 2 * cp + 1) * 7 + j]);
  }
  if (tid < 12) { ssum[tid] = 0.f; ssq[tid] = 0.f; }
  __syncthreads();
  __half* xsh = (__half*)xsu;
  for (int i = tid; i < NB1 * 600; i += 256) {
    int bb = i / 600, f = i % 600, t = f / 6, c = f % 6;
    xsh[((bb * 3 + (c >> 1)) * 295 + 96 + t) * 2 + (c & 1)] =
        __float2half_rn(x[(size_t)(b0 + bb) * 600 + f]);
  }
  __syncthreads();
  bool act = tid < 240;
  int task = act ? tid : 0;
  int bb = task / 60, r = task % 60;
  int op = r / 10, tc = r % 10;
  int o0 = op * 2, t0 = tc * 10;
  int b = b0 + bb;
  float ts0 = 0.f, tq0 = 0.f, ts1 = 0.f, tq1 = 0.f;
  s1_si<0>(xsu, bb, t0, wlu, o0, act, b, r1, ts0, tq0, ts1, tq1);
  s1_si<1>(xsu, bb, t0, wlu, o0, act, b, r1, ts0, tq0, ts1, tq1);
  s1_si<2>(xsu, bb, t0, wlu, o0, act, b, r1, ts0, tq0, ts1, tq1);
  s1_si<3>(xsu, bb, t0, wlu, o0, act, b, r1, ts0, tq0, ts1, tq1);
  s1_si<4>(xsu, bb, t0, wlu, o0, act, b, r1, ts0, tq0, ts1, tq1);
  s1_si<5>(xsu, bb, t0, wlu, o0, act, b, r1, ts0, tq0, ts1, tq1);
  s1_si<6>(xsu, bb, t0, wlu, o0, act, b, r1, ts0, tq0, ts1, tq1);
  s1_si<7>(xsu, bb, t0, wlu, o0, act, b, r1, ts0, tq0, ts1, tq1);
  s1_si<8>(xsu, bb, t0, wlu, o0, act, b, r1, ts0, tq0, ts1, tq1);
  if (act) {
    atomicAdd(&ssum[o0], ts0); atomicAdd(&ssq[o0], tq0);
    atomicAdd(&ssum[o0 + 1], ts1); atomicAdd(&ssq[o0 + 1], tq1);
  }
  __syncthreads();
  if (tid < 12) { atomicAdd(&sum[tid], ssum[tid]); atomicAdd(&sq[tid], ssq[tid]); }
}

// ============================ Stage 2 ============================
// Prologue computes BN1 scale/shift from SUM1/SQ1. LDS act: c-pair half2 rows.
// Out r2p: c-pair DWORDS [b][cp12][row7][t6]; stats from 12-wide values.
#define NB2 5
template<int S, int I2>
__device__ __forceinline__ void s2_do(const unsigned* __restrict__ abu,
    const unsigned* __restrict__ wlu, int op, bool act, int b,
    unsigned* __restrict__ r2p, float& ts0, float& tq0, float& ts1, float& tq1) {
  float acc0[24], acc1[24];
#pragma unroll
  for (int t = 0; t < 24; ++t) { acc0[t] = 0.f; acc1[t] = 0.f; }
#pragma unroll 1
  for (int cp = 0; cp < 6; ++cp) {
#pragma unroll
    for (int h = 0; h < 3; ++h) {
      const hf2* ar = (const hf2*)(abu + (cp * 9 + I2 + h) * 26);
      hf2 rr[25];
#pragma unroll
      for (int t = 0; t < 25; ++t) rr[t] = ar[t];
      const unsigned* wp = wlu + ((cp * 3 + h) * 5) * 24 + op * 2;
#pragma unroll
      for (int j = 0; j < 5; ++j) {
        const int off = S * (j - 2);
        if (off <= -25 || off >= 25) continue;
        hf2 w0 = *(const hf2*)(wp + j * 24);
        hf2 w1 = *(const hf2*)(wp + j * 24 + 1);
#pragma unroll
        for (int t = 0; t < 24; ++t) {
          if (t + off >= 0 && t + off < 25) {
            acc0[t] = fdot2h(rr[t + off], w0, acc0[t]);
            acc1[t] = fdot2h(rr[t + off], w1, acc1[t]);
          }
        }
      }
    }
  }
  if (act) {
    const float inv = 1.0f / (float)S;
    unsigned* pd = r2p + ((size_t)b * 12 + op) * 42 + I2 * 6;
    float m0 = 0.f, m1 = 0.f;
#pragma unroll
    for (int u = 0; u < 12; ++u) {
      float v0 = fmaxf(fmaxf(acc0[2 * u], acc0[2 * u + 1]) * inv, 0.f);
      float v1 = fmaxf(fmaxf(acc1[2 * u], acc1[2 * u + 1]) * inv, 0.f);
      ts0 += v0; tq0 += v0 * v0; ts1 += v1; tq1 += v1 * v1;
      if ((u & 1) == 0) { m0 = v0; m1 = v1; }
      else pd[u >> 1] = pk(fmaxf(m0, v0), fmaxf(m1, v1));
    }
  }
}

__global__ __launch_bounds__(256) void k_stage2(const __half* __restrict__ r1,
    const __half* __restrict__ W2P,
    const float* __restrict__ SUM, const float* __restrict__ SQ,
    const float* __restrict__ g, const float* __restrict__ bbn, float invN,
    unsigned* __restrict__ r2p, float* __restrict__ sum, float* __restrict__ sq, int B) {
  __shared__ __align__(16) unsigned asu[NB2 * 1405];
  __shared__ __align__(16) unsigned wlu[2160];
  __shared__ float ssum[24], ssq[24];
  __shared__ float scf[12], shf[12];
  int b0 = blockIdx.x * NB2, tid = threadIdx.x;
  if (tid < 12) {
    float m = SUM[tid] * invN;
    float v = SQ[tid] * invN - m * m;
    float scale = g[tid] * rsqrtf(v + EPSBN);
    scf[tid] = scale; shf[tid] = bbn[tid] - m * scale;
    ssum[tid] = 0.f; ssq[tid] = 0.f;
    ssum[tid + 12] = 0.f; ssq[tid + 12] = 0.f;
  }
  __syncthreads();
  for (int i = tid; i < NB2 * 1350; i += 256) {
    int bb = i / 1350, s = i % 1350;
    if (b0 + bb < B) {
      int cp = s / 225, rem = s % 225, row = rem / 25, t = rem % 25;
      int c0 = 2 * cp, c1 = c0 + 1;
      float2 a0 = __half22float2(*(const __half2*)(r1 +
          (((size_t)(b0 + bb) * 12 + c0) * 9 + row) * 50 + 2 * t));
      float2 a1 = __half22float2(*(const __half2*)(r1 +
          (((size_t)(b0 + bb) * 12 + c1) * 9 + row) * 50 + 2 * t));
      float v0 = fmaxf(a0.x, a0.y) * scf[c0] + shf[c0];
      float v1 = fmaxf(a1.x, a1.y) * scf[c1] + shf[c1];
      asu[bb * 1405 + (cp * 9 + row) * 26 + t] = pk(v0, v1);
    }
  }
  for (int i = tid; i < 540; i += 256)
    ((uint4*)wlu)[i] = ((const uint4*)W2P)[i];
  __syncthreads();
  int wv = tid >> 6, lane = tid & 63;
  int bb = lane / 12, op = lane % 12;
  bool act = (lane < 60) && (b0 + bb < B);
  if (bb > 4) bb = 4;
  const unsigned* abu = asu + bb * 1405;
  int b = b0 + bb;
  float ts0 = 0.f, tq0 = 0.f, ts1 = 0.f, tq1 = 0.f;
  if (wv == 0) {
    s2_do<1, 0>(abu, wlu, op, act, b, r2p, ts0, tq0, ts1, tq1);
  } else if (wv == 1) {
    s2_do<2, 1>(abu, wlu, op, act, b, r2p, ts0, tq0, ts1, tq1);
    s2_do<64, 6>(abu, wlu, op, act, b, r2p, ts0, tq0, ts1, tq1);
  } else if (wv == 2) {
    s2_do<4, 2>(abu, wlu, op, act, b, r2p, ts0, tq0, ts1, tq1);
    s2_do<32, 5>(abu, wlu, op, act, b, r2p, ts0, tq0, ts1, tq1);
  } else {
    s2_do<8, 3>(abu, wlu, op, act, b, r2p, ts0, tq0, ts1, tq1);
    s2_do<16, 4>(abu, wlu, op, act, b, r2p, ts0, tq0, ts1, tq1);
  }
  if (act) {
    int o0 = op * 2;
    atomicAdd(&ssum[o0], ts0); atomicAdd(&ssq[o0], tq0);
    atomicAdd(&ssum[o0 + 1], ts1); atomicAdd(&ssq[o0 + 1], tq1);
  }
  __syncthreads();
  if (tid < 24) { atomicAdd(&sum[tid], ssum[tid]); atomicAdd(&sq[tid], ssq[tid]); }
}

// ============================ Stage 3 ============================
// r2p c-pair dwords [b][cp12][row7][t6]; staging = 1 dword + affine + pack.
// Thread=(bb8, op24)=192; out r3 c-pair DWORDS [b][cp24][row5][t3].
#define NB3 8
template<int I2>
__device__ __forceinline__ void s3h(const hf2* __restrict__ rr, int h,
    const hf2* __restrict__ w0, const hf2* __restrict__ w1, float* __restrict__ acc) {
  constexpr int S = 1 << I2;
  const int base = (I2 + h) * 6;
#pragma unroll
  for (int j = 0; j < 5; ++j) {
    const int off = S * (j - 2);
    if (off <= -6 || off >= 6) continue;
#pragma unroll
    for (int t = 0; t < 6; ++t) {
      if (t + off >= 0 && t + off < 6) {
        acc[t] = fdot2h(rr[base + t + off], w0[j], acc[t]);
        acc[6 + t] = fdot2h(rr[base + t + off], w1[j], acc[6 + t]);
      }
    }
  }
}

__global__ __launch_bounds__(256) void k_stage3(const unsigned* __restrict__ r2p,
    const __half* __restrict__ W3P,
    const float* __restrict__ SUM, const float* __restrict__ SQ,
    const float* __restrict__ g, const float* __restrict__ bbn, float invN,
    unsigned* __restrict__ r3, float* __restrict__ sum, float* __restrict__ sq) {
  __shared__ __align__(16) unsigned asu[NB3 * 505];
  __shared__ __align__(16) unsigned wlu[8640];
  __shared__ float ssum[48], ssq[48];
  __shared__ float scf[24], shf[24];
  int b0 = blockIdx.x * NB3, tid = threadIdx.x;
  if (tid < 24) {
    float m = SUM[tid] * invN;
    float v = SQ[tid] * invN - m * m;
    float scale = g[tid] * rsqrtf(v + EPSBN);
    scf[tid] = scale; shf[tid] = bbn[tid] - m * scale;
  }
  if (tid < 48) { ssum[tid] = 0.f; ssq[tid] = 0.f; }
  __syncthreads();
  for (int i = tid; i < NB3 * 504; i += 256) {
    int bb = i / 504, f = i % 504, cp = f / 42;
    int c0 = 2 * cp, c1 = c0 + 1;
    float2 a = uph(r2p[(size_t)(b0 + bb) * 504 + f]);
    asu[bb * 505 + f] = pk(a.x * scf[c0] + shf[c0], a.y * scf[c1] + shf[c1]);
  }
  for (int i = tid; i < 2160; i += 256)
    ((uint4*)wlu)[i] = ((const uint4*)W3P)[i];
  __syncthreads();
  bool act = tid < 192;
  int bb = act ? tid / 24 : 0, op = tid % 24;
  int b = b0 + bb;
  if (act) {
    float acc[60];
#pragma unroll
    for (int k = 0; k < 60; ++k) acc[k] = 0.f;
#pragma unroll 1
    for (int cp = 0; cp < 12; ++cp) {
      const hf2* ar = (const hf2*)(asu + bb * 505 + cp * 42);
      hf2 rr[42];
#pragma unroll
      for (int k = 0; k < 42; ++k) rr[k] = ar[k];
#pragma unroll
      for (int h = 0; h < 3; ++h) {
        const unsigned* wp = wlu + (cp * 15 + h * 5) * 48 + op * 2;
        hf2 w0[5], w1[5];
#pragma unroll
        for (int j = 0; j < 5; ++j) {
          w0[j] = *(const hf2*)(wp + j * 48);
          w1[j] = *(const hf2*)(wp + j * 48 + 1);
        }
        s3h<0>(rr, h, w0, w1, acc);
        s3h<1>(rr, h, w0, w1, acc + 12);
        s3h<2>(rr, h, w0, w1, acc + 24);
        s3h<3>(rr, h, w0, w1, acc + 36);
        s3h<4>(rr, h, w0, w1, acc + 48);
      }
    }
    float ts0 = 0.f, tq0 = 0.f, ts1 = 0.f, tq1 = 0.f;
    int ob = op * 2;
#pragma unroll
    for (int i2 = 0; i2 < 5; ++i2) {
      const float inv = 1.0f / (float)(1 << i2);
      size_t rb = ((size_t)b * 24 + op) * 15 + i2 * 3;
#pragma unroll
      for (int u = 0; u < 3; ++u) {
        float v0 = fmaxf(fmaxf(acc[i2 * 12 + 2 * u], acc[i2 * 12 + 2 * u + 1]) * inv, 0.f);
        float v1 = fmaxf(fmaxf(acc[i2 * 12 + 6 + 2 * u], acc[i2 * 12 + 7 + 2 * u]) * inv, 0.f);
        r3[rb + u] = pk(v0, v1);
        ts0 += v0; tq0 += v0 * v0; ts1 += v1; tq1 += v1 * v1;
      }
    }
    atomicAdd(&ssum[ob], ts0); atomicAdd(&ssq[ob], tq0);
    atomicAdd(&ssum[ob + 1], ts1); atomicAdd(&ssq[ob + 1], tq1);
  }
  __syncthreads();
  if (tid < 48) { atomicAdd(&sum[tid], ssum[tid]); atomicAdd(&sq[tid], ssq[tid]); }
}

// ============================ Stage 4 ============================
// r3 c-pair dwords [b][cp24][row5][t3]; staging = 1 dword + affine + pack.
// Thread=(bb8, op24)=192; out r4 fp32 (B,96,3).
#define NB4 8
template<int I2>
__device__ __forceinline__ void s4h(const hf2* __restrict__ rr, int h,
    const hf2* __restrict__ w0, const hf2* __restrict__ w1, float* __restrict__ acc) {
  constexpr int S = 1 << I2;
  const int base = (I2 + h) * 3;
#pragma unroll
  for (int j = 0; j < 3; ++j) {
    const int off = S * (j - 1);
    if (off <= -3 || off >= 3) continue;
    if (off >= 0) {
      acc[0] = fdot2h(rr[base + off], w0[j], acc[0]);
      acc[2] = fdot2h(rr[base + off], w1[j], acc[2]);
    }
    const int i1 = 1 + off;
    if (i1 >= 0 && i1 < 3) {
      acc[1] = fdot2h(rr[base + i1], w0[j], acc[1]);
      acc[3] = fdot2h(rr[base + i1], w1[j], acc[3]);
    }
  }
}

__global__ __launch_bounds__(256) void k_stage4(const unsigned* __restrict__ r3,
    const __half* __restrict__ W4P,
    const float* __restrict__ SUM, const float* __restrict__ SQ,
    const float* __restrict__ g, const float* __restrict__ bbn, float invN,
    float* __restrict__ r4, float* __restrict__ sum, float* __restrict__ sq) {
  __shared__ __align__(16) unsigned asu[NB4 * 361];
  __shared__ __align__(16) unsigned wlu[10368];
  __shared__ float ssum[96], ssq[96];
  __shared__ float scf[48], shf[48];
  int b0 = blockIdx.x * NB4, tid = threadIdx.x;
  if (tid < 48) {
    float m = SUM[tid] * invN;
    float v = SQ[tid] * invN - m * m;
    float scale = g[tid] * rsqrtf(v + EPSBN);
    scf[tid] = scale; shf[tid] = bbn[tid] - m * scale;
  }
  if (tid < 96) { ssum[tid] = 0.f; ssq[tid] = 0.f; }
  __syncthreads();
  for (int i = tid; i < NB4 * 360; i += 256) {
    int bb = i / 360, f = i % 360, cp = f / 15;
    int c0 = 2 * cp, c1 = c0 + 1;
    float2 a = uph(r3[(size_t)(b0 + bb) * 360 + f]);
    asu[bb * 361 + f] = pk(a.x * scf[c0] + shf[c0], a.y * scf[c1] + shf[c1]);
  }
  bool act = tid < 192;
  int bb = act ? tid / 24 : 0, op = tid % 24;
  int b = b0 + bb;
  for (int chunk = 0; chunk < 2; ++chunk) {
    __syncthreads();
    for (int i = tid; i < 2592; i += 256)
      ((uint4*)wlu)[i] = ((const uint4*)W4P)[chunk * 2592 + i];
    __syncthreads();
    if (act) {
      float acc[12];   // [i2 3][o2][t2]
#pragma unroll
      for (int k = 0; k < 12; ++k) acc[k] = 0.f;
#pragma unroll 1
      for (int cp = 0; cp < 24; ++cp) {
        const hf2* ar = (const hf2*)(asu + bb * 361 + cp * 15);
        hf2 rr[15];
#pragma unroll
        for (int k = 0; k < 15; ++k) rr[k] = ar[k];
#pragma unroll
        for (int h = 0; h < 3; ++h) {
          const unsigned* wp = wlu + ((cp * 3 + h) * 3) * 48 + op * 2;
          hf2 w0[3], w1[3];
#pragma unroll
          for (int j = 0; j < 3; ++j) {
            w0[j] = *(const hf2*)(wp + j * 48);
            w1[j] = *(const hf2*)(wp + j * 48 + 1);
          }
          s4h<0>(rr, h, w0, w1, acc);
          s4h<1>(rr, h, w0, w1, acc + 4);
          s4h<2>(rr, h, w0, w1, acc + 8);
        }
      }
      int o0 = chunk * 48 + op * 2;
#pragma unroll
      for (int oo = 0; oo < 2; ++oo) {
        float ts = 0.f, tq = 0.f;
#pragma unroll
        for (int i2 = 0; i2 < 3; ++i2) {
          const float inv = 1.0f / (float)(1 << i2);
          float v = fmaxf(fmaxf(acc[i2 * 4 + oo * 2], acc[i2 * 4 + oo * 2 + 1]) * inv, 0.f);
          r4[(size_t)b * 288 + (o0 + oo) * 3 + i2] = v;
          ts += v; tq += v * v;
        }
        atomicAdd(&ssum[o0 + oo], ts); atomicAdd(&ssq[o0 + oo], tq);
      }
    }
  }
  __syncthreads();
  if (tid < 96) { atomicAdd(&sum[tid], ssum[tid]); atomicAdd(&sq[tid], ssq[tid]); }
}

// ---------------- FC head: BN4-affine + 288->96->48->6 ----------------
__global__ __launch_bounds__(256) void k_fc(const float* __restrict__ r4,
    const float* __restrict__ SUM, const float* __restrict__ SQ,
    const float* __restrict__ g, const float* __restrict__ bbn, float invN,
    const float* __restrict__ f1w, const float* __restrict__ f1b,
    const float* __restrict__ f2w, const float* __restrict__ f2b,
    const float* __restrict__ f3w, const float* __restrict__ f3b,
    float* __restrict__ out) {
  __shared__ float v[4][288];
  __shared__ float h1[4][96];
  __shared__ float h2[4][48];
  __shared__ float scf[96], shf[96];
  int b0 = blockIdx.x * 4, tid = threadIdx.x;
  if (tid < 96) {
    float m = SUM[tid] * invN;
    float vv = SQ[tid] * invN - m * m;
    float scale = g[tid] * rsqrtf(vv + EPSBN);
    scf[tid] = scale; shf[tid] = bbn[tid] - m * scale;
  }
  __syncthreads();
  for (int i = tid; i < 4 * 288; i += 256) {
    int bb = i / 288, f = i % 288, c = f / 3;
    v[bb][f] = r4[(size_t)(b0 + bb) * 288 + f] * scf[c] + shf[c];
  }
  __syncthreads();
  for (int d = tid; d < 384; d += 256) {
    int o = d >> 2, bb = d & 3;
    const float* wr = &f1w[o * 288];
    const float* vv = v[bb];
    float acc = f1b[o];
    for (int f = 0; f < 288; ++f) acc += wr[f] * vv[f];
    h1[bb][o] = acc;
  }
  __syncthreads();
  if (tid < 192) {
    int o = tid >> 2, bb = tid & 3;
    const float* wr = &f2w[o * 96];
    float acc = f2b[o];
    for (int f = 0; f < 96; ++f) acc += wr[f] * h1[bb][f];
    h2[bb][o] = acc;
  }
  __syncthreads();
  if (tid < 24) {
    int o = tid >> 2, bb = tid & 3;
    const float* wr = &f3w[o * 48];
    float acc = f3b[o];
    for (int f = 0; f < 48; ++f) acc += wr[f] * h2[bb][f];
    out[(size_t)(b0 + bb) * 6 + o] = acc;
  }
}

extern "C" void kernel_launch(void* const* d_in, const int* in_sizes, int n_in,
                              void* d_out, int out_size, void* d_ws, size_t ws_size,
                              hipStream_t stream) {
  const float* x   = (const float*)d_in[0];
  const float* w1  = (const float*)d_in[1];
  const float* w2  = (const float*)d_in[2];
  const float* w3  = (const float*)d_in[3];
  const float* w4  = (const float*)d_in[4];
  const float* g1  = (const float*)d_in[5];
  const float* b1  = (const float*)d_in[6];
  const float* g2  = (const float*)d_in[7];
  const float* b2  = (const float*)d_in[8];
  const float* g3  = (const float*)d_in[9];
  const float* b3  = (const float*)d_in[10];
  const float* g4  = (const float*)d_in[11];
  const float* b4  = (const float*)d_in[12];
  const float* f1w = (const float*)d_in[13];
  const float* f1b = (const float*)d_in[14];
  const float* f2w = (const float*)d_in[15];
  const float* f2b = (const float*)d_in[16];
  const float* f3w = (const float*)d_in[17];
  const float* f3b = (const float*)d_in[18];
  float* out = (float*)d_out;
  float* ws = (float*)d_ws;

  const int B = 4096;
  float* SUM1 = ws + 0;   float* SQ1 = ws + 12;
  float* SUM2 = ws + 24;  float* SQ2 = ws + 48;
  float* SUM3 = ws + 72;  float* SQ3 = ws + 120;
  float* SUM4 = ws + 168; float* SQ4 = ws + 264;
  __half* H0  = (__half*)(ws + 1024);
  __half* W2P = H0;                         // 4320 halfs
  __half* W3P = H0 + 4320;                  // 17280
  __half* W4P = H0 + 21600;                 // 41472
  __half* R1h = H0 + 65536;                 // B*5400 halfs
  unsigned* R2P = (unsigned*)(R1h + (size_t)B * 5400);  // B*504 dwords
  unsigned* R3D = (unsigned*)R1h;                        // alias, B*360 dwords
  float*  R4  = (float*)(R2P + (size_t)B * 504);         // B*288 floats

  hipMemsetAsync(d_ws, 0, 384 * sizeof(float), stream);

  k_lift<<<B / NB1, 256, 0, stream>>>(x, w1, w2, w3, w4, W2P, W3P, W4P, R1h, SUM1, SQ1);
  k_stage2<<<(B + NB2 - 1) / NB2, 256, 0, stream>>>(R1h, W2P, SUM1, SQ1, g1, b1,
      1.0f / (float)(B * 450), R2P, SUM2, SQ2, B);
  k_stage3<<<B / NB3, 256, 0, stream>>>(R2P, W3P, SUM2, SQ2, g2, b2,
      1.0f / (float)(B * 84), R3D, SUM3, SQ3);
  k_stage4<<<B / NB4, 256, 0, stream>>>(R3D, W4P, SUM3, SQ3, g3, b3,
      1.0f / (float)(B * 15), R4, SUM4, SQ4);
  k_fc<<<B / 4, 256, 0, stream>>>(R4, SUM4, SQ4, g4, b4,
      1.0f / (float)(B * 3), f1w, f1b, f2w, f2b, f3w, f3b, out);
}